// Round 1
// baseline (3538.963 us; speedup 1.0000x reference)
//
#include <hip/hip_runtime.h>
#include <math.h>

#define EPS 1e-5f
#define MROWS 100352        // B_ * N = 1568 * 64
#define NWIN  1568          // total windows (= B_)

// ---------------------------------------------------------------------------
// Generic 64x64-tile f32 GEMM:  C[M,N] = A[M,K] @ B[K,N] + bias[N]
// 256 threads, 4x4 micro-tile per thread, BK=16.
// ---------------------------------------------------------------------------
__global__ __launch_bounds__(256) void gemm_f32(
    const float* __restrict__ A, const float* __restrict__ B,
    const float* __restrict__ bias, float* __restrict__ C,
    int M, int N, int K) {
  __shared__ float As[16][64];   // [kk][mm]
  __shared__ float Bs[16][64];   // [kk][nn]
  const int tid = threadIdx.x;
  const int tx = tid & 15, ty = tid >> 4;
  const int row0 = blockIdx.y * 64, col0 = blockIdx.x * 64;
  const int lm = tid >> 2, lk = (tid & 3) * 4;   // A loader: row lm, k4 lk
  const int bk = tid >> 4, bn = (tid & 15) * 4;  // B loader: k row bk, col4 bn
  float acc[4][4] = {};
  for (int k0 = 0; k0 < K; k0 += 16) {
    float4 a4 = *(const float4*)&A[(row0 + lm) * K + k0 + lk];
    float4 b4 = *(const float4*)&B[(k0 + bk) * N + col0 + bn];
    __syncthreads();
    As[lk + 0][lm] = a4.x; As[lk + 1][lm] = a4.y;
    As[lk + 2][lm] = a4.z; As[lk + 3][lm] = a4.w;
    *(float4*)&Bs[bk][bn] = b4;
    __syncthreads();
#pragma unroll
    for (int kk = 0; kk < 16; ++kk) {
      float4 av = *(const float4*)&As[kk][ty * 4];
      float4 bv = *(const float4*)&Bs[kk][tx * 4];
      float ar[4] = {av.x, av.y, av.z, av.w};
      float br[4] = {bv.x, bv.y, bv.z, bv.w};
#pragma unroll
      for (int i = 0; i < 4; ++i)
#pragma unroll
        for (int j = 0; j < 4; ++j)
          acc[i][j] += ar[i] * br[j];
    }
  }
#pragma unroll
  for (int i = 0; i < 4; ++i) {
    int r = row0 + ty * 4 + i;
#pragma unroll
    for (int j = 0; j < 4; ++j) {
      int cc = col0 + tx * 4 + j;
      C[r * N + cc] = acc[i][j] + bias[cc];
    }
  }
}

// ---------------------------------------------------------------------------
// Row LayerNorm in place, one wave per row. W = 256 or 512.
// ---------------------------------------------------------------------------
template <int W>
__global__ __launch_bounds__(64) void ln_rows(float* __restrict__ buf,
                                              const float* __restrict__ g,
                                              const float* __restrict__ b) {
  const int row = blockIdx.x, t = threadIdx.x;
  constexpr int NCH = W / 256;
  float4 v[NCH];
  float s = 0.f, sq = 0.f;
#pragma unroll
  for (int ch = 0; ch < NCH; ++ch) {
    v[ch] = *(const float4*)&buf[row * W + ch * 256 + t * 4];
    s += v[ch].x + v[ch].y + v[ch].z + v[ch].w;
    sq += v[ch].x * v[ch].x + v[ch].y * v[ch].y + v[ch].z * v[ch].z + v[ch].w * v[ch].w;
  }
#pragma unroll
  for (int off = 32; off >= 1; off >>= 1) {
    s += __shfl_xor(s, off);
    sq += __shfl_xor(sq, off);
  }
  const float mean = s * (1.f / W);
  const float var = sq * (1.f / W) - mean * mean;
  const float rstd = rsqrtf(var + EPS);
#pragma unroll
  for (int ch = 0; ch < NCH; ++ch) {
    int c = ch * 256 + t * 4;
    float4 o;
    o.x = (v[ch].x - mean) * rstd * g[c + 0] + b[c + 0];
    o.y = (v[ch].y - mean) * rstd * g[c + 1] + b[c + 1];
    o.z = (v[ch].z - mean) * rstd * g[c + 2] + b[c + 2];
    o.w = (v[ch].w - mean) * rstd * g[c + 3] + b[c + 3];
    *(float4*)&buf[row * W + c] = o;
  }
}

__device__ __forceinline__ float gelu_exact(float x) {
  return 0.5f * x * (1.f + erff(x * 0.70710678118654752f));
}

// ---------------------------------------------------------------------------
// Depthwise 3x3 conv (pad 1) + dw_b + BN1 + exact GELU, on window layout.
// One block per window; 4 channel chunks of 128; 10x10 halo tile in LDS.
// Also writes per-window channel sums (for global avg pool) to ci_part.
// ---------------------------------------------------------------------------
__global__ __launch_bounds__(256) void dwconv_bn_gelu(
    const float* __restrict__ xin,  // (MROWS, 512) window layout
    const float* __restrict__ wgt9, const float* __restrict__ dwb,
    const float* __restrict__ g1, const float* __restrict__ b1,
    const float* __restrict__ m1, const float* __restrict__ v1,
    float* __restrict__ outp,       // (MROWS, 512)
    float* __restrict__ ci_part) {  // (NWIN, 512)
  __shared__ float tile[100 * 128];  // 51.2 KB
  const int b_ = blockIdx.x;
  const int b = b_ / 784, win = b_ % 784;
  const int wi = win / 28, wj = win % 28;
  const int h0 = wi * 8 - 1, w0 = wj * 8 - 1;
  const int tid = threadIdx.x;
  const int c = tid & 127, half = tid >> 7;
  for (int chunk = 0; chunk < 4; ++chunk) {
    const int c0 = chunk * 128;
    __syncthreads();
    for (int it = 0; it < 50; ++it) {
      int p = it * 2 + half;
      int ph = h0 + p / 10, pw = w0 + p % 10;
      float val = 0.f;
      if (ph >= 0 && ph < 224 && pw >= 0 && pw < 224) {
        int bs = b * 784 + (ph >> 3) * 28 + (pw >> 3);
        int n = ((ph & 7) << 3) | (pw & 7);
        val = xin[(bs * 64 + n) * 512 + c0 + c];
      }
      tile[p * 128 + c] = val;
    }
    __syncthreads();
    float w[9];
#pragma unroll
    for (int k = 0; k < 9; ++k) w[k] = wgt9[(c0 + c) * 9 + k];
    const float scale = g1[c0 + c] * rsqrtf(v1[c0 + c] + EPS);
    const float shift = b1[c0 + c] - m1[c0 + c] * scale;
    const float bias0 = dwb[c0 + c];
    float csum = 0.f;
    for (int q = 0; q < 32; ++q) {
      int qq = half * 32 + q;
      int r = qq >> 3, cc = qq & 7;
      float acc = bias0;
#pragma unroll
      for (int dr = 0; dr < 3; ++dr)
#pragma unroll
        for (int dc = 0; dc < 3; ++dc)
          acc += tile[((r + dr) * 10 + cc + dc) * 128 + c] * w[dr * 3 + dc];
      float t2 = acc * scale + shift;
      float ge = gelu_exact(t2);
      outp[(b_ * 64 + qq) * 512 + c0 + c] = ge;
      csum += ge;
    }
    __syncthreads();
    tile[tid] = csum;
    __syncthreads();
    if (tid < 128) ci_part[b_ * 512 + c0 + tid] = tile[tid] + tile[tid + 128];
  }
}

// Deterministic reduction of per-window sums -> per-batch channel means.
__global__ __launch_bounds__(512) void ci_reduce(const float* __restrict__ ci_part,
                                                 float* __restrict__ ci_mean) {
  const int b = blockIdx.x, c = threadIdx.x;
  float s = 0.f;
  for (int w = 0; w < 784; ++w) s += ci_part[(b * 784 + w) * 512 + c];
  ci_mean[b * 512 + c] = s * (1.f / 50176.f);
}

// Channel-interaction MLP -> sigmoid gate (2 x 256). Single block.
__global__ __launch_bounds__(512) void ci_gate(
    const float* __restrict__ ci_mean,
    const float* __restrict__ w1, const float* __restrict__ bi1,
    const float* __restrict__ g2, const float* __restrict__ b2,
    const float* __restrict__ m2, const float* __restrict__ v2,
    const float* __restrict__ w2, const float* __restrict__ bi2,
    float* __restrict__ gate) {
  __shared__ float cm[1024];
  __shared__ float c1[128];
  const int t = threadIdx.x;
  cm[t] = ci_mean[t];
  cm[t + 512] = ci_mean[t + 512];
  __syncthreads();
  if (t < 128) {
    int b = t >> 6, j = t & 63;
    float acc = bi1[j];
    for (int c = 0; c < 512; ++c) acc += cm[b * 512 + c] * w1[c * 64 + j];
    float sc = g2[j] * rsqrtf(v2[j] + EPS);
    float val = (acc - m2[j]) * sc + b2[j];
    c1[t] = gelu_exact(val);
  }
  __syncthreads();
  {
    int b = t >> 8, o = t & 255;
    float acc = bi2[o];
#pragma unroll
    for (int j = 0; j < 64; ++j) acc += c1[b * 64 + j] * w2[j * 256 + o];
    gate[b * 256 + o] = 1.f / (1.f + expf(-acc));
  }
}

// ---------------------------------------------------------------------------
// Windowed attention: one wave per (window, head). N=64, hd=32.
// qkv row layout: [q(8x32) | k(8x32) | v(8x32)] = 768.
// ---------------------------------------------------------------------------
__global__ __launch_bounds__(64) void attn_kernel(
    const float* __restrict__ qkv, const float* __restrict__ gate,
    const float* __restrict__ rpb, const int* __restrict__ rel,
    float* __restrict__ outp) {  // (MROWS, 256)
  __shared__ float ks[64 * 32];
  __shared__ float vs[64 * 32];
  const int bid = blockIdx.x;
  const int b_ = bid >> 3, h = bid & 7;
  const int b = b_ / 784;
  const int t = threadIdx.x;
  const float scale = 0.17677669529663687f;  // 32^-0.5
  const int base = (b_ * 64 + t) * 768 + h * 32;
  float qr[32];
#pragma unroll
  for (int d4 = 0; d4 < 8; ++d4) {
    float4 kv = *(const float4*)&qkv[base + 256 + d4 * 4];
    *(float4*)&ks[t * 32 + d4 * 4] = kv;
    float4 vv = *(const float4*)&qkv[base + 512 + d4 * 4];
    float4 gg = *(const float4*)&gate[b * 256 + h * 32 + d4 * 4];
    vv.x *= gg.x; vv.y *= gg.y; vv.z *= gg.z; vv.w *= gg.w;
    *(float4*)&vs[t * 32 + d4 * 4] = vv;
    float4 qv = *(const float4*)&qkv[base + d4 * 4];
    qr[d4 * 4 + 0] = qv.x * scale; qr[d4 * 4 + 1] = qv.y * scale;
    qr[d4 * 4 + 2] = qv.z * scale; qr[d4 * 4 + 3] = qv.w * scale;
  }
  __syncthreads();
  float p[64];
  float mx = -1e30f;
#pragma unroll
  for (int m = 0; m < 64; ++m) {
    float acc = rpb[rel[t * 64 + m] * 8 + h];
    const float4* km = (const float4*)&ks[m * 32];
#pragma unroll
    for (int d4 = 0; d4 < 8; ++d4) {
      float4 kv = km[d4];
      acc += qr[d4 * 4 + 0] * kv.x + qr[d4 * 4 + 1] * kv.y +
             qr[d4 * 4 + 2] * kv.z + qr[d4 * 4 + 3] * kv.w;
    }
    p[m] = acc;
    mx = fmaxf(mx, acc);
  }
  float s = 0.f;
#pragma unroll
  for (int m = 0; m < 64; ++m) {
    p[m] = __expf(p[m] - mx);
    s += p[m];
  }
  const float inv = 1.f / s;
  float o[32] = {};
#pragma unroll
  for (int m = 0; m < 64; ++m) {
    float pm = p[m] * inv;
    const float4* vm = (const float4*)&vs[m * 32];
#pragma unroll
    for (int d4 = 0; d4 < 8; ++d4) {
      float4 vv = vm[d4];
      o[d4 * 4 + 0] += pm * vv.x; o[d4 * 4 + 1] += pm * vv.y;
      o[d4 * 4 + 2] += pm * vv.z; o[d4 * 4 + 3] += pm * vv.w;
    }
  }
  const int ob = (b_ * 64 + t) * 256 + h * 32;
#pragma unroll
  for (int d4 = 0; d4 < 8; ++d4) {
    float4 ov = {o[d4 * 4 + 0], o[d4 * 4 + 1], o[d4 * 4 + 2], o[d4 * 4 + 3]};
    *(float4*)&outp[ob + d4 * 4] = ov;
  }
}

// ---------------------------------------------------------------------------
// Fused: spatial-interaction gate (1x1 -> BN4 -> GELU -> 1x1 -> sigmoid),
// BN3 on gated conv branch, LayerNorm-out on attention branch,
// concat write into (MROWS, 512). 16 pixels per block, 256 threads.
// ---------------------------------------------------------------------------
__global__ __launch_bounds__(256) void si_ln_concat(
    const float* __restrict__ xatt,  // (MROWS,256) attention out (pre-LN)
    const float* __restrict__ xpj,   // (MROWS,256) conv-branch pj out
    const float* __restrict__ w1, const float* __restrict__ bi1,
    const float* __restrict__ g4, const float* __restrict__ b4v,
    const float* __restrict__ m4, const float* __restrict__ v4,
    const float* __restrict__ w2, const float* __restrict__ bi2,
    const float* __restrict__ g3, const float* __restrict__ b3v,
    const float* __restrict__ m3, const float* __restrict__ v3,
    const float* __restrict__ glno, const float* __restrict__ blno,
    float* __restrict__ outc) {  // (MROWS, 512)
  __shared__ float xr[16 * 256];
  __shared__ float s1s[16 * 64];
  __shared__ float sig[16];
  const int t = threadIdx.x;
  const int row0 = blockIdx.x * 16;
  // load 16 rows of xatt
#pragma unroll
  for (int i = 0; i < 4; ++i) {
    int idx = i * 256 + t;           // float4 index
    int pr = idx >> 6, pc = (idx & 63) * 4;
    *(float4*)&xr[pr * 256 + pc] = *(const float4*)&xatt[(row0 + pr) * 256 + pc];
  }
  __syncthreads();
  // s1 = gelu(bn4(xatt @ si_w1 + b)) : 16 rows x 64 cols, 4 rows per thread
  {
    const int j = t & 63, pg = t >> 6;
    float acc[4];
    const float bj = bi1[j];
#pragma unroll
    for (int i = 0; i < 4; ++i) acc[i] = bj;
    for (int cc = 0; cc < 256; ++cc) {
      float wv = w1[cc * 64 + j];
#pragma unroll
      for (int i = 0; i < 4; ++i) acc[i] += xr[(pg * 4 + i) * 256 + cc] * wv;
    }
    const float sc4 = g4[j] * rsqrtf(v4[j] + EPS);
    const float m4j = m4[j], b4j = b4v[j];
#pragma unroll
    for (int i = 0; i < 4; ++i) {
      float val = (acc[i] - m4j) * sc4 + b4j;
      s1s[(pg * 4 + i) * 64 + j] = gelu_exact(val);
    }
  }
  __syncthreads();
  if (t < 16) {
    float a2 = bi2[0];
#pragma unroll
    for (int jj = 0; jj < 64; ++jj) a2 += s1s[t * 64 + jj] * w2[jj];
    sig[t] = 1.f / (1.f + expf(-a2));
  }
  __syncthreads();
  // LN over xatt rows + BN3(sig * xpj), concat write
  {
    const int p = t >> 4, l = t & 15;
    float4 v4s[4];
    float s = 0.f, sq = 0.f;
#pragma unroll
    for (int cq = 0; cq < 4; ++cq) {
      float4 x4 = *(const float4*)&xr[p * 256 + cq * 64 + l * 4];
      v4s[cq] = x4;
      s += x4.x + x4.y + x4.z + x4.w;
      sq += x4.x * x4.x + x4.y * x4.y + x4.z * x4.z + x4.w * x4.w;
    }
#pragma unroll
    for (int off = 8; off >= 1; off >>= 1) {
      s += __shfl_xor(s, off);
      sq += __shfl_xor(sq, off);
    }
    const float mean = s * (1.f / 256.f);
    const float var = sq * (1.f / 256.f) - mean * mean;
    const float rstd = rsqrtf(var + EPS);
    const int orow = (row0 + p) * 512;
#pragma unroll
    for (int cq = 0; cq < 4; ++cq) {
      int c = cq * 64 + l * 4;
      float4 x4 = v4s[cq];
      float4 o;
      o.x = (x4.x - mean) * rstd * glno[c + 0] + blno[c + 0];
      o.y = (x4.y - mean) * rstd * glno[c + 1] + blno[c + 1];
      o.z = (x4.z - mean) * rstd * glno[c + 2] + blno[c + 2];
      o.w = (x4.w - mean) * rstd * glno[c + 3] + blno[c + 3];
      *(float4*)&outc[orow + c] = o;
    }
    const float sg = sig[p];
#pragma unroll
    for (int cq = 0; cq < 4; ++cq) {
      int c = cq * 64 + l * 4;
      float4 pv = *(const float4*)&xpj[(row0 + p) * 256 + c];
      float4 o;
      float sc, sh;
      sc = g3[c + 0] * rsqrtf(v3[c + 0] + EPS); sh = b3v[c + 0] - m3[c + 0] * sc;
      o.x = sg * pv.x * sc + sh;
      sc = g3[c + 1] * rsqrtf(v3[c + 1] + EPS); sh = b3v[c + 1] - m3[c + 1] * sc;
      o.y = sg * pv.y * sc + sh;
      sc = g3[c + 2] * rsqrtf(v3[c + 2] + EPS); sh = b3v[c + 2] - m3[c + 2] * sc;
      o.z = sg * pv.z * sc + sh;
      sc = g3[c + 3] * rsqrtf(v3[c + 3] + EPS); sh = b3v[c + 3] - m3[c + 3] * sc;
      o.w = sg * pv.w * sc + sh;
      *(float4*)&outc[orow + 256 + c] = o;
    }
  }
}

// ---------------------------------------------------------------------------
extern "C" void kernel_launch(void* const* d_in, const int* in_sizes, int n_in,
                              void* d_out, int out_size, void* d_ws, size_t ws_size,
                              hipStream_t stream) {
  const float* x     = (const float*)d_in[0];
  const float* w_pa  = (const float*)d_in[1];
  const float* b_pa  = (const float*)d_in[2];
  const float* g_lna = (const float*)d_in[3];
  const float* b_lna = (const float*)d_in[4];
  const float* w_pc  = (const float*)d_in[5];
  const float* b_pc  = (const float*)d_in[6];
  const float* g_lnc = (const float*)d_in[7];
  const float* b_lnc = (const float*)d_in[8];
  const float* dw_w  = (const float*)d_in[9];
  const float* dw_b  = (const float*)d_in[10];
  const float* g_bn1 = (const float*)d_in[11];
  const float* b_bn1 = (const float*)d_in[12];
  const float* m_bn1 = (const float*)d_in[13];
  const float* v_bn1 = (const float*)d_in[14];
  const float* ci_w1 = (const float*)d_in[15];
  const float* ci_b1 = (const float*)d_in[16];
  const float* g_bn2 = (const float*)d_in[17];
  const float* b_bn2 = (const float*)d_in[18];
  const float* m_bn2 = (const float*)d_in[19];
  const float* v_bn2 = (const float*)d_in[20];
  const float* ci_w2 = (const float*)d_in[21];
  const float* ci_b2 = (const float*)d_in[22];
  const float* pj_w  = (const float*)d_in[23];
  const float* pj_b  = (const float*)d_in[24];
  const float* g_bn3 = (const float*)d_in[25];
  const float* b_bn3 = (const float*)d_in[26];
  const float* m_bn3 = (const float*)d_in[27];
  const float* v_bn3 = (const float*)d_in[28];
  const float* w_qkv = (const float*)d_in[29];
  const float* b_qkv = (const float*)d_in[30];
  const float* si_w1 = (const float*)d_in[31];
  const float* si_b1 = (const float*)d_in[32];
  const float* g_bn4 = (const float*)d_in[33];
  const float* b_bn4 = (const float*)d_in[34];
  const float* m_bn4 = (const float*)d_in[35];
  const float* v_bn4 = (const float*)d_in[36];
  const float* si_w2 = (const float*)d_in[37];
  const float* si_b2 = (const float*)d_in[38];
  const float* g_lno = (const float*)d_in[39];
  const float* b_lno = (const float*)d_in[40];
  const float* w_out = (const float*)d_in[41];
  const float* b_out = (const float*)d_in[42];
  const float* rpb   = (const float*)d_in[43];
  const int*   rel   = (const int*)d_in[44];

  char* ws = (char*)d_ws;
  // phase-aliased workspace layout (~591 MiB):
  //   [0, 205.5M)   : W1 (x_cnn LN'd)  -> later low half of QKV -> concat
  //   [205.5, 411M) : W2 (conv out)    -> later high part of QKV
  //   [0, 308.3M)   : QKV (after conv+pj both consumed)
  float* W1   = (float*)(ws + 0);
  float* QKV  = (float*)(ws + 0);
  float* W2   = (float*)(ws + 205520896ull);
  float* W4   = (float*)(ws + 411041792ull);  // x_att -> x_att2
  float* W5   = (float*)(ws + 513802240ull);  // x_cnn_pj
  float* CIP  = (float*)(ws + 616562688ull);  // (1568, 512) partial sums
  float* CIM  = (float*)(ws + 619773952ull);  // (2, 512)
  float* GATE = (float*)(ws + 619778048ull);  // (2, 256)
  float* OUT  = (float*)d_out;

  const int M = MROWS;
  dim3 b256(256), b64(64), b512(512);

  // 1) x_att = LN(x @ w_pa + b_pa)        -> W4 (M,256)
  gemm_f32<<<dim3(4, M / 64), b256, 0, stream>>>(x, w_pa, b_pa, W4, M, 256, 512);
  ln_rows<256><<<M, b64, 0, stream>>>(W4, g_lna, b_lna);

  // 2) x_cnn = LN(x @ w_pc + b_pc)        -> W1 (M,512)
  gemm_f32<<<dim3(8, M / 64), b256, 0, stream>>>(x, w_pc, b_pc, W1, M, 512, 512);
  ln_rows<512><<<M, b64, 0, stream>>>(W1, g_lnc, b_lnc);

  // 3) depthwise conv + BN1 + GELU        -> W2 ; per-window channel sums
  dwconv_bn_gelu<<<NWIN, b256, 0, stream>>>(W1, dw_w, dw_b, g_bn1, b_bn1, m_bn1,
                                            v_bn1, W2, CIP);
  ci_reduce<<<2, b512, 0, stream>>>(CIP, CIM);
  ci_gate<<<1, b512, 0, stream>>>(CIM, ci_w1, ci_b1, g_bn2, b_bn2, m_bn2, v_bn2,
                                  ci_w2, ci_b2, GATE);

  // 4) pj: conv branch 512->256           -> W5
  gemm_f32<<<dim3(4, M / 64), b256, 0, stream>>>(W2, pj_w, pj_b, W5, M, 256, 512);

  // 5) qkv = x_att @ w_qkv + b_qkv        -> QKV (overwrites dead W1+W2)
  gemm_f32<<<dim3(12, M / 64), b256, 0, stream>>>(W4, w_qkv, b_qkv, QKV, M, 768, 256);

  // 6) windowed attention (+gate, +rel-pos bias) -> W4 (x_att2)
  attn_kernel<<<NWIN * 8, b64, 0, stream>>>(QKV, GATE, rpb, rel, W4);

  // 7) spatial gate + BN3 + LN-out + concat -> W1 region (M,512)
  si_ln_concat<<<M / 16, b256, 0, stream>>>(W4, W5, si_w1, si_b1, g_bn4, b_bn4,
                                            m_bn4, v_bn4, si_w2, si_b2, g_bn3,
                                            b_bn3, m_bn3, v_bn3, g_lno, b_lno, W1);

  // 8) out = concat @ w_out + b_out       -> d_out
  gemm_f32<<<dim3(8, M / 64), b256, 0, stream>>>(W1, w_out, b_out, OUT, M, 512, 512);
}

// Round 2
// 1301.814 us; speedup vs baseline: 2.7185x; 2.7185x over previous
//
#include <hip/hip_runtime.h>
#include <math.h>

#define EPS 1e-5f
#define MROWS 100352        // B_ * N = 1568 * 64
#define NWIN  1568

typedef __attribute__((ext_vector_type(8))) short bf16x8;
typedef __attribute__((ext_vector_type(4))) float f32x4;

__device__ __forceinline__ unsigned short f2bf(float f) {
  unsigned u = __float_as_uint(f);
  u += 0x7fffu + ((u >> 16) & 1u);
  return (unsigned short)(u >> 16);
}
__device__ __forceinline__ float bf2f(unsigned short s) {
  return __uint_as_float(((unsigned)s) << 16);
}
__device__ __forceinline__ float gelu_exact(float x) {
  return 0.5f * x * (1.f + erff(x * 0.70710678118654752f));
}

#define GLOAD16(gp, lp)                                              \
  __builtin_amdgcn_global_load_lds(                                  \
      (const __attribute__((address_space(1))) void*)(gp),           \
      (__attribute__((address_space(3))) void*)(lp), 16, 0, 0)

// ---------------------------------------------------------------------------
// bf16 MFMA GEMM (m97 structure): C[M,N] = A[M,K](bf16) @ Bt[N,K](bf16)^T + bias
// 128x128 tile, BK=32, 256 threads = 4 waves (2x2 of 64x64), 16 MFMA/wave/K-step.
// ---------------------------------------------------------------------------
template <bool OUTBF>
__global__ __launch_bounds__(256) void gemm_bf16(
    const unsigned short* __restrict__ A, const unsigned short* __restrict__ Bt,
    const float* __restrict__ bias, void* __restrict__ Cout,
    int M, int N, int K) {
  __shared__ unsigned short As[128 * 32];  // 8 KB
  __shared__ unsigned short Bs[128 * 32];  // 8 KB
  const int tid = threadIdx.x;
  const int lane = tid & 63, wave = tid >> 6;
  const int wr = wave >> 1, wc = wave & 1;
  const int row0 = blockIdx.y * 128, col0 = blockIdx.x * 128;
  const int lrow = tid >> 2, loff = (tid & 3) * 8;
  f32x4 acc[4][4];
#pragma unroll
  for (int m = 0; m < 4; ++m)
#pragma unroll
    for (int n = 0; n < 4; ++n) acc[m][n] = (f32x4){0.f, 0.f, 0.f, 0.f};
  for (int k0 = 0; k0 < K; k0 += 32) {
    __syncthreads();
#pragma unroll
    for (int p = 0; p < 2; ++p) {
      int r = p * 64 + lrow;
      GLOAD16(&A[(size_t)(row0 + r) * K + k0 + loff], &As[r * 32 + loff]);
      GLOAD16(&Bt[(size_t)(col0 + r) * K + k0 + loff], &Bs[r * 32 + loff]);
    }
    __syncthreads();
    const int g8 = (lane >> 4) * 8, rl = lane & 15;
    bf16x8 af[4], bfr[4];
#pragma unroll
    for (int m = 0; m < 4; ++m)
      af[m] = *(const bf16x8*)&As[(wr * 64 + m * 16 + rl) * 32 + g8];
#pragma unroll
    for (int n = 0; n < 4; ++n)
      bfr[n] = *(const bf16x8*)&Bs[(wc * 64 + n * 16 + rl) * 32 + g8];
#pragma unroll
    for (int m = 0; m < 4; ++m)
#pragma unroll
      for (int n = 0; n < 4; ++n)
        acc[m][n] = __builtin_amdgcn_mfma_f32_16x16x32_bf16(af[m], bfr[n],
                                                            acc[m][n], 0, 0, 0);
  }
  const int crow = (lane >> 4) * 4, ccol = lane & 15;
#pragma unroll
  for (int n = 0; n < 4; ++n) {
    const int gc = col0 + wc * 64 + n * 16 + ccol;
    const float bz = bias[gc];
#pragma unroll
    for (int m = 0; m < 4; ++m) {
      const int gr0 = row0 + wr * 64 + m * 16 + crow;
#pragma unroll
      for (int r = 0; r < 4; ++r) {
        float val = acc[m][n][r] + bz;
        if constexpr (OUTBF)
          ((unsigned short*)Cout)[(size_t)(gr0 + r) * N + gc] = f2bf(val);
        else
          ((float*)Cout)[(size_t)(gr0 + r) * N + gc] = val;
      }
    }
  }
}

// ---------------------------------------------------------------------------
// Weight convert + transpose: in (K,N) f32 -> out (N,K) bf16.
// ---------------------------------------------------------------------------
__global__ __launch_bounds__(256) void wt_convert(const float* __restrict__ in,
                                                  unsigned short* __restrict__ out,
                                                  int K, int N) {
  int i = blockIdx.x * 256 + threadIdx.x;
  if (i >= K * N) return;
  int n = i / K, k = i - n * K;
  out[i] = f2bf(in[(size_t)k * N + n]);
}

// x (f32) -> bf16, 8 elems/thread.
__global__ __launch_bounds__(256) void cvt_bf16(const float* __restrict__ in,
                                                unsigned short* __restrict__ out,
                                                int n8) {
  int i = blockIdx.x * 256 + threadIdx.x;
  if (i >= n8) return;
  float4 a = ((const float4*)in)[i * 2];
  float4 b = ((const float4*)in)[i * 2 + 1];
  ((ushort4*)out)[i * 2] = make_ushort4(f2bf(a.x), f2bf(a.y), f2bf(a.z), f2bf(a.w));
  ((ushort4*)out)[i * 2 + 1] = make_ushort4(f2bf(b.x), f2bf(b.y), f2bf(b.z), f2bf(b.w));
}

// ---------------------------------------------------------------------------
// Row LayerNorm: f32 in -> bf16 out. One wave per row.
// ---------------------------------------------------------------------------
template <int W>
__global__ __launch_bounds__(64) void ln_rows_bf(const float* __restrict__ in,
                                                 unsigned short* __restrict__ out,
                                                 const float* __restrict__ g,
                                                 const float* __restrict__ b) {
  const int row = blockIdx.x, t = threadIdx.x;
  constexpr int NCH = W / 256;
  float4 v[NCH];
  float s = 0.f, sq = 0.f;
#pragma unroll
  for (int ch = 0; ch < NCH; ++ch) {
    v[ch] = *(const float4*)&in[(size_t)row * W + ch * 256 + t * 4];
    s += v[ch].x + v[ch].y + v[ch].z + v[ch].w;
    sq += v[ch].x * v[ch].x + v[ch].y * v[ch].y + v[ch].z * v[ch].z + v[ch].w * v[ch].w;
  }
#pragma unroll
  for (int off = 32; off >= 1; off >>= 1) {
    s += __shfl_xor(s, off);
    sq += __shfl_xor(sq, off);
  }
  const float mean = s * (1.f / W);
  const float var = sq * (1.f / W) - mean * mean;
  const float rstd = rsqrtf(var + EPS);
#pragma unroll
  for (int ch = 0; ch < NCH; ++ch) {
    int c = ch * 256 + t * 4;
    ushort4 o = make_ushort4(
        f2bf((v[ch].x - mean) * rstd * g[c + 0] + b[c + 0]),
        f2bf((v[ch].y - mean) * rstd * g[c + 1] + b[c + 1]),
        f2bf((v[ch].z - mean) * rstd * g[c + 2] + b[c + 2]),
        f2bf((v[ch].w - mean) * rstd * g[c + 3] + b[c + 3]));
    *(ushort4*)&out[(size_t)row * W + c] = o;
  }
}

// ---------------------------------------------------------------------------
// Depthwise 3x3 + BN1 + GELU (bf16 in/out), window layout, + per-window sums.
// ---------------------------------------------------------------------------
__global__ __launch_bounds__(256) void dwconv_bn_gelu(
    const unsigned short* __restrict__ xin, const float* __restrict__ wgt9,
    const float* __restrict__ dwb, const float* __restrict__ g1,
    const float* __restrict__ b1, const float* __restrict__ m1,
    const float* __restrict__ v1, unsigned short* __restrict__ outp,
    float* __restrict__ ci_part) {
  __shared__ float tile[100 * 128];
  const int b_ = blockIdx.x;
  const int b = b_ / 784, win = b_ % 784;
  const int wi = win / 28, wj = win % 28;
  const int h0 = wi * 8 - 1, w0 = wj * 8 - 1;
  const int tid = threadIdx.x;
  const int c = tid & 127, half = tid >> 7;
  for (int chunk = 0; chunk < 4; ++chunk) {
    const int c0 = chunk * 128;
    __syncthreads();
    for (int it = 0; it < 50; ++it) {
      int p = it * 2 + half;
      int ph = h0 + p / 10, pw = w0 + p % 10;
      float val = 0.f;
      if (ph >= 0 && ph < 224 && pw >= 0 && pw < 224) {
        int bs = b * 784 + (ph >> 3) * 28 + (pw >> 3);
        int n = ((ph & 7) << 3) | (pw & 7);
        val = bf2f(xin[(size_t)(bs * 64 + n) * 512 + c0 + c]);
      }
      tile[p * 128 + c] = val;
    }
    __syncthreads();
    float w[9];
#pragma unroll
    for (int k = 0; k < 9; ++k) w[k] = wgt9[(c0 + c) * 9 + k];
    const float scale = g1[c0 + c] * rsqrtf(v1[c0 + c] + EPS);
    const float shift = b1[c0 + c] - m1[c0 + c] * scale;
    const float bias0 = dwb[c0 + c];
    float csum = 0.f;
    for (int q = 0; q < 32; ++q) {
      int qq = half * 32 + q;
      int r = qq >> 3, cc = qq & 7;
      float acc = bias0;
#pragma unroll
      for (int dr = 0; dr < 3; ++dr)
#pragma unroll
        for (int dc = 0; dc < 3; ++dc)
          acc += tile[((r + dr) * 10 + cc + dc) * 128 + c] * w[dr * 3 + dc];
      float ge = gelu_exact(acc * scale + shift);
      outp[(size_t)(b_ * 64 + qq) * 512 + c0 + c] = f2bf(ge);
      csum += ge;
    }
    __syncthreads();
    tile[tid] = csum;
    __syncthreads();
    if (tid < 128) ci_part[(size_t)b_ * 512 + c0 + tid] = tile[tid] + tile[tid + 128];
  }
}

__global__ __launch_bounds__(512) void ci_reduce(const float* __restrict__ ci_part,
                                                 float* __restrict__ ci_mean) {
  const int b = blockIdx.x, c = threadIdx.x;
  float s = 0.f;
  for (int w = 0; w < 784; ++w) s += ci_part[(size_t)(b * 784 + w) * 512 + c];
  ci_mean[b * 512 + c] = s * (1.f / 50176.f);
}

__global__ __launch_bounds__(512) void ci_gate(
    const float* __restrict__ ci_mean, const float* __restrict__ w1,
    const float* __restrict__ bi1, const float* __restrict__ g2,
    const float* __restrict__ b2, const float* __restrict__ m2,
    const float* __restrict__ v2, const float* __restrict__ w2,
    const float* __restrict__ bi2, float* __restrict__ gate) {
  __shared__ float cm[1024];
  __shared__ float c1[128];
  const int t = threadIdx.x;
  cm[t] = ci_mean[t];
  cm[t + 512] = ci_mean[t + 512];
  __syncthreads();
  if (t < 128) {
    int b = t >> 6, j = t & 63;
    float acc = bi1[j];
    for (int c = 0; c < 512; ++c) acc += cm[b * 512 + c] * w1[c * 64 + j];
    float sc = g2[j] * rsqrtf(v2[j] + EPS);
    c1[t] = gelu_exact((acc - m2[j]) * sc + b2[j]);
  }
  __syncthreads();
  {
    int b = t >> 8, o = t & 255;
    float acc = bi2[o];
#pragma unroll
    for (int j = 0; j < 64; ++j) acc += c1[b * 64 + j] * w2[j * 256 + o];
    gate[b * 256 + o] = 1.f / (1.f + expf(-acc));
  }
}

// ---------------------------------------------------------------------------
// Windowed attention, bf16 qkv in, f32 out. One wave per (window, head).
// ---------------------------------------------------------------------------
__global__ __launch_bounds__(64) void attn_kernel(
    const unsigned short* __restrict__ qkv, const float* __restrict__ gate,
    const float* __restrict__ rpb, const int* __restrict__ rel,
    float* __restrict__ outp) {
  __shared__ float ks[64 * 32];
  __shared__ float vs[64 * 32];
  const int bid = blockIdx.x;
  const int b_ = bid >> 3, h = bid & 7;
  const int b = b_ / 784;
  const int t = threadIdx.x;
  const float scale = 0.17677669529663687f;
  const size_t base = (size_t)(b_ * 64 + t) * 768 + h * 32;
  float qr[32];
#pragma unroll
  for (int d8 = 0; d8 < 4; ++d8) {
    uint4 qu = *(const uint4*)&qkv[base + d8 * 8];
    uint4 ku = *(const uint4*)&qkv[base + 256 + d8 * 8];
    uint4 vu = *(const uint4*)&qkv[base + 512 + d8 * 8];
    unsigned qw[4] = {qu.x, qu.y, qu.z, qu.w};
    unsigned kw[4] = {ku.x, ku.y, ku.z, ku.w};
    unsigned vw[4] = {vu.x, vu.y, vu.z, vu.w};
#pragma unroll
    for (int d = 0; d < 4; ++d) {
      int e = d8 * 8 + d * 2;
      qr[e + 0] = __uint_as_float(qw[d] << 16) * scale;
      qr[e + 1] = __uint_as_float(qw[d] & 0xffff0000u) * scale;
      ks[t * 32 + e + 0] = __uint_as_float(kw[d] << 16);
      ks[t * 32 + e + 1] = __uint_as_float(kw[d] & 0xffff0000u);
      float g0 = gate[b * 256 + h * 32 + e + 0];
      float g1 = gate[b * 256 + h * 32 + e + 1];
      vs[t * 32 + e + 0] = __uint_as_float(vw[d] << 16) * g0;
      vs[t * 32 + e + 1] = __uint_as_float(vw[d] & 0xffff0000u) * g1;
    }
  }
  __syncthreads();
  float p[64];
  float mx = -1e30f;
#pragma unroll
  for (int m = 0; m < 64; ++m) {
    float acc = rpb[rel[t * 64 + m] * 8 + h];
    const float4* km = (const float4*)&ks[m * 32];
#pragma unroll
    for (int d4 = 0; d4 < 8; ++d4) {
      float4 kv = km[d4];
      acc += qr[d4 * 4 + 0] * kv.x + qr[d4 * 4 + 1] * kv.y +
             qr[d4 * 4 + 2] * kv.z + qr[d4 * 4 + 3] * kv.w;
    }
    p[m] = acc;
    mx = fmaxf(mx, acc);
  }
  float s = 0.f;
#pragma unroll
  for (int m = 0; m < 64; ++m) {
    p[m] = __expf(p[m] - mx);
    s += p[m];
  }
  const float inv = 1.f / s;
  float o[32] = {};
#pragma unroll
  for (int m = 0; m < 64; ++m) {
    float pm = p[m] * inv;
    const float4* vm = (const float4*)&vs[m * 32];
#pragma unroll
    for (int d4 = 0; d4 < 8; ++d4) {
      float4 vv = vm[d4];
      o[d4 * 4 + 0] += pm * vv.x; o[d4 * 4 + 1] += pm * vv.y;
      o[d4 * 4 + 2] += pm * vv.z; o[d4 * 4 + 3] += pm * vv.w;
    }
  }
  const size_t ob = (size_t)(b_ * 64 + t) * 256 + h * 32;
#pragma unroll
  for (int d4 = 0; d4 < 8; ++d4) {
    float4 ov = {o[d4 * 4 + 0], o[d4 * 4 + 1], o[d4 * 4 + 2], o[d4 * 4 + 3]};
    *(float4*)&outp[ob + d4 * 4] = ov;
  }
}

// ---------------------------------------------------------------------------
// Spatial-interaction gate + BN3 + LN-out + concat -> bf16 (MROWS,512).
// ---------------------------------------------------------------------------
__global__ __launch_bounds__(256) void si_ln_concat(
    const float* __restrict__ xatt, const float* __restrict__ xpj,
    const float* __restrict__ w1, const float* __restrict__ bi1,
    const float* __restrict__ g4, const float* __restrict__ b4v,
    const float* __restrict__ m4, const float* __restrict__ v4,
    const float* __restrict__ w2, const float* __restrict__ bi2,
    const float* __restrict__ g3, const float* __restrict__ b3v,
    const float* __restrict__ m3, const float* __restrict__ v3,
    const float* __restrict__ glno, const float* __restrict__ blno,
    unsigned short* __restrict__ outc) {
  __shared__ float xr[16 * 256];
  __shared__ float s1s[16 * 64];
  __shared__ float sig[16];
  const int t = threadIdx.x;
  const int row0 = blockIdx.x * 16;
#pragma unroll
  for (int i = 0; i < 4; ++i) {
    int idx = i * 256 + t;
    int pr = idx >> 6, pc = (idx & 63) * 4;
    *(float4*)&xr[pr * 256 + pc] = *(const float4*)&xatt[(size_t)(row0 + pr) * 256 + pc];
  }
  __syncthreads();
  {
    const int j = t & 63, pg = t >> 6;
    float acc[4];
    const float bj = bi1[j];
#pragma unroll
    for (int i = 0; i < 4; ++i) acc[i] = bj;
    for (int cc = 0; cc < 256; ++cc) {
      float wv = w1[cc * 64 + j];
#pragma unroll
      for (int i = 0; i < 4; ++i) acc[i] += xr[(pg * 4 + i) * 256 + cc] * wv;
    }
    const float sc4 = g4[j] * rsqrtf(v4[j] + EPS);
    const float m4j = m4[j], b4j = b4v[j];
#pragma unroll
    for (int i = 0; i < 4; ++i)
      s1s[(pg * 4 + i) * 64 + j] = gelu_exact((acc[i] - m4j) * sc4 + b4j);
  }
  __syncthreads();
  if (t < 16) {
    float a2 = bi2[0];
#pragma unroll
    for (int jj = 0; jj < 64; ++jj) a2 += s1s[t * 64 + jj] * w2[jj];
    sig[t] = 1.f / (1.f + expf(-a2));
  }
  __syncthreads();
  {
    const int p = t >> 4, l = t & 15;
    float4 v4s[4];
    float s = 0.f, sq = 0.f;
#pragma unroll
    for (int cq = 0; cq < 4; ++cq) {
      float4 x4 = *(const float4*)&xr[p * 256 + cq * 64 + l * 4];
      v4s[cq] = x4;
      s += x4.x + x4.y + x4.z + x4.w;
      sq += x4.x * x4.x + x4.y * x4.y + x4.z * x4.z + x4.w * x4.w;
    }
#pragma unroll
    for (int off = 8; off >= 1; off >>= 1) {
      s += __shfl_xor(s, off);
      sq += __shfl_xor(sq, off);
    }
    const float mean = s * (1.f / 256.f);
    const float var = sq * (1.f / 256.f) - mean * mean;
    const float rstd = rsqrtf(var + EPS);
    const size_t orow = (size_t)(row0 + p) * 512;
#pragma unroll
    for (int cq = 0; cq < 4; ++cq) {
      int c = cq * 64 + l * 4;
      float4 x4 = v4s[cq];
      *(ushort4*)&outc[orow + c] = make_ushort4(
          f2bf((x4.x - mean) * rstd * glno[c + 0] + blno[c + 0]),
          f2bf((x4.y - mean) * rstd * glno[c + 1] + blno[c + 1]),
          f2bf((x4.z - mean) * rstd * glno[c + 2] + blno[c + 2]),
          f2bf((x4.w - mean) * rstd * glno[c + 3] + blno[c + 3]));
    }
    const float sg = sig[p];
#pragma unroll
    for (int cq = 0; cq < 4; ++cq) {
      int c = cq * 64 + l * 4;
      float4 pv = *(const float4*)&xpj[(size_t)(row0 + p) * 256 + c];
      float sc0 = g3[c + 0] * rsqrtf(v3[c + 0] + EPS);
      float sc1 = g3[c + 1] * rsqrtf(v3[c + 1] + EPS);
      float sc2 = g3[c + 2] * rsqrtf(v3[c + 2] + EPS);
      float sc3 = g3[c + 3] * rsqrtf(v3[c + 3] + EPS);
      *(ushort4*)&outc[orow + 256 + c] = make_ushort4(
          f2bf(sg * pv.x * sc0 + (b3v[c + 0] - m3[c + 0] * sc0)),
          f2bf(sg * pv.y * sc1 + (b3v[c + 1] - m3[c + 1] * sc1)),
          f2bf(sg * pv.z * sc2 + (b3v[c + 2] - m3[c + 2] * sc2)),
          f2bf(sg * pv.w * sc3 + (b3v[c + 3] - m3[c + 3] * sc3)));
    }
  }
}

// ---------------------------------------------------------------------------
extern "C" void kernel_launch(void* const* d_in, const int* in_sizes, int n_in,
                              void* d_out, int out_size, void* d_ws, size_t ws_size,
                              hipStream_t stream) {
  const float* x     = (const float*)d_in[0];
  const float* w_pa  = (const float*)d_in[1];
  const float* b_pa  = (const float*)d_in[2];
  const float* g_lna = (const float*)d_in[3];
  const float* b_lna = (const float*)d_in[4];
  const float* w_pc  = (const float*)d_in[5];
  const float* b_pc  = (const float*)d_in[6];
  const float* g_lnc = (const float*)d_in[7];
  const float* b_lnc = (const float*)d_in[8];
  const float* dw_w  = (const float*)d_in[9];
  const float* dw_b  = (const float*)d_in[10];
  const float* g_bn1 = (const float*)d_in[11];
  const float* b_bn1 = (const float*)d_in[12];
  const float* m_bn1 = (const float*)d_in[13];
  const float* v_bn1 = (const float*)d_in[14];
  const float* ci_w1 = (const float*)d_in[15];
  const float* ci_b1 = (const float*)d_in[16];
  const float* g_bn2 = (const float*)d_in[17];
  const float* b_bn2 = (const float*)d_in[18];
  const float* m_bn2 = (const float*)d_in[19];
  const float* v_bn2 = (const float*)d_in[20];
  const float* ci_w2 = (const float*)d_in[21];
  const float* ci_b2 = (const float*)d_in[22];
  const float* pj_w  = (const float*)d_in[23];
  const float* pj_b  = (const float*)d_in[24];
  const float* g_bn3 = (const float*)d_in[25];
  const float* b_bn3 = (const float*)d_in[26];
  const float* m_bn3 = (const float*)d_in[27];
  const float* v_bn3 = (const float*)d_in[28];
  const float* w_qkv = (const float*)d_in[29];
  const float* b_qkv = (const float*)d_in[30];
  const float* si_w1 = (const float*)d_in[31];
  const float* si_b1 = (const float*)d_in[32];
  const float* g_bn4 = (const float*)d_in[33];
  const float* b_bn4 = (const float*)d_in[34];
  const float* m_bn4 = (const float*)d_in[35];
  const float* v_bn4 = (const float*)d_in[36];
  const float* si_w2 = (const float*)d_in[37];
  const float* si_b2 = (const float*)d_in[38];
  const float* g_lno = (const float*)d_in[39];
  const float* b_lno = (const float*)d_in[40];
  const float* w_out = (const float*)d_in[41];
  const float* b_out = (const float*)d_in[42];
  const float* rpb   = (const float*)d_in[43];
  const int*   rel   = (const int*)d_in[44];

  char* ws = (char*)d_ws;
  // Workspace layout (phase-aliased), ~570 MB total:
  unsigned short* XBF   = (unsigned short*)(ws + 0);            // x bf16 (M,512)
  float*          G1    = (float*)(ws + 102760448ull);          // x_att pre-LN f32 (M,256)
  unsigned short* CVBF  = (unsigned short*)(ws + 102760448ull); // conv out bf16 (M,512), aliases G1
  unsigned short* QKVBF = (unsigned short*)(ws + 0);            // qkv bf16 (M,768), aliases XBF+G1
  float*          ATT   = (float*)(ws + 154140672ull);          // attn out f32 (M,256)
  unsigned short* A1BF  = (unsigned short*)(ws + 205520896ull); // x_att LN bf16 (M,256)
  float*          G2    = (float*)(ws + 256901120ull);          // x_cnn pre-LN f32 (M,512)
  float*          PJ    = (float*)(ws + 256901120ull);          // pj out f32 (M,256), aliases G2 lo
  unsigned short* CAT   = (unsigned short*)(ws + 359661568ull); // concat bf16 (M,512)
  unsigned short* C1BF  = (unsigned short*)(ws + 462422016ull); // x_cnn LN bf16 (M,512)
  float*          CIP   = (float*)(ws + 565182464ull);          // (1568,512)
  float*          CIM   = (float*)(ws + 568393728ull);          // (2,512)
  float*          GATE  = (float*)(ws + 568397824ull);          // (2,256)
  unsigned short* WT    = (unsigned short*)(ws + 568399872ull); // weights bf16^T
  unsigned short* WpaT  = WT + 0;       // (256,512)
  unsigned short* WpcT  = WT + 131072;  // (512,512)
  unsigned short* PjT   = WT + 393216;  // (256,512)
  unsigned short* QkvT  = WT + 524288;  // (768,256)
  unsigned short* OutT  = WT + 720896;  // (512,512)

  const int M = MROWS;
  dim3 b256(256), b64(64), b512(512);

  // weight convert+transpose (tiny)
  wt_convert<<<512, b256, 0, stream>>>(w_pa, WpaT, 512, 256);
  wt_convert<<<1024, b256, 0, stream>>>(w_pc, WpcT, 512, 512);
  wt_convert<<<512, b256, 0, stream>>>(pj_w, PjT, 512, 256);
  wt_convert<<<768, b256, 0, stream>>>(w_qkv, QkvT, 256, 768);
  wt_convert<<<1024, b256, 0, stream>>>(w_out, OutT, 512, 512);
  // x -> bf16
  cvt_bf16<<<(M * 512 / 8 + 255) / 256, b256, 0, stream>>>(x, XBF, M * 512 / 8);

  // 1) x_att = LN(x @ w_pa + b_pa)
  gemm_bf16<false><<<dim3(2, M / 128), b256, 0, stream>>>(XBF, WpaT, b_pa, G1, M, 256, 512);
  ln_rows_bf<256><<<M, b64, 0, stream>>>(G1, A1BF, g_lna, b_lna);

  // 2) x_cnn = LN(x @ w_pc + b_pc)
  gemm_bf16<false><<<dim3(4, M / 128), b256, 0, stream>>>(XBF, WpcT, b_pc, G2, M, 512, 512);
  ln_rows_bf<512><<<M, b64, 0, stream>>>(G2, C1BF, g_lnc, b_lnc);

  // 3) depthwise conv + BN1 + GELU + channel sums
  dwconv_bn_gelu<<<NWIN, b256, 0, stream>>>(C1BF, dw_w, dw_b, g_bn1, b_bn1, m_bn1,
                                            v_bn1, CVBF, CIP);
  ci_reduce<<<2, b512, 0, stream>>>(CIP, CIM);
  ci_gate<<<1, b512, 0, stream>>>(CIM, ci_w1, ci_b1, g_bn2, b_bn2, m_bn2, v_bn2,
                                  ci_w2, ci_b2, GATE);

  // 4) pj GEMM (conv branch 512->256)
  gemm_bf16<false><<<dim3(2, M / 128), b256, 0, stream>>>(CVBF, PjT, pj_b, PJ, M, 256, 512);

  // 5) qkv GEMM (bf16 out)
  gemm_bf16<true><<<dim3(6, M / 128), b256, 0, stream>>>(A1BF, QkvT, b_qkv, QKVBF, M, 768, 256);

  // 6) windowed attention
  attn_kernel<<<NWIN * 8, b64, 0, stream>>>(QKVBF, GATE, rpb, rel, ATT);

  // 7) spatial gate + BN3 + LN-out + concat (bf16)
  si_ln_concat<<<M / 16, b256, 0, stream>>>(ATT, PJ, si_w1, si_b1, g_bn4, b_bn4,
                                            m_bn4, v_bn4, si_w2, si_b2, g_bn3,
                                            b_bn3, m_bn3, v_bn3, g_lno, b_lno, CAT);

  // 8) final GEMM -> d_out (f32)
  gemm_bf16<false><<<dim3(4, M / 128), b256, 0, stream>>>(CAT, OutT, b_out,
                                                          (float*)d_out, M, 512, 512);
}

// Round 3
// 1079.221 us; speedup vs baseline: 3.2792x; 1.2063x over previous
//
#include <hip/hip_runtime.h>
#include <math.h>

#define EPS 1e-5f
#define MROWS 100352        // B_ * N = 1568 * 64
#define NWIN  1568

typedef __attribute__((ext_vector_type(8))) short bf16x8;
typedef __attribute__((ext_vector_type(4))) float f32x4;

__device__ __forceinline__ unsigned short f2bf(float f) {
  unsigned u = __float_as_uint(f);
  u += 0x7fffu + ((u >> 16) & 1u);
  return (unsigned short)(u >> 16);
}
__device__ __forceinline__ float bf2f(unsigned short s) {
  return __uint_as_float(((unsigned)s) << 16);
}
__device__ __forceinline__ float gelu_exact(float x) {
  return 0.5f * x * (1.f + erff(x * 0.70710678118654752f));
}

#define GLOAD16(gp, lp)                                              \
  __builtin_amdgcn_global_load_lds(                                  \
      (const __attribute__((address_space(1))) void*)(gp),           \
      (__attribute__((address_space(3))) void*)(lp), 16, 0, 0)

// ---------------------------------------------------------------------------
// bf16 MFMA GEMM (m97 structure): C[M,N] = A[M,K](bf16) @ Bt[N,K](bf16)^T + bias
// ---------------------------------------------------------------------------
template <bool OUTBF>
__global__ __launch_bounds__(256) void gemm_bf16(
    const unsigned short* __restrict__ A, const unsigned short* __restrict__ Bt,
    const float* __restrict__ bias, void* __restrict__ Cout,
    int M, int N, int K) {
  __shared__ unsigned short As[128 * 32];
  __shared__ unsigned short Bs[128 * 32];
  const int tid = threadIdx.x;
  const int lane = tid & 63, wave = tid >> 6;
  const int wr = wave >> 1, wc = wave & 1;
  const int row0 = blockIdx.y * 128, col0 = blockIdx.x * 128;
  const int lrow = tid >> 2, loff = (tid & 3) * 8;
  f32x4 acc[4][4];
#pragma unroll
  for (int m = 0; m < 4; ++m)
#pragma unroll
    for (int n = 0; n < 4; ++n) acc[m][n] = (f32x4){0.f, 0.f, 0.f, 0.f};
  for (int k0 = 0; k0 < K; k0 += 32) {
    __syncthreads();
#pragma unroll
    for (int p = 0; p < 2; ++p) {
      int r = p * 64 + lrow;
      GLOAD16(&A[(size_t)(row0 + r) * K + k0 + loff], &As[r * 32 + loff]);
      GLOAD16(&Bt[(size_t)(col0 + r) * K + k0 + loff], &Bs[r * 32 + loff]);
    }
    __syncthreads();
    const int g8 = (lane >> 4) * 8, rl = lane & 15;
    bf16x8 af[4], bfr[4];
#pragma unroll
    for (int m = 0; m < 4; ++m)
      af[m] = *(const bf16x8*)&As[(wr * 64 + m * 16 + rl) * 32 + g8];
#pragma unroll
    for (int n = 0; n < 4; ++n)
      bfr[n] = *(const bf16x8*)&Bs[(wc * 64 + n * 16 + rl) * 32 + g8];
#pragma unroll
    for (int m = 0; m < 4; ++m)
#pragma unroll
      for (int n = 0; n < 4; ++n)
        acc[m][n] = __builtin_amdgcn_mfma_f32_16x16x32_bf16(af[m], bfr[n],
                                                            acc[m][n], 0, 0, 0);
  }
  const int crow = (lane >> 4) * 4, ccol = lane & 15;
#pragma unroll
  for (int n = 0; n < 4; ++n) {
    const int gc = col0 + wc * 64 + n * 16 + ccol;
    const float bz = bias[gc];
#pragma unroll
    for (int m = 0; m < 4; ++m) {
      const int gr0 = row0 + wr * 64 + m * 16 + crow;
#pragma unroll
      for (int r = 0; r < 4; ++r) {
        float val = acc[m][n][r] + bz;
        if constexpr (OUTBF)
          ((unsigned short*)Cout)[(size_t)(gr0 + r) * N + gc] = f2bf(val);
        else
          ((float*)Cout)[(size_t)(gr0 + r) * N + gc] = val;
      }
    }
  }
}

// Weight convert + transpose: in (K,N) f32 -> out (N,K) bf16.
__global__ __launch_bounds__(256) void wt_convert(const float* __restrict__ in,
                                                  unsigned short* __restrict__ out,
                                                  int K, int N) {
  int i = blockIdx.x * 256 + threadIdx.x;
  if (i >= K * N) return;
  int n = i / K, k = i - n * K;
  out[i] = f2bf(in[(size_t)k * N + n]);
}

__global__ __launch_bounds__(256) void cvt_bf16(const float* __restrict__ in,
                                                unsigned short* __restrict__ out,
                                                int n8) {
  int i = blockIdx.x * 256 + threadIdx.x;
  if (i >= n8) return;
  float4 a = ((const float4*)in)[i * 2];
  float4 b = ((const float4*)in)[i * 2 + 1];
  ((ushort4*)out)[i * 2] = make_ushort4(f2bf(a.x), f2bf(a.y), f2bf(a.z), f2bf(a.w));
  ((ushort4*)out)[i * 2 + 1] = make_ushort4(f2bf(b.x), f2bf(b.y), f2bf(b.z), f2bf(b.w));
}

// ---------------------------------------------------------------------------
// Row LayerNorm: bf16 in -> bf16 out. One wave per row.
// ---------------------------------------------------------------------------
template <int W>
__global__ __launch_bounds__(64) void ln_rows_bf(const unsigned short* __restrict__ in,
                                                 unsigned short* __restrict__ out,
                                                 const float* __restrict__ g,
                                                 const float* __restrict__ b) {
  const int row = blockIdx.x, t = threadIdx.x;
  constexpr int NE = W / 64;
  float v[NE];
  const size_t base = (size_t)row * W + t * NE;
#pragma unroll
  for (int c4 = 0; c4 < NE / 4; ++c4) {
    ushort4 u = *(const ushort4*)&in[base + c4 * 4];
    v[c4 * 4 + 0] = bf2f(u.x); v[c4 * 4 + 1] = bf2f(u.y);
    v[c4 * 4 + 2] = bf2f(u.z); v[c4 * 4 + 3] = bf2f(u.w);
  }
  float s = 0.f, sq = 0.f;
#pragma unroll
  for (int j = 0; j < NE; ++j) { s += v[j]; sq += v[j] * v[j]; }
#pragma unroll
  for (int off = 32; off >= 1; off >>= 1) {
    s += __shfl_xor(s, off);
    sq += __shfl_xor(sq, off);
  }
  const float mean = s * (1.f / W);
  const float var = sq * (1.f / W) - mean * mean;
  const float rstd = rsqrtf(var + EPS);
#pragma unroll
  for (int c4 = 0; c4 < NE / 4; ++c4) {
    int c = t * NE + c4 * 4;
    ushort4 o = make_ushort4(
        f2bf((v[c4 * 4 + 0] - mean) * rstd * g[c + 0] + b[c + 0]),
        f2bf((v[c4 * 4 + 1] - mean) * rstd * g[c + 1] + b[c + 1]),
        f2bf((v[c4 * 4 + 2] - mean) * rstd * g[c + 2] + b[c + 2]),
        f2bf((v[c4 * 4 + 3] - mean) * rstd * g[c + 3] + b[c + 3]));
    *(ushort4*)&out[base + c4 * 4] = o;
  }
}

// ---------------------------------------------------------------------------
// Depthwise 3x3 + BN1 + GELU (bf16 in/out) + per-window channel sums.
// ---------------------------------------------------------------------------
__global__ __launch_bounds__(256) void dwconv_bn_gelu(
    const unsigned short* __restrict__ xin, const float* __restrict__ wgt9,
    const float* __restrict__ dwb, const float* __restrict__ g1,
    const float* __restrict__ b1, const float* __restrict__ m1,
    const float* __restrict__ v1, unsigned short* __restrict__ outp,
    float* __restrict__ ci_part) {
  __shared__ float tile[100 * 128];
  const int b_ = blockIdx.x;
  const int b = b_ / 784, win = b_ % 784;
  const int wi = win / 28, wj = win % 28;
  const int h0 = wi * 8 - 1, w0 = wj * 8 - 1;
  const int tid = threadIdx.x;
  const int c = tid & 127, half = tid >> 7;
  for (int chunk = 0; chunk < 4; ++chunk) {
    const int c0 = chunk * 128;
    __syncthreads();
    for (int it = 0; it < 50; ++it) {
      int p = it * 2 + half;
      int ph = h0 + p / 10, pw = w0 + p % 10;
      float val = 0.f;
      if (ph >= 0 && ph < 224 && pw >= 0 && pw < 224) {
        int bs = b * 784 + (ph >> 3) * 28 + (pw >> 3);
        int n = ((ph & 7) << 3) | (pw & 7);
        val = bf2f(xin[(size_t)(bs * 64 + n) * 512 + c0 + c]);
      }
      tile[p * 128 + c] = val;
    }
    __syncthreads();
    float w[9];
#pragma unroll
    for (int k = 0; k < 9; ++k) w[k] = wgt9[(c0 + c) * 9 + k];
    const float scale = g1[c0 + c] * rsqrtf(v1[c0 + c] + EPS);
    const float shift = b1[c0 + c] - m1[c0 + c] * scale;
    const float bias0 = dwb[c0 + c];
    float csum = 0.f;
    for (int q = 0; q < 32; ++q) {
      int qq = half * 32 + q;
      int r = qq >> 3, cc = qq & 7;
      float acc = bias0;
#pragma unroll
      for (int dr = 0; dr < 3; ++dr)
#pragma unroll
        for (int dc = 0; dc < 3; ++dc)
          acc += tile[((r + dr) * 10 + cc + dc) * 128 + c] * w[dr * 3 + dc];
      float ge = gelu_exact(acc * scale + shift);
      outp[(size_t)(b_ * 64 + qq) * 512 + c0 + c] = f2bf(ge);
      csum += ge;
    }
    __syncthreads();
    tile[tid] = csum;
    __syncthreads();
    if (tid < 128) ci_part[(size_t)b_ * 512 + c0 + tid] = tile[tid] + tile[tid + 128];
  }
}

__global__ __launch_bounds__(512) void ci_reduce(const float* __restrict__ ci_part,
                                                 float* __restrict__ ci_mean) {
  const int b = blockIdx.x, c = threadIdx.x;
  float s = 0.f;
  for (int w = 0; w < 784; ++w) s += ci_part[(size_t)(b * 784 + w) * 512 + c];
  ci_mean[b * 512 + c] = s * (1.f / 50176.f);
}

__global__ __launch_bounds__(512) void ci_gate(
    const float* __restrict__ ci_mean, const float* __restrict__ w1,
    const float* __restrict__ bi1, const float* __restrict__ g2,
    const float* __restrict__ b2, const float* __restrict__ m2,
    const float* __restrict__ v2, const float* __restrict__ w2,
    const float* __restrict__ bi2, float* __restrict__ gate) {
  __shared__ float cm[1024];
  __shared__ float c1[128];
  const int t = threadIdx.x;
  cm[t] = ci_mean[t];
  cm[t + 512] = ci_mean[t + 512];
  __syncthreads();
  if (t < 128) {
    int b = t >> 6, j = t & 63;
    float acc = bi1[j];
    for (int c = 0; c < 512; ++c) acc += cm[b * 512 + c] * w1[c * 64 + j];
    float sc = g2[j] * rsqrtf(v2[j] + EPS);
    c1[t] = gelu_exact((acc - m2[j]) * sc + b2[j]);
  }
  __syncthreads();
  {
    int b = t >> 8, o = t & 255;
    float acc = bi2[o];
#pragma unroll
    for (int j = 0; j < 64; ++j) acc += c1[b * 64 + j] * w2[j * 256 + o];
    gate[b * 256 + o] = 1.f / (1.f + expf(-acc));
  }
}

// Precompute bias table biasf[h][n][m] = rpb[rel[n*64+m]*8+h]  (8x64x64 f32)
__global__ __launch_bounds__(256) void bias_pre(const float* __restrict__ rpb,
                                                const int* __restrict__ rel,
                                                float* __restrict__ biasf) {
  int i = blockIdx.x * 256 + threadIdx.x;
  if (i >= 4096) return;
  int r = rel[i];
#pragma unroll
  for (int h = 0; h < 8; ++h) biasf[h * 4096 + i] = rpb[r * 8 + h];
}

// ---------------------------------------------------------------------------
// MFMA windowed attention. Block = 1 window, 4 waves; wave handles 2 heads.
// S^T = K·Q^T (both fragments natural-layout, loaded direct from global);
// softmax in registers (shfl over lane-quadrants); P (bf16, normalized) and
// gated V^T staged in per-wave LDS; PV via MFMA. No block barriers needed.
// ---------------------------------------------------------------------------
__global__ __launch_bounds__(256) void attn_mfma(
    const unsigned short* __restrict__ qkv,  // (M,768) bf16
    const float* __restrict__ gate,          // (2,256)
    const float* __restrict__ biasf,         // (8,64,64) f32
    float* __restrict__ outp) {              // (M,256) f32
  __shared__ unsigned short lds[4 * (64 * 68 + 32 * 68)];  // 52224 B
  const int w = blockIdx.x;
  const int b = w / 784;
  const int tid = threadIdx.x, lane = tid & 63, wave = tid >> 6;
  unsigned short* p_lds = lds + wave * (64 * 68 + 32 * 68);
  unsigned short* vT = p_lds + 64 * 68;
  const int l15 = lane & 15, l4 = lane >> 4;
  const float scale = 0.17677669529663687f;  // 32^-0.5
  for (int hh = 0; hh < 2; ++hh) {
    const int h = wave * 2 + hh;
    // ---- stage V^T (with channel gate) into LDS: vT[d][m] = V[m][d]*g[d]
    {
      const float* gh = &gate[b * 256 + h * 32];
      const size_t vbase = ((size_t)w * 64 + lane) * 768 + 512 + h * 32;
#pragma unroll
      for (int c = 0; c < 4; ++c) {
        uint4 vv = *(const uint4*)&qkv[vbase + c * 8];
        float4 gA = *(const float4*)&gh[c * 8];
        float4 gB = *(const float4*)&gh[c * 8 + 4];
        unsigned vw[4] = {vv.x, vv.y, vv.z, vv.w};
        float gg[8] = {gA.x, gA.y, gA.z, gA.w, gB.x, gB.y, gB.z, gB.w};
#pragma unroll
        for (int j = 0; j < 4; ++j) {
          int d = c * 8 + j * 2;
          vT[(d + 0) * 68 + lane] = f2bf(__uint_as_float(vw[j] << 16) * gg[j * 2]);
          vT[(d + 1) * 68 + lane] =
              f2bf(__uint_as_float(vw[j] & 0xffff0000u) * gg[j * 2 + 1]);
        }
      }
    }
    // ---- S^T = K·Q^T : A-frag = K rows (m), B-frag = Q rows (n)
    bf16x8 kf[4], qf[4];
    const size_t qkbase = (size_t)w * 64 * 768 + h * 32 + l4 * 8;
#pragma unroll
    for (int t = 0; t < 4; ++t) {
      kf[t] = *(const bf16x8*)&qkv[qkbase + (size_t)(t * 16 + l15) * 768 + 256];
      qf[t] = *(const bf16x8*)&qkv[qkbase + (size_t)(t * 16 + l15) * 768];
    }
    f32x4 s[4][4];
#pragma unroll
    for (int mt = 0; mt < 4; ++mt)
#pragma unroll
      for (int nt = 0; nt < 4; ++nt) s[mt][nt] = (f32x4){0.f, 0.f, 0.f, 0.f};
#pragma unroll
    for (int mt = 0; mt < 4; ++mt)
#pragma unroll
      for (int nt = 0; nt < 4; ++nt)
        s[mt][nt] = __builtin_amdgcn_mfma_f32_16x16x32_bf16(kf[mt], qf[nt],
                                                            s[mt][nt], 0, 0, 0);
    // acc element (mt,nt,r): m = mt*16 + l4*4 + r ; n = nt*16 + l15
    // ---- scale + bias + softmax over m (16 regs + shfl 16/32)
    float inv_s[4];
#pragma unroll
    for (int nt = 0; nt < 4; ++nt) {
      float mx = -1e30f;
#pragma unroll
      for (int mt = 0; mt < 4; ++mt) {
        float4 b4 = *(const float4*)&biasf[(h * 64 + nt * 16 + l15) * 64 +
                                           mt * 16 + l4 * 4];
        s[mt][nt][0] = s[mt][nt][0] * scale + b4.x;
        s[mt][nt][1] = s[mt][nt][1] * scale + b4.y;
        s[mt][nt][2] = s[mt][nt][2] * scale + b4.z;
        s[mt][nt][3] = s[mt][nt][3] * scale + b4.w;
#pragma unroll
        for (int r = 0; r < 4; ++r) mx = fmaxf(mx, s[mt][nt][r]);
      }
      mx = fmaxf(mx, __shfl_xor(mx, 16));
      mx = fmaxf(mx, __shfl_xor(mx, 32));
      float sum = 0.f;
#pragma unroll
      for (int mt = 0; mt < 4; ++mt)
#pragma unroll
        for (int r = 0; r < 4; ++r) {
          float e = __expf(s[mt][nt][r] - mx);
          s[mt][nt][r] = e;
          sum += e;
        }
      sum += __shfl_xor(sum, 16);
      sum += __shfl_xor(sum, 32);
      inv_s[nt] = 1.f / sum;
    }
    // ---- write normalized P (bf16) to LDS as p_lds[n][m]
#pragma unroll
    for (int nt = 0; nt < 4; ++nt)
#pragma unroll
      for (int mt = 0; mt < 4; ++mt) {
        ushort4 pk = make_ushort4(f2bf(s[mt][nt][0] * inv_s[nt]),
                                  f2bf(s[mt][nt][1] * inv_s[nt]),
                                  f2bf(s[mt][nt][2] * inv_s[nt]),
                                  f2bf(s[mt][nt][3] * inv_s[nt]));
        *(ushort4*)&p_lds[(nt * 16 + l15) * 68 + mt * 16 + l4 * 4] = pk;
      }
    // ---- O = P·V via MFMA (A-frag = P rows n, B-frag = vT rows d)
    f32x4 o[4][2];
#pragma unroll
    for (int i = 0; i < 4; ++i)
#pragma unroll
      for (int dt = 0; dt < 2; ++dt) o[i][dt] = (f32x4){0.f, 0.f, 0.f, 0.f};
#pragma unroll
    for (int ks = 0; ks < 2; ++ks) {
      bf16x8 pa[4], vf[2];
#pragma unroll
      for (int i = 0; i < 4; ++i) {
        const unsigned short* pp = &p_lds[(i * 16 + l15) * 68 + ks * 32 + l4 * 8];
        union { bf16x8 v; ushort4 u[2]; } tmp;
        tmp.u[0] = *(const ushort4*)pp;
        tmp.u[1] = *(const ushort4*)(pp + 4);
        pa[i] = tmp.v;
      }
#pragma unroll
      for (int dt = 0; dt < 2; ++dt) {
        const unsigned short* vp = &vT[(dt * 16 + l15) * 68 + ks * 32 + l4 * 8];
        union { bf16x8 v; ushort4 u[2]; } tmp;
        tmp.u[0] = *(const ushort4*)vp;
        tmp.u[1] = *(const ushort4*)(vp + 4);
        vf[dt] = tmp.v;
      }
#pragma unroll
      for (int i = 0; i < 4; ++i)
#pragma unroll
        for (int dt = 0; dt < 2; ++dt)
          o[i][dt] = __builtin_amdgcn_mfma_f32_16x16x32_bf16(pa[i], vf[dt],
                                                             o[i][dt], 0, 0, 0);
    }
    // o[i][dt][r]: n = i*16 + l4*4 + r, d = dt*16 + l15
#pragma unroll
    for (int i = 0; i < 4; ++i)
#pragma unroll
      for (int dt = 0; dt < 2; ++dt)
#pragma unroll
        for (int r = 0; r < 4; ++r)
          outp[((size_t)w * 64 + i * 16 + l4 * 4 + r) * 256 + h * 32 +
               dt * 16 + l15] = o[i][dt][r];
  }
}

// ---------------------------------------------------------------------------
// Spatial-interaction gate + BN3 + LN-out + concat -> bf16 (MROWS,512).
// ---------------------------------------------------------------------------
__global__ __launch_bounds__(256) void si_ln_concat(
    const float* __restrict__ xatt, const float* __restrict__ xpj,
    const float* __restrict__ w1, const float* __restrict__ bi1,
    const float* __restrict__ g4, const float* __restrict__ b4v,
    const float* __restrict__ m4, const float* __restrict__ v4,
    const float* __restrict__ w2, const float* __restrict__ bi2,
    const float* __restrict__ g3, const float* __restrict__ b3v,
    const float* __restrict__ m3, const float* __restrict__ v3,
    const float* __restrict__ glno, const float* __restrict__ blno,
    unsigned short* __restrict__ outc) {
  __shared__ float xr[16 * 256];
  __shared__ float s1s[16 * 64];
  __shared__ float sig[16];
  const int t = threadIdx.x;
  const int row0 = blockIdx.x * 16;
#pragma unroll
  for (int i = 0; i < 4; ++i) {
    int idx = i * 256 + t;
    int pr = idx >> 6, pc = (idx & 63) * 4;
    *(float4*)&xr[pr * 256 + pc] = *(const float4*)&xatt[(size_t)(row0 + pr) * 256 + pc];
  }
  __syncthreads();
  {
    const int j = t & 63, pg = t >> 6;
    float acc[4];
    const float bj = bi1[j];
#pragma unroll
    for (int i = 0; i < 4; ++i) acc[i] = bj;
    for (int cc = 0; cc < 256; ++cc) {
      float wv = w1[cc * 64 + j];
#pragma unroll
      for (int i = 0; i < 4; ++i) acc[i] += xr[(pg * 4 + i) * 256 + cc] * wv;
    }
    const float sc4 = g4[j] * rsqrtf(v4[j] + EPS);
    const float m4j = m4[j], b4j = b4v[j];
#pragma unroll
    for (int i = 0; i < 4; ++i)
      s1s[(pg * 4 + i) * 64 + j] = gelu_exact((acc[i] - m4j) * sc4 + b4j);
  }
  __syncthreads();
  if (t < 16) {
    float a2 = bi2[0];
#pragma unroll
    for (int jj = 0; jj < 64; ++jj) a2 += s1s[t * 64 + jj] * w2[jj];
    sig[t] = 1.f / (1.f + expf(-a2));
  }
  __syncthreads();
  {
    const int p = t >> 4, l = t & 15;
    float4 v4s[4];
    float s = 0.f, sq = 0.f;
#pragma unroll
    for (int cq = 0; cq < 4; ++cq) {
      float4 x4 = *(const float4*)&xr[p * 256 + cq * 64 + l * 4];
      v4s[cq] = x4;
      s += x4.x + x4.y + x4.z + x4.w;
      sq += x4.x * x4.x + x4.y * x4.y + x4.z * x4.z + x4.w * x4.w;
    }
#pragma unroll
    for (int off = 8; off >= 1; off >>= 1) {
      s += __shfl_xor(s, off);
      sq += __shfl_xor(sq, off);
    }
    const float mean = s * (1.f / 256.f);
    const float var = sq * (1.f / 256.f) - mean * mean;
    const float rstd = rsqrtf(var + EPS);
    const size_t orow = (size_t)(row0 + p) * 512;
#pragma unroll
    for (int cq = 0; cq < 4; ++cq) {
      int c = cq * 64 + l * 4;
      float4 x4 = v4s[cq];
      *(ushort4*)&outc[orow + c] = make_ushort4(
          f2bf((x4.x - mean) * rstd * glno[c + 0] + blno[c + 0]),
          f2bf((x4.y - mean) * rstd * glno[c + 1] + blno[c + 1]),
          f2bf((x4.z - mean) * rstd * glno[c + 2] + blno[c + 2]),
          f2bf((x4.w - mean) * rstd * glno[c + 3] + blno[c + 3]));
    }
    const float sg = sig[p];
#pragma unroll
    for (int cq = 0; cq < 4; ++cq) {
      int c = cq * 64 + l * 4;
      float4 pv = *(const float4*)&xpj[(size_t)(row0 + p) * 256 + c];
      float sc0 = g3[c + 0] * rsqrtf(v3[c + 0] + EPS);
      float sc1 = g3[c + 1] * rsqrtf(v3[c + 1] + EPS);
      float sc2 = g3[c + 2] * rsqrtf(v3[c + 2] + EPS);
      float sc3 = g3[c + 3] * rsqrtf(v3[c + 3] + EPS);
      *(ushort4*)&outc[orow + 256 + c] = make_ushort4(
          f2bf(sg * pv.x * sc0 + (b3v[c + 0] - m3[c + 0] * sc0)),
          f2bf(sg * pv.y * sc1 + (b3v[c + 1] - m3[c + 1] * sc1)),
          f2bf(sg * pv.z * sc2 + (b3v[c + 2] - m3[c + 2] * sc2)),
          f2bf(sg * pv.w * sc3 + (b3v[c + 3] - m3[c + 3] * sc3)));
    }
  }
}

// ---------------------------------------------------------------------------
extern "C" void kernel_launch(void* const* d_in, const int* in_sizes, int n_in,
                              void* d_out, int out_size, void* d_ws, size_t ws_size,
                              hipStream_t stream) {
  const float* x     = (const float*)d_in[0];
  const float* w_pa  = (const float*)d_in[1];
  const float* b_pa  = (const float*)d_in[2];
  const float* g_lna = (const float*)d_in[3];
  const float* b_lna = (const float*)d_in[4];
  const float* w_pc  = (const float*)d_in[5];
  const float* b_pc  = (const float*)d_in[6];
  const float* g_lnc = (const float*)d_in[7];
  const float* b_lnc = (const float*)d_in[8];
  const float* dw_w  = (const float*)d_in[9];
  const float* dw_b  = (const float*)d_in[10];
  const float* g_bn1 = (const float*)d_in[11];
  const float* b_bn1 = (const float*)d_in[12];
  const float* m_bn1 = (const float*)d_in[13];
  const float* v_bn1 = (const float*)d_in[14];
  const float* ci_w1 = (const float*)d_in[15];
  const float* ci_b1 = (const float*)d_in[16];
  const float* g_bn2 = (const float*)d_in[17];
  const float* b_bn2 = (const float*)d_in[18];
  const float* m_bn2 = (const float*)d_in[19];
  const float* v_bn2 = (const float*)d_in[20];
  const float* ci_w2 = (const float*)d_in[21];
  const float* ci_b2 = (const float*)d_in[22];
  const float* pj_w  = (const float*)d_in[23];
  const float* pj_b  = (const float*)d_in[24];
  const float* g_bn3 = (const float*)d_in[25];
  const float* b_bn3 = (const float*)d_in[26];
  const float* m_bn3 = (const float*)d_in[27];
  const float* v_bn3 = (const float*)d_in[28];
  const float* w_qkv = (const float*)d_in[29];
  const float* b_qkv = (const float*)d_in[30];
  const float* si_w1 = (const float*)d_in[31];
  const float* si_b1 = (const float*)d_in[32];
  const float* g_bn4 = (const float*)d_in[33];
  const float* b_bn4 = (const float*)d_in[34];
  const float* m_bn4 = (const float*)d_in[35];
  const float* v_bn4 = (const float*)d_in[36];
  const float* si_w2 = (const float*)d_in[37];
  const float* si_b2 = (const float*)d_in[38];
  const float* g_lno = (const float*)d_in[39];
  const float* b_lno = (const float*)d_in[40];
  const float* w_out = (const float*)d_in[41];
  const float* b_out = (const float*)d_in[42];
  const float* rpb   = (const float*)d_in[43];
  const int*   rel   = (const int*)d_in[44];

  char* ws = (char*)d_ws;
  unsigned short* XBF   = (unsigned short*)(ws + 0);            // x bf16 (M,512)
  unsigned short* G1BF  = (unsigned short*)(ws + 102760448ull); // x_att pre-LN bf16 (M,256)
  unsigned short* CVBF  = (unsigned short*)(ws + 102760448ull); // conv out bf16 (M,512)
  unsigned short* QKVBF = (unsigned short*)(ws + 0);            // qkv bf16 (M,768)
  float*          ATT   = (float*)(ws + 154140672ull);          // attn out f32 (M,256)
  unsigned short* A1BF  = (unsigned short*)(ws + 205520896ull); // x_att LN bf16 (M,256)
  unsigned short* G2BF  = (unsigned short*)(ws + 256901120ull); // x_cnn pre-LN bf16 (M,512)
  float*          PJ    = (float*)(ws + 256901120ull);          // pj out f32 (M,256)
  unsigned short* CAT   = (unsigned short*)(ws + 359661568ull); // concat bf16 (M,512)
  unsigned short* C1BF  = (unsigned short*)(ws + 462422016ull); // x_cnn LN bf16 (M,512)
  float*          CIP   = (float*)(ws + 565182464ull);          // (1568,512)
  float*          BIASF = (float*)(ws + 565182464ull);          // (8,64,64) aliases CIP after use
  float*          CIM   = (float*)(ws + 568393728ull);          // (2,512)
  float*          GATE  = (float*)(ws + 568397824ull);          // (2,256)
  unsigned short* WT    = (unsigned short*)(ws + 568399872ull);
  unsigned short* WpaT  = WT + 0;       // (256,512)
  unsigned short* WpcT  = WT + 131072;  // (512,512)
  unsigned short* PjT   = WT + 393216;  // (256,512)
  unsigned short* QkvT  = WT + 524288;  // (768,256)
  unsigned short* OutT  = WT + 720896;  // (512,512)

  const int M = MROWS;
  dim3 b256(256), b64(64), b512(512);

  wt_convert<<<512, b256, 0, stream>>>(w_pa, WpaT, 512, 256);
  wt_convert<<<1024, b256, 0, stream>>>(w_pc, WpcT, 512, 512);
  wt_convert<<<512, b256, 0, stream>>>(pj_w, PjT, 512, 256);
  wt_convert<<<768, b256, 0, stream>>>(w_qkv, QkvT, 256, 768);
  wt_convert<<<1024, b256, 0, stream>>>(w_out, OutT, 512, 512);
  cvt_bf16<<<(M * 512 / 8 + 255) / 256, b256, 0, stream>>>(x, XBF, M * 512 / 8);

  // 1) x_att = LN(x @ w_pa + b_pa)
  gemm_bf16<true><<<dim3(2, M / 128), b256, 0, stream>>>(XBF, WpaT, b_pa, G1BF, M, 256, 512);
  ln_rows_bf<256><<<M, b64, 0, stream>>>(G1BF, A1BF, g_lna, b_lna);

  // 2) x_cnn = LN(x @ w_pc + b_pc)
  gemm_bf16<true><<<dim3(4, M / 128), b256, 0, stream>>>(XBF, WpcT, b_pc, G2BF, M, 512, 512);
  ln_rows_bf<512><<<M, b64, 0, stream>>>(G2BF, C1BF, g_lnc, b_lnc);

  // 3) depthwise conv + BN1 + GELU + channel sums
  dwconv_bn_gelu<<<NWIN, b256, 0, stream>>>(C1BF, dw_w, dw_b, g_bn1, b_bn1, m_bn1,
                                            v_bn1, CVBF, CIP);
  ci_reduce<<<2, b512, 0, stream>>>(CIP, CIM);
  ci_gate<<<1, b512, 0, stream>>>(CIM, ci_w1, ci_b1, g_bn2, b_bn2, m_bn2, v_bn2,
                                  ci_w2, ci_b2, GATE);
  bias_pre<<<16, b256, 0, stream>>>(rpb, rel, BIASF);  // CIP now dead

  // 4) pj GEMM (conv branch 512->256)
  gemm_bf16<false><<<dim3(2, M / 128), b256, 0, stream>>>(CVBF, PjT, pj_b, PJ, M, 256, 512);

  // 5) qkv GEMM (bf16 out)
  gemm_bf16<true><<<dim3(6, M / 128), b256, 0, stream>>>(A1BF, QkvT, b_qkv, QKVBF, M, 768, 256);

  // 6) MFMA windowed attention
  attn_mfma<<<NWIN, b256, 0, stream>>>(QKVBF, GATE, BIASF, ATT);

  // 7) spatial gate + BN3 + LN-out + concat (bf16)
  si_ln_concat<<<M / 16, b256, 0, stream>>>(ATT, PJ, si_w1, si_b1, g_bn4, b_bn4,
                                            m_bn4, v_bn4, si_w2, si_b2, g_bn3,
                                            b_bn3, m_bn3, v_bn3, g_lno, b_lno, CAT);

  // 8) final GEMM -> d_out (f32)
  gemm_bf16<false><<<dim3(4, M / 128), b256, 0, stream>>>(CAT, OutT, b_out,
                                                          (float*)d_out, M, 512, 512);
}

// Round 4
// 860.578 us; speedup vs baseline: 4.1123x; 1.2541x over previous
//
#include <hip/hip_runtime.h>
#include <math.h>

#define EPS 1e-5f
#define MROWS 100352        // B_ * N = 1568 * 64
#define NWIN  1568

typedef __attribute__((ext_vector_type(8))) short bf16x8;
typedef __attribute__((ext_vector_type(4))) float f32x4;

__device__ __forceinline__ unsigned short f2bf(float f) {
  unsigned u = __float_as_uint(f);
  u += 0x7fffu + ((u >> 16) & 1u);
  return (unsigned short)(u >> 16);
}
__device__ __forceinline__ float bf2f(unsigned short s) {
  return __uint_as_float(((unsigned)s) << 16);
}
__device__ __forceinline__ float gelu_exact(float x) {
  return 0.5f * x * (1.f + erff(x * 0.70710678118654752f));
}

#define GLOAD16(gp, lp)                                              \
  __builtin_amdgcn_global_load_lds(                                  \
      (const __attribute__((address_space(1))) void*)(gp),           \
      (__attribute__((address_space(3))) void*)(lp), 16, 0, 0)

// ---------------------------------------------------------------------------
// bf16 MFMA GEMM: C[M,N] = A[M,K](bf16) @ Bt[N,K](bf16)^T + bias
// ---------------------------------------------------------------------------
template <bool OUTBF>
__global__ __launch_bounds__(256) void gemm_bf16(
    const unsigned short* __restrict__ A, const unsigned short* __restrict__ Bt,
    const float* __restrict__ bias, void* __restrict__ Cout,
    int M, int N, int K) {
  __shared__ unsigned short As[128 * 32];
  __shared__ unsigned short Bs[128 * 32];
  const int tid = threadIdx.x;
  const int lane = tid & 63, wave = tid >> 6;
  const int wr = wave >> 1, wc = wave & 1;
  const int row0 = blockIdx.y * 128, col0 = blockIdx.x * 128;
  const int lrow = tid >> 2, loff = (tid & 3) * 8;
  f32x4 acc[4][4];
#pragma unroll
  for (int m = 0; m < 4; ++m)
#pragma unroll
    for (int n = 0; n < 4; ++n) acc[m][n] = (f32x4){0.f, 0.f, 0.f, 0.f};
  for (int k0 = 0; k0 < K; k0 += 32) {
    __syncthreads();
#pragma unroll
    for (int p = 0; p < 2; ++p) {
      int r = p * 64 + lrow;
      GLOAD16(&A[(size_t)(row0 + r) * K + k0 + loff], &As[r * 32 + loff]);
      GLOAD16(&Bt[(size_t)(col0 + r) * K + k0 + loff], &Bs[r * 32 + loff]);
    }
    __syncthreads();
    const int g8 = (lane >> 4) * 8, rl = lane & 15;
    bf16x8 af[4], bfr[4];
#pragma unroll
    for (int m = 0; m < 4; ++m)
      af[m] = *(const bf16x8*)&As[(wr * 64 + m * 16 + rl) * 32 + g8];
#pragma unroll
    for (int n = 0; n < 4; ++n)
      bfr[n] = *(const bf16x8*)&Bs[(wc * 64 + n * 16 + rl) * 32 + g8];
#pragma unroll
    for (int m = 0; m < 4; ++m)
#pragma unroll
      for (int n = 0; n < 4; ++n)
        acc[m][n] = __builtin_amdgcn_mfma_f32_16x16x32_bf16(af[m], bfr[n],
                                                            acc[m][n], 0, 0, 0);
  }
  const int crow = (lane >> 4) * 4, ccol = lane & 15;
#pragma unroll
  for (int n = 0; n < 4; ++n) {
    const int gc = col0 + wc * 64 + n * 16 + ccol;
    const float bz = bias[gc];
#pragma unroll
    for (int m = 0; m < 4; ++m) {
      const int gr0 = row0 + wr * 64 + m * 16 + crow;
#pragma unroll
      for (int r = 0; r < 4; ++r) {
        float val = acc[m][n][r] + bz;
        if constexpr (OUTBF)
          ((unsigned short*)Cout)[(size_t)(gr0 + r) * N + gc] = f2bf(val);
        else
          ((float*)Cout)[(size_t)(gr0 + r) * N + gc] = val;
      }
    }
  }
}

// ---------------------------------------------------------------------------
// Same GEMM but A is f32 in global (converted to bf16 during reg-staging).
// Output bf16. Used for the fused pa+pc input GEMM (N=768) reading x directly.
// ---------------------------------------------------------------------------
__global__ __launch_bounds__(256) void gemm_f32a(
    const float* __restrict__ A, const unsigned short* __restrict__ Bt,
    const float* __restrict__ bias, unsigned short* __restrict__ Cout,
    int M, int N, int K) {
  __shared__ unsigned short As[128 * 32];
  __shared__ unsigned short Bs[128 * 32];
  const int tid = threadIdx.x;
  const int lane = tid & 63, wave = tid >> 6;
  const int wr = wave >> 1, wc = wave & 1;
  const int row0 = blockIdx.y * 128, col0 = blockIdx.x * 128;
  const int lrow = tid >> 2, loff = (tid & 3) * 8;  // B loader
  const int ar = tid >> 1, ac = (tid & 1) * 16;     // A loader
  f32x4 acc[4][4];
#pragma unroll
  for (int m = 0; m < 4; ++m)
#pragma unroll
    for (int n = 0; n < 4; ++n) acc[m][n] = (f32x4){0.f, 0.f, 0.f, 0.f};
  for (int k0 = 0; k0 < K; k0 += 32) {
    float4 f[4];
#pragma unroll
    for (int i = 0; i < 4; ++i)
      f[i] = *(const float4*)&A[(size_t)(row0 + ar) * K + k0 + ac + i * 4];
    __syncthreads();
#pragma unroll
    for (int p = 0; p < 2; ++p) {
      int r = p * 64 + lrow;
      GLOAD16(&Bt[(size_t)(col0 + r) * K + k0 + loff], &Bs[r * 32 + loff]);
    }
#pragma unroll
    for (int i = 0; i < 4; ++i) {
      ushort4 u = make_ushort4(f2bf(f[i].x), f2bf(f[i].y), f2bf(f[i].z), f2bf(f[i].w));
      *(ushort4*)&As[ar * 32 + ac + i * 4] = u;
    }
    __syncthreads();
    const int g8 = (lane >> 4) * 8, rl = lane & 15;
    bf16x8 af[4], bfr[4];
#pragma unroll
    for (int m = 0; m < 4; ++m)
      af[m] = *(const bf16x8*)&As[(wr * 64 + m * 16 + rl) * 32 + g8];
#pragma unroll
    for (int n = 0; n < 4; ++n)
      bfr[n] = *(const bf16x8*)&Bs[(wc * 64 + n * 16 + rl) * 32 + g8];
#pragma unroll
    for (int m = 0; m < 4; ++m)
#pragma unroll
      for (int n = 0; n < 4; ++n)
        acc[m][n] = __builtin_amdgcn_mfma_f32_16x16x32_bf16(af[m], bfr[n],
                                                            acc[m][n], 0, 0, 0);
  }
  const int crow = (lane >> 4) * 4, ccol = lane & 15;
#pragma unroll
  for (int n = 0; n < 4; ++n) {
    const int gc = col0 + wc * 64 + n * 16 + ccol;
    const float bz = bias[gc];
#pragma unroll
    for (int m = 0; m < 4; ++m) {
      const int gr0 = row0 + wr * 64 + m * 16 + crow;
#pragma unroll
      for (int r = 0; r < 4; ++r)
        Cout[(size_t)(gr0 + r) * N + gc] = f2bf(acc[m][n][r] + bz);
    }
  }
}

// Weight convert + transpose: in (K,N) f32 -> out (N,K) bf16.
__global__ __launch_bounds__(256) void wt_convert(const float* __restrict__ in,
                                                  unsigned short* __restrict__ out,
                                                  int K, int N) {
  int i = blockIdx.x * 256 + threadIdx.x;
  if (i >= K * N) return;
  int n = i / K, k = i - n * K;
  out[i] = f2bf(in[(size_t)k * N + n]);
}

__global__ __launch_bounds__(256) void pack_bias(const float* __restrict__ b_pa,
                                                 const float* __restrict__ b_pc,
                                                 float* __restrict__ out) {
  int t = blockIdx.x * 256 + threadIdx.x;
  if (t < 256) out[t] = b_pa[t];
  else if (t < 768) out[t] = b_pc[t - 256];
}

// ---------------------------------------------------------------------------
// Row LayerNorm, strided bf16 in -> compact bf16 out. 4 rows/block (1/wave).
// ---------------------------------------------------------------------------
template <int W>
__global__ __launch_bounds__(256) void ln_rows_bf(
    const unsigned short* __restrict__ in, int istride,
    unsigned short* __restrict__ out,
    const float* __restrict__ g, const float* __restrict__ b) {
  const int row = blockIdx.x * 4 + (threadIdx.x >> 6);
  const int t = threadIdx.x & 63;
  constexpr int NE = W / 64;
  float v[NE];
  const size_t ibase = (size_t)row * istride + t * NE;
  const size_t obase = (size_t)row * W + t * NE;
#pragma unroll
  for (int c4 = 0; c4 < NE / 4; ++c4) {
    ushort4 u = *(const ushort4*)&in[ibase + c4 * 4];
    v[c4 * 4 + 0] = bf2f(u.x); v[c4 * 4 + 1] = bf2f(u.y);
    v[c4 * 4 + 2] = bf2f(u.z); v[c4 * 4 + 3] = bf2f(u.w);
  }
  float s = 0.f, sq = 0.f;
#pragma unroll
  for (int j = 0; j < NE; ++j) { s += v[j]; sq += v[j] * v[j]; }
#pragma unroll
  for (int off = 32; off >= 1; off >>= 1) {
    s += __shfl_xor(s, off);
    sq += __shfl_xor(sq, off);
  }
  const float mean = s * (1.f / W);
  const float var = sq * (1.f / W) - mean * mean;
  const float rstd = rsqrtf(var + EPS);
#pragma unroll
  for (int c4 = 0; c4 < NE / 4; ++c4) {
    int c = t * NE + c4 * 4;
    ushort4 o = make_ushort4(
        f2bf((v[c4 * 4 + 0] - mean) * rstd * g[c + 0] + b[c + 0]),
        f2bf((v[c4 * 4 + 1] - mean) * rstd * g[c + 1] + b[c + 1]),
        f2bf((v[c4 * 4 + 2] - mean) * rstd * g[c + 2] + b[c + 2]),
        f2bf((v[c4 * 4 + 3] - mean) * rstd * g[c + 3] + b[c + 3]));
    *(ushort4*)&out[obase + c4 * 4] = o;
  }
}

// ---------------------------------------------------------------------------
// Depthwise 3x3 + BN1 + GELU, bf16 LDS tile, vectorized staging.
// Block = 1 window; 4 chunks of 128 ch; thread = 4 ch x 8 px.
// ---------------------------------------------------------------------------
__global__ __launch_bounds__(256) void dwconv_bn_gelu(
    const unsigned short* __restrict__ xin, const float* __restrict__ wgt9,
    const float* __restrict__ dwb, const float* __restrict__ g1,
    const float* __restrict__ b1, const float* __restrict__ m1,
    const float* __restrict__ v1, unsigned short* __restrict__ outp,
    float* __restrict__ ci_part) {
  __shared__ unsigned short tile[100 * 128];  // 25.6 KB
  __shared__ float psum[8 * 128];             // 4 KB
  const int b_ = blockIdx.x;
  const int b = b_ / 784, win = b_ % 784;
  const int wi = win / 28, wj = win % 28;
  const int h0 = wi * 8 - 1, w0 = wj * 8 - 1;
  const int tid = threadIdx.x;
  const int c4 = (tid & 31) * 4;  // 4 channels
  const int pg = tid >> 5;        // 8 pixel-groups of 8 pixels
  for (int chunk = 0; chunk < 4; ++chunk) {
    const int c0 = chunk * 128;
    __syncthreads();
    // stage 100 px x 128 ch bf16, 16B per thread-iter
#pragma unroll
    for (int it = 0; it < 7; ++it) {
      int idx = it * 256 + tid;
      if (idx < 1600) {
        int p = idx >> 4;
        int ch8 = (idx & 15) * 8;
        int ph = h0 + p / 10, pw = w0 + p % 10;
        uint4 val = {0u, 0u, 0u, 0u};
        if (ph >= 0 && ph < 224 && pw >= 0 && pw < 224) {
          int bs = b * 784 + (ph >> 3) * 28 + (pw >> 3);
          int n = ((ph & 7) << 3) | (pw & 7);
          val = *(const uint4*)&xin[(size_t)(bs * 64 + n) * 512 + c0 + ch8];
        }
        *(uint4*)&tile[p * 128 + ch8] = val;
      }
    }
    __syncthreads();
    float wreg[9][4];
    float scale[4], shift[4], bias0[4];
#pragma unroll
    for (int j = 0; j < 4; ++j) {
      int cc = c0 + c4 + j;
#pragma unroll
      for (int k = 0; k < 9; ++k) wreg[k][j] = wgt9[cc * 9 + k];
      scale[j] = g1[cc] * rsqrtf(v1[cc] + EPS);
      shift[j] = b1[cc] - m1[cc] * scale[j];
      bias0[j] = dwb[cc];
    }
    float cs0 = 0.f, cs1 = 0.f, cs2 = 0.f, cs3 = 0.f;
    for (int q = 0; q < 8; ++q) {
      const int qq = pg * 8 + q;
      const int r = qq >> 3, cc_ = qq & 7;
      float a0 = bias0[0], a1 = bias0[1], a2 = bias0[2], a3 = bias0[3];
#pragma unroll
      for (int dr = 0; dr < 3; ++dr)
#pragma unroll
        for (int dc = 0; dc < 3; ++dc) {
          ushort4 u = *(const ushort4*)&tile[((r + dr) * 10 + cc_ + dc) * 128 + c4];
          const int k = dr * 3 + dc;
          a0 += bf2f(u.x) * wreg[k][0];
          a1 += bf2f(u.y) * wreg[k][1];
          a2 += bf2f(u.z) * wreg[k][2];
          a3 += bf2f(u.w) * wreg[k][3];
        }
      float g0 = gelu_exact(a0 * scale[0] + shift[0]);
      float g1v = gelu_exact(a1 * scale[1] + shift[1]);
      float g2v = gelu_exact(a2 * scale[2] + shift[2]);
      float g3v = gelu_exact(a3 * scale[3] + shift[3]);
      cs0 += g0; cs1 += g1v; cs2 += g2v; cs3 += g3v;
      *(ushort4*)&outp[(size_t)(b_ * 64 + qq) * 512 + c0 + c4] =
          make_ushort4(f2bf(g0), f2bf(g1v), f2bf(g2v), f2bf(g3v));
    }
    *(float4*)&psum[pg * 128 + c4] = make_float4(cs0, cs1, cs2, cs3);
    __syncthreads();
    if (tid < 128) {
      float s = 0.f;
#pragma unroll
      for (int g = 0; g < 8; ++g) s += psum[g * 128 + tid];
      ci_part[(size_t)b_ * 512 + c0 + tid] = s;
    }
  }
}

__global__ __launch_bounds__(512) void ci_reduce(const float* __restrict__ ci_part,
                                                 float* __restrict__ ci_mean) {
  const int b = blockIdx.x, c = threadIdx.x;
  float s = 0.f;
  for (int w = 0; w < 784; ++w) s += ci_part[(size_t)(b * 784 + w) * 512 + c];
  ci_mean[b * 512 + c] = s * (1.f / 50176.f);
}

__global__ __launch_bounds__(512) void ci_gate(
    const float* __restrict__ ci_mean, const float* __restrict__ w1,
    const float* __restrict__ bi1, const float* __restrict__ g2,
    const float* __restrict__ b2, const float* __restrict__ m2,
    const float* __restrict__ v2, const float* __restrict__ w2,
    const float* __restrict__ bi2, float* __restrict__ gate) {
  __shared__ float cm[1024];
  __shared__ float c1[128];
  const int t = threadIdx.x;
  cm[t] = ci_mean[t];
  cm[t + 512] = ci_mean[t + 512];
  __syncthreads();
  if (t < 128) {
    int b = t >> 6, j = t & 63;
    float acc = bi1[j];
    for (int c = 0; c < 512; ++c) acc += cm[b * 512 + c] * w1[c * 64 + j];
    float sc = g2[j] * rsqrtf(v2[j] + EPS);
    c1[t] = gelu_exact((acc - m2[j]) * sc + b2[j]);
  }
  __syncthreads();
  {
    int b = t >> 8, o = t & 255;
    float acc = bi2[o];
#pragma unroll
    for (int j = 0; j < 64; ++j) acc += c1[b * 64 + j] * w2[j * 256 + o];
    gate[b * 256 + o] = 1.f / (1.f + expf(-acc));
  }
}

// Precompute bias table biasf[h][n][m] = rpb[rel[n*64+m]*8+h]
__global__ __launch_bounds__(256) void bias_pre(const float* __restrict__ rpb,
                                                const int* __restrict__ rel,
                                                float* __restrict__ biasf) {
  int i = blockIdx.x * 256 + threadIdx.x;
  if (i >= 4096) return;
  int r = rel[i];
#pragma unroll
  for (int h = 0; h < 8; ++h) biasf[h * 4096 + i] = rpb[r * 8 + h];
}

// ---------------------------------------------------------------------------
// MFMA windowed attention (bf16 out). Block = 1 window, 4 waves x 2 heads.
// ---------------------------------------------------------------------------
__global__ __launch_bounds__(256) void attn_mfma(
    const unsigned short* __restrict__ qkv,  // (M,768) bf16
    const float* __restrict__ gate,          // (2,256)
    const float* __restrict__ biasf,         // (8,64,64) f32
    unsigned short* __restrict__ outp) {     // (M,256) bf16
  __shared__ unsigned short lds[4 * (64 * 68 + 32 * 68)];
  const int w = blockIdx.x;
  const int b = w / 784;
  const int tid = threadIdx.x, lane = tid & 63, wave = tid >> 6;
  unsigned short* p_lds = lds + wave * (64 * 68 + 32 * 68);
  unsigned short* vT = p_lds + 64 * 68;
  const int l15 = lane & 15, l4 = lane >> 4;
  const float scale = 0.17677669529663687f;
  for (int hh = 0; hh < 2; ++hh) {
    const int h = wave * 2 + hh;
    {
      const float* gh = &gate[b * 256 + h * 32];
      const size_t vbase = ((size_t)w * 64 + lane) * 768 + 512 + h * 32;
#pragma unroll
      for (int c = 0; c < 4; ++c) {
        uint4 vv = *(const uint4*)&qkv[vbase + c * 8];
        float4 gA = *(const float4*)&gh[c * 8];
        float4 gB = *(const float4*)&gh[c * 8 + 4];
        unsigned vw[4] = {vv.x, vv.y, vv.z, vv.w};
        float gg[8] = {gA.x, gA.y, gA.z, gA.w, gB.x, gB.y, gB.z, gB.w};
#pragma unroll
        for (int j = 0; j < 4; ++j) {
          int d = c * 8 + j * 2;
          vT[(d + 0) * 68 + lane] = f2bf(__uint_as_float(vw[j] << 16) * gg[j * 2]);
          vT[(d + 1) * 68 + lane] =
              f2bf(__uint_as_float(vw[j] & 0xffff0000u) * gg[j * 2 + 1]);
        }
      }
    }
    bf16x8 kf[4], qf[4];
    const size_t qkbase = (size_t)w * 64 * 768 + h * 32 + l4 * 8;
#pragma unroll
    for (int t = 0; t < 4; ++t) {
      kf[t] = *(const bf16x8*)&qkv[qkbase + (size_t)(t * 16 + l15) * 768 + 256];
      qf[t] = *(const bf16x8*)&qkv[qkbase + (size_t)(t * 16 + l15) * 768];
    }
    f32x4 s[4][4];
#pragma unroll
    for (int mt = 0; mt < 4; ++mt)
#pragma unroll
      for (int nt = 0; nt < 4; ++nt) s[mt][nt] = (f32x4){0.f, 0.f, 0.f, 0.f};
#pragma unroll
    for (int mt = 0; mt < 4; ++mt)
#pragma unroll
      for (int nt = 0; nt < 4; ++nt)
        s[mt][nt] = __builtin_amdgcn_mfma_f32_16x16x32_bf16(kf[mt], qf[nt],
                                                            s[mt][nt], 0, 0, 0);
    float inv_s[4];
#pragma unroll
    for (int nt = 0; nt < 4; ++nt) {
      float mx = -1e30f;
#pragma unroll
      for (int mt = 0; mt < 4; ++mt) {
        float4 b4 = *(const float4*)&biasf[(h * 64 + nt * 16 + l15) * 64 +
                                           mt * 16 + l4 * 4];
        s[mt][nt][0] = s[mt][nt][0] * scale + b4.x;
        s[mt][nt][1] = s[mt][nt][1] * scale + b4.y;
        s[mt][nt][2] = s[mt][nt][2] * scale + b4.z;
        s[mt][nt][3] = s[mt][nt][3] * scale + b4.w;
#pragma unroll
        for (int r = 0; r < 4; ++r) mx = fmaxf(mx, s[mt][nt][r]);
      }
      mx = fmaxf(mx, __shfl_xor(mx, 16));
      mx = fmaxf(mx, __shfl_xor(mx, 32));
      float sum = 0.f;
#pragma unroll
      for (int mt = 0; mt < 4; ++mt)
#pragma unroll
        for (int r = 0; r < 4; ++r) {
          float e = __expf(s[mt][nt][r] - mx);
          s[mt][nt][r] = e;
          sum += e;
        }
      sum += __shfl_xor(sum, 16);
      sum += __shfl_xor(sum, 32);
      inv_s[nt] = 1.f / sum;
    }
#pragma unroll
    for (int nt = 0; nt < 4; ++nt)
#pragma unroll
      for (int mt = 0; mt < 4; ++mt) {
        ushort4 pk = make_ushort4(f2bf(s[mt][nt][0] * inv_s[nt]),
                                  f2bf(s[mt][nt][1] * inv_s[nt]),
                                  f2bf(s[mt][nt][2] * inv_s[nt]),
                                  f2bf(s[mt][nt][3] * inv_s[nt]));
        *(ushort4*)&p_lds[(nt * 16 + l15) * 68 + mt * 16 + l4 * 4] = pk;
      }
    f32x4 o[4][2];
#pragma unroll
    for (int i = 0; i < 4; ++i)
#pragma unroll
      for (int dt = 0; dt < 2; ++dt) o[i][dt] = (f32x4){0.f, 0.f, 0.f, 0.f};
#pragma unroll
    for (int ks = 0; ks < 2; ++ks) {
      bf16x8 pa[4], vf[2];
#pragma unroll
      for (int i = 0; i < 4; ++i) {
        const unsigned short* pp = &p_lds[(i * 16 + l15) * 68 + ks * 32 + l4 * 8];
        union { bf16x8 v; ushort4 u[2]; } tmp;
        tmp.u[0] = *(const ushort4*)pp;
        tmp.u[1] = *(const ushort4*)(pp + 4);
        pa[i] = tmp.v;
      }
#pragma unroll
      for (int dt = 0; dt < 2; ++dt) {
        const unsigned short* vp = &vT[(dt * 16 + l15) * 68 + ks * 32 + l4 * 8];
        union { bf16x8 v; ushort4 u[2]; } tmp;
        tmp.u[0] = *(const ushort4*)vp;
        tmp.u[1] = *(const ushort4*)(vp + 4);
        vf[dt] = tmp.v;
      }
#pragma unroll
      for (int i = 0; i < 4; ++i)
#pragma unroll
        for (int dt = 0; dt < 2; ++dt)
          o[i][dt] = __builtin_amdgcn_mfma_f32_16x16x32_bf16(pa[i], vf[dt],
                                                             o[i][dt], 0, 0, 0);
    }
#pragma unroll
    for (int i = 0; i < 4; ++i)
#pragma unroll
      for (int dt = 0; dt < 2; ++dt)
#pragma unroll
        for (int r = 0; r < 4; ++r)
          outp[((size_t)w * 64 + i * 16 + l4 * 4 + r) * 256 + h * 32 +
               dt * 16 + l15] = f2bf(o[i][dt][r]);
  }
}

// ---------------------------------------------------------------------------
// Spatial gate + BN3 + LN-out + concat (bf16 in, bf16 out).
// ---------------------------------------------------------------------------
__global__ __launch_bounds__(256) void si_ln_concat(
    const unsigned short* __restrict__ xatt, const unsigned short* __restrict__ xpj,
    const float* __restrict__ w1, const float* __restrict__ bi1,
    const float* __restrict__ g4, const float* __restrict__ b4v,
    const float* __restrict__ m4, const float* __restrict__ v4,
    const float* __restrict__ w2, const float* __restrict__ bi2,
    const float* __restrict__ g3, const float* __restrict__ b3v,
    const float* __restrict__ m3, const float* __restrict__ v3,
    const float* __restrict__ glno, const float* __restrict__ blno,
    unsigned short* __restrict__ outc) {
  __shared__ float xr[16 * 256];
  __shared__ float s1s[16 * 64];
  __shared__ float sig[16];
  const int t = threadIdx.x;
  const int row0 = blockIdx.x * 16;
#pragma unroll
  for (int i = 0; i < 2; ++i) {
    int idx = i * 256 + t;
    int pr = idx >> 5, pc = (idx & 31) * 8;
    const unsigned short* src = &xatt[(size_t)(row0 + pr) * 256 + pc];
    ushort4 a = *(const ushort4*)src;
    ushort4 c = *(const ushort4*)(src + 4);
    float* dst = &xr[pr * 256 + pc];
    dst[0] = bf2f(a.x); dst[1] = bf2f(a.y); dst[2] = bf2f(a.z); dst[3] = bf2f(a.w);
    dst[4] = bf2f(c.x); dst[5] = bf2f(c.y); dst[6] = bf2f(c.z); dst[7] = bf2f(c.w);
  }
  __syncthreads();
  {
    const int j = t & 63, pg = t >> 6;
    float acc[4];
    const float bj = bi1[j];
#pragma unroll
    for (int i = 0; i < 4; ++i) acc[i] = bj;
    for (int cc = 0; cc < 256; ++cc) {
      float wv = w1[cc * 64 + j];
#pragma unroll
      for (int i = 0; i < 4; ++i) acc[i] += xr[(pg * 4 + i) * 256 + cc] * wv;
    }
    const float sc4 = g4[j] * rsqrtf(v4[j] + EPS);
    const float m4j = m4[j], b4j = b4v[j];
#pragma unroll
    for (int i = 0; i < 4; ++i)
      s1s[(pg * 4 + i) * 64 + j] = gelu_exact((acc[i] - m4j) * sc4 + b4j);
  }
  __syncthreads();
  if (t < 16) {
    float a2 = bi2[0];
#pragma unroll
    for (int jj = 0; jj < 64; ++jj) a2 += s1s[t * 64 + jj] * w2[jj];
    sig[t] = 1.f / (1.f + expf(-a2));
  }
  __syncthreads();
  {
    const int p = t >> 4, l = t & 15;
    float4 v4s[4];
    float s = 0.f, sq = 0.f;
#pragma unroll
    for (int cq = 0; cq < 4; ++cq) {
      float4 x4 = *(const float4*)&xr[p * 256 + cq * 64 + l * 4];
      v4s[cq] = x4;
      s += x4.x + x4.y + x4.z + x4.w;
      sq += x4.x * x4.x + x4.y * x4.y + x4.z * x4.z + x4.w * x4.w;
    }
#pragma unroll
    for (int off = 8; off >= 1; off >>= 1) {
      s += __shfl_xor(s, off);
      sq += __shfl_xor(sq, off);
    }
    const float mean = s * (1.f / 256.f);
    const float var = sq * (1.f / 256.f) - mean * mean;
    const float rstd = rsqrtf(var + EPS);
    const size_t orow = (size_t)(row0 + p) * 512;
#pragma unroll
    for (int cq = 0; cq < 4; ++cq) {
      int c = cq * 64 + l * 4;
      float4 x4 = v4s[cq];
      *(ushort4*)&outc[orow + c] = make_ushort4(
          f2bf((x4.x - mean) * rstd * glno[c + 0] + blno[c + 0]),
          f2bf((x4.y - mean) * rstd * glno[c + 1] + blno[c + 1]),
          f2bf((x4.z - mean) * rstd * glno[c + 2] + blno[c + 2]),
          f2bf((x4.w - mean) * rstd * glno[c + 3] + blno[c + 3]));
    }
    const float sg = sig[p];
#pragma unroll
    for (int cq = 0; cq < 4; ++cq) {
      int c = cq * 64 + l * 4;
      ushort4 pu = *(const ushort4*)&xpj[(size_t)(row0 + p) * 256 + c];
      float px = bf2f(pu.x), py = bf2f(pu.y), pz = bf2f(pu.z), pw = bf2f(pu.w);
      float sc0 = g3[c + 0] * rsqrtf(v3[c + 0] + EPS);
      float sc1 = g3[c + 1] * rsqrtf(v3[c + 1] + EPS);
      float sc2 = g3[c + 2] * rsqrtf(v3[c + 2] + EPS);
      float sc3 = g3[c + 3] * rsqrtf(v3[c + 3] + EPS);
      *(ushort4*)&outc[orow + 256 + c] = make_ushort4(
          f2bf(sg * px * sc0 + (b3v[c + 0] - m3[c + 0] * sc0)),
          f2bf(sg * py * sc1 + (b3v[c + 1] - m3[c + 1] * sc1)),
          f2bf(sg * pz * sc2 + (b3v[c + 2] - m3[c + 2] * sc2)),
          f2bf(sg * pw * sc3 + (b3v[c + 3] - m3[c + 3] * sc3)));
    }
  }
}

// ---------------------------------------------------------------------------
extern "C" void kernel_launch(void* const* d_in, const int* in_sizes, int n_in,
                              void* d_out, int out_size, void* d_ws, size_t ws_size,
                              hipStream_t stream) {
  const float* x     = (const float*)d_in[0];
  const float* w_pa  = (const float*)d_in[1];
  const float* b_pa  = (const float*)d_in[2];
  const float* g_lna = (const float*)d_in[3];
  const float* b_lna = (const float*)d_in[4];
  const float* w_pc  = (const float*)d_in[5];
  const float* b_pc  = (const float*)d_in[6];
  const float* g_lnc = (const float*)d_in[7];
  const float* b_lnc = (const float*)d_in[8];
  const float* dw_w  = (const float*)d_in[9];
  const float* dw_b  = (const float*)d_in[10];
  const float* g_bn1 = (const float*)d_in[11];
  const float* b_bn1 = (const float*)d_in[12];
  const float* m_bn1 = (const float*)d_in[13];
  const float* v_bn1 = (const float*)d_in[14];
  const float* ci_w1 = (const float*)d_in[15];
  const float* ci_b1 = (const float*)d_in[16];
  const float* g_bn2 = (const float*)d_in[17];
  const float* b_bn2 = (const float*)d_in[18];
  const float* m_bn2 = (const float*)d_in[19];
  const float* v_bn2 = (const float*)d_in[20];
  const float* ci_w2 = (const float*)d_in[21];
  const float* ci_b2 = (const float*)d_in[22];
  const float* pj_w  = (const float*)d_in[23];
  const float* pj_b  = (const float*)d_in[24];
  const float* g_bn3 = (const float*)d_in[25];
  const float* b_bn3 = (const float*)d_in[26];
  const float* m_bn3 = (const float*)d_in[27];
  const float* v_bn3 = (const float*)d_in[28];
  const float* w_qkv = (const float*)d_in[29];
  const float* b_qkv = (const float*)d_in[30];
  const float* si_w1 = (const float*)d_in[31];
  const float* si_b1 = (const float*)d_in[32];
  const float* g_bn4 = (const float*)d_in[33];
  const float* b_bn4 = (const float*)d_in[34];
  const float* m_bn4 = (const float*)d_in[35];
  const float* v_bn4 = (const float*)d_in[36];
  const float* si_w2 = (const float*)d_in[37];
  const float* si_b2 = (const float*)d_in[38];
  const float* g_lno = (const float*)d_in[39];
  const float* b_lno = (const float*)d_in[40];
  const float* w_out = (const float*)d_in[41];
  const float* b_out = (const float*)d_in[42];
  const float* rpb   = (const float*)d_in[43];
  const int*   rel   = (const int*)d_in[44];

  char* ws = (char*)d_ws;
  // Phase-aliased workspace (~468 MB):
  unsigned short* G12BF = (unsigned short*)(ws + 0);            // (M,768) fused pre-LN
  unsigned short* QKVBF = (unsigned short*)(ws + 0);            // (M,768), after G12 dead
  unsigned short* A1BF  = (unsigned short*)(ws + 154140672ull); // (M,256) x_att LN
  unsigned short* ATTBF = (unsigned short*)(ws + 154140672ull); // (M,256), after A1 dead
  unsigned short* C1BF  = (unsigned short*)(ws + 205520896ull); // (M,512) x_cnn LN
  unsigned short* CAT   = (unsigned short*)(ws + 205520896ull); // (M,512), after C1 dead
  unsigned short* CVBF  = (unsigned short*)(ws + 308281344ull); // (M,512) conv out
  unsigned short* PJBF  = (unsigned short*)(ws + 411041792ull); // (M,256) pj out
  float*          CIP   = (float*)(ws + 462422016ull);          // (1568,512)
  float*          CIM   = (float*)(ws + 465633280ull);          // (2,512)
  float*          GATE  = (float*)(ws + 465637376ull);          // (2,256)
  float*          B12   = (float*)(ws + 465639424ull);          // (768)
  float*          BIASF = (float*)(ws + 465642496ull);          // (8,64,64)
  unsigned short* WT    = (unsigned short*)(ws + 465773568ull);
  unsigned short* WpaT  = WT + 0;       // (256,512)  -- contiguous with WpcT
  unsigned short* WpcT  = WT + 131072;  // (512,512)
  unsigned short* PjT   = WT + 393216;  // (256,512)
  unsigned short* QkvT  = WT + 524288;  // (768,256)
  unsigned short* OutT  = WT + 720896;  // (512,512)

  const int M = MROWS;
  dim3 b256(256), b512(512);

  wt_convert<<<512, b256, 0, stream>>>(w_pa, WpaT, 512, 256);
  wt_convert<<<1024, b256, 0, stream>>>(w_pc, WpcT, 512, 512);
  wt_convert<<<512, b256, 0, stream>>>(pj_w, PjT, 512, 256);
  wt_convert<<<768, b256, 0, stream>>>(w_qkv, QkvT, 256, 768);
  wt_convert<<<1024, b256, 0, stream>>>(w_out, OutT, 512, 512);
  pack_bias<<<3, b256, 0, stream>>>(b_pa, b_pc, B12);

  // 1+2) fused input GEMM (f32 A): [x@w_pa | x@w_pc] -> G12BF (M,768)
  gemm_f32a<<<dim3(6, M / 128), b256, 0, stream>>>(x, WpaT, B12, G12BF, M, 768, 512);
  ln_rows_bf<256><<<M / 4, b256, 0, stream>>>(G12BF, 768, A1BF, g_lna, b_lna);
  ln_rows_bf<512><<<M / 4, b256, 0, stream>>>(G12BF + 256, 768, C1BF, g_lnc, b_lnc);

  // 3) depthwise conv + BN1 + GELU + channel sums
  dwconv_bn_gelu<<<NWIN, b256, 0, stream>>>(C1BF, dw_w, dw_b, g_bn1, b_bn1, m_bn1,
                                            v_bn1, CVBF, CIP);
  ci_reduce<<<2, b512, 0, stream>>>(CIP, CIM);
  ci_gate<<<1, b512, 0, stream>>>(CIM, ci_w1, ci_b1, g_bn2, b_bn2, m_bn2, v_bn2,
                                  ci_w2, ci_b2, GATE);
  bias_pre<<<16, b256, 0, stream>>>(rpb, rel, BIASF);

  // 4) pj GEMM (bf16 out)
  gemm_bf16<true><<<dim3(2, M / 128), b256, 0, stream>>>(CVBF, PjT, pj_b, PJBF, M, 256, 512);

  // 5) qkv GEMM (bf16 out, overlays dead G12BF)
  gemm_bf16<true><<<dim3(6, M / 128), b256, 0, stream>>>(A1BF, QkvT, b_qkv, QKVBF, M, 768, 256);

  // 6) MFMA windowed attention (bf16 out, overlays dead A1BF)
  attn_mfma<<<NWIN, b256, 0, stream>>>(QKVBF, GATE, BIASF, ATTBF);

  // 7) spatial gate + BN3 + LN-out + concat (overlays dead C1BF)
  si_ln_concat<<<M / 16, b256, 0, stream>>>(ATTBF, PJBF, si_w1, si_b1, g_bn4, b_bn4,
                                            m_bn4, v_bn4, si_w2, si_b2, g_bn3,
                                            b_bn3, m_bn3, v_bn3, g_lno, b_lno, CAT);

  // 8) final GEMM -> d_out (f32)
  gemm_bf16<false><<<dim3(4, M / 128), b256, 0, stream>>>(CAT, OutT, b_out,
                                                          (float*)d_out, M, 512, 512);
}

// Round 5
// 853.825 us; speedup vs baseline: 4.1448x; 1.0079x over previous
//
#include <hip/hip_runtime.h>
#include <math.h>

#define EPS 1e-5f
#define MROWS 100352        // B_ * N = 1568 * 64
#define NWIN  1568

typedef __attribute__((ext_vector_type(8))) short bf16x8;
typedef __attribute__((ext_vector_type(4))) float f32x4;

__device__ __forceinline__ unsigned short f2bf(float f) {
  unsigned u = __float_as_uint(f);
  u += 0x7fffu + ((u >> 16) & 1u);
  return (unsigned short)(u >> 16);
}
__device__ __forceinline__ float bf2f(unsigned short s) {
  return __uint_as_float(((unsigned)s) << 16);
}
__device__ __forceinline__ float gelu_exact(float x) {
  return 0.5f * x * (1.f + erff(x * 0.70710678118654752f));
}

#define GLOAD16(gp, lp)                                              \
  __builtin_amdgcn_global_load_lds(                                  \
      (const __attribute__((address_space(1))) void*)(gp),           \
      (__attribute__((address_space(3))) void*)(lp), 16, 0, 0)

// XCD-aware chunked swizzle (requires nwg % 8 == 0; guarded otherwise).
// Sibling blocks (same row panel, consecutive bx) become adjacent on one XCD
// so the A row-panel is fetched once into that XCD's L2.
__device__ __forceinline__ void xcd_map(int& bx, int& by) {
  const int nwg = gridDim.x * gridDim.y;
  int n = blockIdx.y * gridDim.x + blockIdx.x;
  int w = n;
  if ((nwg & 7) == 0) w = (n & 7) * (nwg >> 3) + (n >> 3);
  by = w / gridDim.x;
  bx = w - by * gridDim.x;
}

// ---------------------------------------------------------------------------
// bf16 MFMA GEMM: C[M,N] = A[M,K](bf16) @ Bt[N,K](bf16)^T + bias
// ---------------------------------------------------------------------------
template <bool OUTBF>
__global__ __launch_bounds__(256) void gemm_bf16(
    const unsigned short* __restrict__ A, const unsigned short* __restrict__ Bt,
    const float* __restrict__ bias, void* __restrict__ Cout,
    int M, int N, int K) {
  __shared__ unsigned short As[128 * 32];
  __shared__ unsigned short Bs[128 * 32];
  const int tid = threadIdx.x;
  const int lane = tid & 63, wave = tid >> 6;
  const int wr = wave >> 1, wc = wave & 1;
  int bx, by;
  xcd_map(bx, by);
  const int row0 = by * 128, col0 = bx * 128;
  const int lrow = tid >> 2, loff = (tid & 3) * 8;
  f32x4 acc[4][4];
#pragma unroll
  for (int m = 0; m < 4; ++m)
#pragma unroll
    for (int n = 0; n < 4; ++n) acc[m][n] = (f32x4){0.f, 0.f, 0.f, 0.f};
  for (int k0 = 0; k0 < K; k0 += 32) {
    __syncthreads();
#pragma unroll
    for (int p = 0; p < 2; ++p) {
      int r = p * 64 + lrow;
      GLOAD16(&A[(size_t)(row0 + r) * K + k0 + loff], &As[r * 32 + loff]);
      GLOAD16(&Bt[(size_t)(col0 + r) * K + k0 + loff], &Bs[r * 32 + loff]);
    }
    __syncthreads();
    const int g8 = (lane >> 4) * 8, rl = lane & 15;
    bf16x8 af[4], bfr[4];
#pragma unroll
    for (int m = 0; m < 4; ++m)
      af[m] = *(const bf16x8*)&As[(wr * 64 + m * 16 + rl) * 32 + g8];
#pragma unroll
    for (int n = 0; n < 4; ++n)
      bfr[n] = *(const bf16x8*)&Bs[(wc * 64 + n * 16 + rl) * 32 + g8];
#pragma unroll
    for (int m = 0; m < 4; ++m)
#pragma unroll
      for (int n = 0; n < 4; ++n)
        acc[m][n] = __builtin_amdgcn_mfma_f32_16x16x32_bf16(af[m], bfr[n],
                                                            acc[m][n], 0, 0, 0);
  }
  const int crow = (lane >> 4) * 4, ccol = lane & 15;
#pragma unroll
  for (int n = 0; n < 4; ++n) {
    const int gc = col0 + wc * 64 + n * 16 + ccol;
    const float bz = bias[gc];
#pragma unroll
    for (int m = 0; m < 4; ++m) {
      const int gr0 = row0 + wr * 64 + m * 16 + crow;
#pragma unroll
      for (int r = 0; r < 4; ++r) {
        float val = acc[m][n][r] + bz;
        if constexpr (OUTBF)
          ((unsigned short*)Cout)[(size_t)(gr0 + r) * N + gc] = f2bf(val);
        else
          ((float*)Cout)[(size_t)(gr0 + r) * N + gc] = val;
      }
    }
  }
}

// ---------------------------------------------------------------------------
// Same GEMM but A is f32 in global (converted to bf16 via v_cvt_pk_bf16_f32
// during reg-staging). Output bf16. Used for the fused pa+pc input GEMM.
// ---------------------------------------------------------------------------
__global__ __launch_bounds__(256) void gemm_f32a(
    const float* __restrict__ A, const unsigned short* __restrict__ Bt,
    const float* __restrict__ bias, unsigned short* __restrict__ Cout,
    int M, int N, int K) {
  __shared__ unsigned short As[128 * 32];
  __shared__ unsigned short Bs[128 * 32];
  const int tid = threadIdx.x;
  const int lane = tid & 63, wave = tid >> 6;
  const int wr = wave >> 1, wc = wave & 1;
  int bx, by;
  xcd_map(bx, by);
  const int row0 = by * 128, col0 = bx * 128;
  const int lrow = tid >> 2, loff = (tid & 3) * 8;  // B loader
  const int ar = tid >> 1, ac = (tid & 1) * 16;     // A loader
  f32x4 acc[4][4];
#pragma unroll
  for (int m = 0; m < 4; ++m)
#pragma unroll
    for (int n = 0; n < 4; ++n) acc[m][n] = (f32x4){0.f, 0.f, 0.f, 0.f};
  for (int k0 = 0; k0 < K; k0 += 32) {
    float4 f[4];
#pragma unroll
    for (int i = 0; i < 4; ++i)
      f[i] = *(const float4*)&A[(size_t)(row0 + ar) * K + k0 + ac + i * 4];
    __syncthreads();
#pragma unroll
    for (int p = 0; p < 2; ++p) {
      int r = p * 64 + lrow;
      GLOAD16(&Bt[(size_t)(col0 + r) * K + k0 + loff], &Bs[r * 32 + loff]);
    }
#pragma unroll
    for (int i = 0; i < 4; ++i) {
      unsigned p0, p1;
      asm("v_cvt_pk_bf16_f32 %0, %1, %2" : "=v"(p0) : "v"(f[i].x), "v"(f[i].y));
      asm("v_cvt_pk_bf16_f32 %0, %1, %2" : "=v"(p1) : "v"(f[i].z), "v"(f[i].w));
      *(uint2*)&As[ar * 32 + ac + i * 4] = make_uint2(p0, p1);
    }
    __syncthreads();
    const int g8 = (lane >> 4) * 8, rl = lane & 15;
    bf16x8 af[4], bfr[4];
#pragma unroll
    for (int m = 0; m < 4; ++m)
      af[m] = *(const bf16x8*)&As[(wr * 64 + m * 16 + rl) * 32 + g8];
#pragma unroll
    for (int n = 0; n < 4; ++n)
      bfr[n] = *(const bf16x8*)&Bs[(wc * 64 + n * 16 + rl) * 32 + g8];
#pragma unroll
    for (int m = 0; m < 4; ++m)
#pragma unroll
      for (int n = 0; n < 4; ++n)
        acc[m][n] = __builtin_amdgcn_mfma_f32_16x16x32_bf16(af[m], bfr[n],
                                                            acc[m][n], 0, 0, 0);
  }
  const int crow = (lane >> 4) * 4, ccol = lane & 15;
#pragma unroll
  for (int n = 0; n < 4; ++n) {
    const int gc = col0 + wc * 64 + n * 16 + ccol;
    const float bz = bias[gc];
#pragma unroll
    for (int m = 0; m < 4; ++m) {
      const int gr0 = row0 + wr * 64 + m * 16 + crow;
#pragma unroll
      for (int r = 0; r < 4; ++r)
        Cout[(size_t)(gr0 + r) * N + gc] = f2bf(acc[m][n][r] + bz);
    }
  }
}

// Weight convert + transpose: in (K,N) f32 -> out (N,K) bf16.
__global__ __launch_bounds__(256) void wt_convert(const float* __restrict__ in,
                                                  unsigned short* __restrict__ out,
                                                  int K, int N) {
  int i = blockIdx.x * 256 + threadIdx.x;
  if (i >= K * N) return;
  int n = i / K, k = i - n * K;
  out[i] = f2bf(in[(size_t)k * N + n]);
}

__global__ __launch_bounds__(256) void pack_bias(const float* __restrict__ b_pa,
                                                 const float* __restrict__ b_pc,
                                                 float* __restrict__ out) {
  int t = blockIdx.x * 256 + threadIdx.x;
  if (t < 256) out[t] = b_pa[t];
  else if (t < 768) out[t] = b_pc[t - 256];
}

// ---------------------------------------------------------------------------
// Row LayerNorm, strided bf16 in -> compact bf16 out. 4 rows/block (1/wave).
// ---------------------------------------------------------------------------
template <int W>
__global__ __launch_bounds__(256) void ln_rows_bf(
    const unsigned short* __restrict__ in, int istride,
    unsigned short* __restrict__ out,
    const float* __restrict__ g, const float* __restrict__ b) {
  const int row = blockIdx.x * 4 + (threadIdx.x >> 6);
  const int t = threadIdx.x & 63;
  constexpr int NE = W / 64;
  float v[NE];
  const size_t ibase = (size_t)row * istride + t * NE;
  const size_t obase = (size_t)row * W + t * NE;
#pragma unroll
  for (int c4 = 0; c4 < NE / 4; ++c4) {
    ushort4 u = *(const ushort4*)&in[ibase + c4 * 4];
    v[c4 * 4 + 0] = bf2f(u.x); v[c4 * 4 + 1] = bf2f(u.y);
    v[c4 * 4 + 2] = bf2f(u.z); v[c4 * 4 + 3] = bf2f(u.w);
  }
  float s = 0.f, sq = 0.f;
#pragma unroll
  for (int j = 0; j < NE; ++j) { s += v[j]; sq += v[j] * v[j]; }
#pragma unroll
  for (int off = 32; off >= 1; off >>= 1) {
    s += __shfl_xor(s, off);
    sq += __shfl_xor(sq, off);
  }
  const float mean = s * (1.f / W);
  const float var = sq * (1.f / W) - mean * mean;
  const float rstd = rsqrtf(var + EPS);
#pragma unroll
  for (int c4 = 0; c4 < NE / 4; ++c4) {
    int c = t * NE + c4 * 4;
    ushort4 o = make_ushort4(
        f2bf((v[c4 * 4 + 0] - mean) * rstd * g[c + 0] + b[c + 0]),
        f2bf((v[c4 * 4 + 1] - mean) * rstd * g[c + 1] + b[c + 1]),
        f2bf((v[c4 * 4 + 2] - mean) * rstd * g[c + 2] + b[c + 2]),
        f2bf((v[c4 * 4 + 3] - mean) * rstd * g[c + 3] + b[c + 3]));
    *(ushort4*)&out[obase + c4 * 4] = o;
  }
}

// ---------------------------------------------------------------------------
// Depthwise 3x3 + BN1 + GELU, bf16 LDS tile, vectorized staging.
// ---------------------------------------------------------------------------
__global__ __launch_bounds__(256) void dwconv_bn_gelu(
    const unsigned short* __restrict__ xin, const float* __restrict__ wgt9,
    const float* __restrict__ dwb, const float* __restrict__ g1,
    const float* __restrict__ b1, const float* __restrict__ m1,
    const float* __restrict__ v1, unsigned short* __restrict__ outp,
    float* __restrict__ ci_part) {
  __shared__ unsigned short tile[100 * 128];  // 25.6 KB
  __shared__ float psum[8 * 128];             // 4 KB
  const int b_ = blockIdx.x;
  const int b = b_ / 784, win = b_ % 784;
  const int wi = win / 28, wj = win % 28;
  const int h0 = wi * 8 - 1, w0 = wj * 8 - 1;
  const int tid = threadIdx.x;
  const int c4 = (tid & 31) * 4;
  const int pg = tid >> 5;
  for (int chunk = 0; chunk < 4; ++chunk) {
    const int c0 = chunk * 128;
    __syncthreads();
#pragma unroll
    for (int it = 0; it < 7; ++it) {
      int idx = it * 256 + tid;
      if (idx < 1600) {
        int p = idx >> 4;
        int ch8 = (idx & 15) * 8;
        int ph = h0 + p / 10, pw = w0 + p % 10;
        uint4 val = {0u, 0u, 0u, 0u};
        if (ph >= 0 && ph < 224 && pw >= 0 && pw < 224) {
          int bs = b * 784 + (ph >> 3) * 28 + (pw >> 3);
          int n = ((ph & 7) << 3) | (pw & 7);
          val = *(const uint4*)&xin[(size_t)(bs * 64 + n) * 512 + c0 + ch8];
        }
        *(uint4*)&tile[p * 128 + ch8] = val;
      }
    }
    __syncthreads();
    float wreg[9][4];
    float scale[4], shift[4], bias0[4];
#pragma unroll
    for (int j = 0; j < 4; ++j) {
      int cc = c0 + c4 + j;
#pragma unroll
      for (int k = 0; k < 9; ++k) wreg[k][j] = wgt9[cc * 9 + k];
      scale[j] = g1[cc] * rsqrtf(v1[cc] + EPS);
      shift[j] = b1[cc] - m1[cc] * scale[j];
      bias0[j] = dwb[cc];
    }
    float cs0 = 0.f, cs1 = 0.f, cs2 = 0.f, cs3 = 0.f;
    for (int q = 0; q < 8; ++q) {
      const int qq = pg * 8 + q;
      const int r = qq >> 3, cc_ = qq & 7;
      float a0 = bias0[0], a1 = bias0[1], a2 = bias0[2], a3 = bias0[3];
#pragma unroll
      for (int dr = 0; dr < 3; ++dr)
#pragma unroll
        for (int dc = 0; dc < 3; ++dc) {
          ushort4 u = *(const ushort4*)&tile[((r + dr) * 10 + cc_ + dc) * 128 + c4];
          const int k = dr * 3 + dc;
          a0 += bf2f(u.x) * wreg[k][0];
          a1 += bf2f(u.y) * wreg[k][1];
          a2 += bf2f(u.z) * wreg[k][2];
          a3 += bf2f(u.w) * wreg[k][3];
        }
      float g0 = gelu_exact(a0 * scale[0] + shift[0]);
      float g1v = gelu_exact(a1 * scale[1] + shift[1]);
      float g2v = gelu_exact(a2 * scale[2] + shift[2]);
      float g3v = gelu_exact(a3 * scale[3] + shift[3]);
      cs0 += g0; cs1 += g1v; cs2 += g2v; cs3 += g3v;
      *(ushort4*)&outp[(size_t)(b_ * 64 + qq) * 512 + c0 + c4] =
          make_ushort4(f2bf(g0), f2bf(g1v), f2bf(g2v), f2bf(g3v));
    }
    *(float4*)&psum[pg * 128 + c4] = make_float4(cs0, cs1, cs2, cs3);
    __syncthreads();
    if (tid < 128) {
      float s = 0.f;
#pragma unroll
      for (int g = 0; g < 8; ++g) s += psum[g * 128 + tid];
      ci_part[(size_t)b_ * 512 + c0 + tid] = s;
    }
  }
}

__global__ __launch_bounds__(512) void ci_reduce(const float* __restrict__ ci_part,
                                                 float* __restrict__ ci_mean) {
  const int b = blockIdx.x, c = threadIdx.x;
  float s = 0.f;
  for (int w = 0; w < 784; ++w) s += ci_part[(size_t)(b * 784 + w) * 512 + c];
  ci_mean[b * 512 + c] = s * (1.f / 50176.f);
}

__global__ __launch_bounds__(512) void ci_gate(
    const float* __restrict__ ci_mean, const float* __restrict__ w1,
    const float* __restrict__ bi1, const float* __restrict__ g2,
    const float* __restrict__ b2, const float* __restrict__ m2,
    const float* __restrict__ v2, const float* __restrict__ w2,
    const float* __restrict__ bi2, float* __restrict__ gate) {
  __shared__ float cm[1024];
  __shared__ float c1[128];
  const int t = threadIdx.x;
  cm[t] = ci_mean[t];
  cm[t + 512] = ci_mean[t + 512];
  __syncthreads();
  if (t < 128) {
    int b = t >> 6, j = t & 63;
    float acc = bi1[j];
    for (int c = 0; c < 512; ++c) acc += cm[b * 512 + c] * w1[c * 64 + j];
    float sc = g2[j] * rsqrtf(v2[j] + EPS);
    c1[t] = gelu_exact((acc - m2[j]) * sc + b2[j]);
  }
  __syncthreads();
  {
    int b = t >> 8, o = t & 255;
    float acc = bi2[o];
#pragma unroll
    for (int j = 0; j < 64; ++j) acc += c1[b * 64 + j] * w2[j * 256 + o];
    gate[b * 256 + o] = 1.f / (1.f + expf(-acc));
  }
}

// Precompute bias table biasf[h][n][m] = rpb[rel[n*64+m]*8+h]
__global__ __launch_bounds__(256) void bias_pre(const float* __restrict__ rpb,
                                                const int* __restrict__ rel,
                                                float* __restrict__ biasf) {
  int i = blockIdx.x * 256 + threadIdx.x;
  if (i >= 4096) return;
  int r = rel[i];
#pragma unroll
  for (int h = 0; h < 8; ++h) biasf[h * 4096 + i] = rpb[r * 8 + h];
}

// ---------------------------------------------------------------------------
// MFMA windowed attention (bf16 out). Block = 1 window, 4 waves x 2 heads.
// ---------------------------------------------------------------------------
__global__ __launch_bounds__(256) void attn_mfma(
    const unsigned short* __restrict__ qkv,  // (M,768) bf16
    const float* __restrict__ gate,          // (2,256)
    const float* __restrict__ biasf,         // (8,64,64) f32
    unsigned short* __restrict__ outp) {     // (M,256) bf16
  __shared__ unsigned short lds[4 * (64 * 68 + 32 * 68)];
  const int w = blockIdx.x;
  const int b = w / 784;
  const int tid = threadIdx.x, lane = tid & 63, wave = tid >> 6;
  unsigned short* p_lds = lds + wave * (64 * 68 + 32 * 68);
  unsigned short* vT = p_lds + 64 * 68;
  const int l15 = lane & 15, l4 = lane >> 4;
  const float scale = 0.17677669529663687f;
  for (int hh = 0; hh < 2; ++hh) {
    const int h = wave * 2 + hh;
    {
      const float* gh = &gate[b * 256 + h * 32];
      const size_t vbase = ((size_t)w * 64 + lane) * 768 + 512 + h * 32;
#pragma unroll
      for (int c = 0; c < 4; ++c) {
        uint4 vv = *(const uint4*)&qkv[vbase + c * 8];
        float4 gA = *(const float4*)&gh[c * 8];
        float4 gB = *(const float4*)&gh[c * 8 + 4];
        unsigned vw[4] = {vv.x, vv.y, vv.z, vv.w};
        float gg[8] = {gA.x, gA.y, gA.z, gA.w, gB.x, gB.y, gB.z, gB.w};
#pragma unroll
        for (int j = 0; j < 4; ++j) {
          int d = c * 8 + j * 2;
          vT[(d + 0) * 68 + lane] = f2bf(__uint_as_float(vw[j] << 16) * gg[j * 2]);
          vT[(d + 1) * 68 + lane] =
              f2bf(__uint_as_float(vw[j] & 0xffff0000u) * gg[j * 2 + 1]);
        }
      }
    }
    bf16x8 kf[4], qf[4];
    const size_t qkbase = (size_t)w * 64 * 768 + h * 32 + l4 * 8;
#pragma unroll
    for (int t = 0; t < 4; ++t) {
      kf[t] = *(const bf16x8*)&qkv[qkbase + (size_t)(t * 16 + l15) * 768 + 256];
      qf[t] = *(const bf16x8*)&qkv[qkbase + (size_t)(t * 16 + l15) * 768];
    }
    f32x4 s[4][4];
#pragma unroll
    for (int mt = 0; mt < 4; ++mt)
#pragma unroll
      for (int nt = 0; nt < 4; ++nt) s[mt][nt] = (f32x4){0.f, 0.f, 0.f, 0.f};
#pragma unroll
    for (int mt = 0; mt < 4; ++mt)
#pragma unroll
      for (int nt = 0; nt < 4; ++nt)
        s[mt][nt] = __builtin_amdgcn_mfma_f32_16x16x32_bf16(kf[mt], qf[nt],
                                                            s[mt][nt], 0, 0, 0);
    float inv_s[4];
#pragma unroll
    for (int nt = 0; nt < 4; ++nt) {
      float mx = -1e30f;
#pragma unroll
      for (int mt = 0; mt < 4; ++mt) {
        float4 b4 = *(const float4*)&biasf[(h * 64 + nt * 16 + l15) * 64 +
                                           mt * 16 + l4 * 4];
        s[mt][nt][0] = s[mt][nt][0] * scale + b4.x;
        s[mt][nt][1] = s[mt][nt][1] * scale + b4.y;
        s[mt][nt][2] = s[mt][nt][2] * scale + b4.z;
        s[mt][nt][3] = s[mt][nt][3] * scale + b4.w;
#pragma unroll
        for (int r = 0; r < 4; ++r) mx = fmaxf(mx, s[mt][nt][r]);
      }
      mx = fmaxf(mx, __shfl_xor(mx, 16));
      mx = fmaxf(mx, __shfl_xor(mx, 32));
      float sum = 0.f;
#pragma unroll
      for (int mt = 0; mt < 4; ++mt)
#pragma unroll
        for (int r = 0; r < 4; ++r) {
          float e = __expf(s[mt][nt][r] - mx);
          s[mt][nt][r] = e;
          sum += e;
        }
      sum += __shfl_xor(sum, 16);
      sum += __shfl_xor(sum, 32);
      inv_s[nt] = 1.f / sum;
    }
#pragma unroll
    for (int nt = 0; nt < 4; ++nt)
#pragma unroll
      for (int mt = 0; mt < 4; ++mt) {
        ushort4 pk = make_ushort4(f2bf(s[mt][nt][0] * inv_s[nt]),
                                  f2bf(s[mt][nt][1] * inv_s[nt]),
                                  f2bf(s[mt][nt][2] * inv_s[nt]),
                                  f2bf(s[mt][nt][3] * inv_s[nt]));
        *(ushort4*)&p_lds[(nt * 16 + l15) * 68 + mt * 16 + l4 * 4] = pk;
      }
    f32x4 o[4][2];
#pragma unroll
    for (int i = 0; i < 4; ++i)
#pragma unroll
      for (int dt = 0; dt < 2; ++dt) o[i][dt] = (f32x4){0.f, 0.f, 0.f, 0.f};
#pragma unroll
    for (int ks = 0; ks < 2; ++ks) {
      bf16x8 pa[4], vf[2];
#pragma unroll
      for (int i = 0; i < 4; ++i) {
        const unsigned short* pp = &p_lds[(i * 16 + l15) * 68 + ks * 32 + l4 * 8];
        union { bf16x8 v; ushort4 u[2]; } tmp;
        tmp.u[0] = *(const ushort4*)pp;
        tmp.u[1] = *(const ushort4*)(pp + 4);
        pa[i] = tmp.v;
      }
#pragma unroll
      for (int dt = 0; dt < 2; ++dt) {
        const unsigned short* vp = &vT[(dt * 16 + l15) * 68 + ks * 32 + l4 * 8];
        union { bf16x8 v; ushort4 u[2]; } tmp;
        tmp.u[0] = *(const ushort4*)vp;
        tmp.u[1] = *(const ushort4*)(vp + 4);
        vf[dt] = tmp.v;
      }
#pragma unroll
      for (int i = 0; i < 4; ++i)
#pragma unroll
        for (int dt = 0; dt < 2; ++dt)
          o[i][dt] = __builtin_amdgcn_mfma_f32_16x16x32_bf16(pa[i], vf[dt],
                                                             o[i][dt], 0, 0, 0);
    }
#pragma unroll
    for (int i = 0; i < 4; ++i)
#pragma unroll
      for (int dt = 0; dt < 2; ++dt)
#pragma unroll
        for (int r = 0; r < 4; ++r)
          outp[((size_t)w * 64 + i * 16 + l4 * 4 + r) * 256 + h * 32 +
               dt * 16 + l15] = f2bf(o[i][dt][r]);
  }
}

// ---------------------------------------------------------------------------
// Spatial gate + BN3 + LN-out + concat (bf16 in, bf16 out).
// ---------------------------------------------------------------------------
__global__ __launch_bounds__(256) void si_ln_concat(
    const unsigned short* __restrict__ xatt, const unsigned short* __restrict__ xpj,
    const float* __restrict__ w1, const float* __restrict__ bi1,
    const float* __restrict__ g4, const float* __restrict__ b4v,
    const float* __restrict__ m4, const float* __restrict__ v4,
    const float* __restrict__ w2, const float* __restrict__ bi2,
    const float* __restrict__ g3, const float* __restrict__ b3v,
    const float* __restrict__ m3, const float* __restrict__ v3,
    const float* __restrict__ glno, const float* __restrict__ blno,
    unsigned short* __restrict__ outc) {
  __shared__ float xr[16 * 256];
  __shared__ float s1s[16 * 64];
  __shared__ float sig[16];
  const int t = threadIdx.x;
  const int row0 = blockIdx.x * 16;
#pragma unroll
  for (int i = 0; i < 2; ++i) {
    int idx = i * 256 + t;
    int pr = idx >> 5, pc = (idx & 31) * 8;
    const unsigned short* src = &xatt[(size_t)(row0 + pr) * 256 + pc];
    ushort4 a = *(const ushort4*)src;
    ushort4 c = *(const ushort4*)(src + 4);
    float* dst = &xr[pr * 256 + pc];
    dst[0] = bf2f(a.x); dst[1] = bf2f(a.y); dst[2] = bf2f(a.z); dst[3] = bf2f(a.w);
    dst[4] = bf2f(c.x); dst[5] = bf2f(c.y); dst[6] = bf2f(c.z); dst[7] = bf2f(c.w);
  }
  __syncthreads();
  {
    const int j = t & 63, pg = t >> 6;
    float acc[4];
    const float bj = bi1[j];
#pragma unroll
    for (int i = 0; i < 4; ++i) acc[i] = bj;
    for (int cc = 0; cc < 256; ++cc) {
      float wv = w1[cc * 64 + j];
#pragma unroll
      for (int i = 0; i < 4; ++i) acc[i] += xr[(pg * 4 + i) * 256 + cc] * wv;
    }
    const float sc4 = g4[j] * rsqrtf(v4[j] + EPS);
    const float m4j = m4[j], b4j = b4v[j];
#pragma unroll
    for (int i = 0; i < 4; ++i)
      s1s[(pg * 4 + i) * 64 + j] = gelu_exact((acc[i] - m4j) * sc4 + b4j);
  }
  __syncthreads();
  if (t < 16) {
    float a2 = bi2[0];
#pragma unroll
    for (int jj = 0; jj < 64; ++jj) a2 += s1s[t * 64 + jj] * w2[jj];
    sig[t] = 1.f / (1.f + expf(-a2));
  }
  __syncthreads();
  {
    const int p = t >> 4, l = t & 15;
    float4 v4s[4];
    float s = 0.f, sq = 0.f;
#pragma unroll
    for (int cq = 0; cq < 4; ++cq) {
      float4 x4 = *(const float4*)&xr[p * 256 + cq * 64 + l * 4];
      v4s[cq] = x4;
      s += x4.x + x4.y + x4.z + x4.w;
      sq += x4.x * x4.x + x4.y * x4.y + x4.z * x4.z + x4.w * x4.w;
    }
#pragma unroll
    for (int off = 8; off >= 1; off >>= 1) {
      s += __shfl_xor(s, off);
      sq += __shfl_xor(sq, off);
    }
    const float mean = s * (1.f / 256.f);
    const float var = sq * (1.f / 256.f) - mean * mean;
    const float rstd = rsqrtf(var + EPS);
    const size_t orow = (size_t)(row0 + p) * 512;
#pragma unroll
    for (int cq = 0; cq < 4; ++cq) {
      int c = cq * 64 + l * 4;
      float4 x4 = v4s[cq];
      *(ushort4*)&outc[orow + c] = make_ushort4(
          f2bf((x4.x - mean) * rstd * glno[c + 0] + blno[c + 0]),
          f2bf((x4.y - mean) * rstd * glno[c + 1] + blno[c + 1]),
          f2bf((x4.z - mean) * rstd * glno[c + 2] + blno[c + 2]),
          f2bf((x4.w - mean) * rstd * glno[c + 3] + blno[c + 3]));
    }
    const float sg = sig[p];
#pragma unroll
    for (int cq = 0; cq < 4; ++cq) {
      int c = cq * 64 + l * 4;
      ushort4 pu = *(const ushort4*)&xpj[(size_t)(row0 + p) * 256 + c];
      float px = bf2f(pu.x), py = bf2f(pu.y), pz = bf2f(pu.z), pw = bf2f(pu.w);
      float sc0 = g3[c + 0] * rsqrtf(v3[c + 0] + EPS);
      float sc1 = g3[c + 1] * rsqrtf(v3[c + 1] + EPS);
      float sc2 = g3[c + 2] * rsqrtf(v3[c + 2] + EPS);
      float sc3 = g3[c + 3] * rsqrtf(v3[c + 3] + EPS);
      *(ushort4*)&outc[orow + 256 + c] = make_ushort4(
          f2bf(sg * px * sc0 + (b3v[c + 0] - m3[c + 0] * sc0)),
          f2bf(sg * py * sc1 + (b3v[c + 1] - m3[c + 1] * sc1)),
          f2bf(sg * pz * sc2 + (b3v[c + 2] - m3[c + 2] * sc2)),
          f2bf(sg * pw * sc3 + (b3v[c + 3] - m3[c + 3] * sc3)));
    }
  }
}

// ---------------------------------------------------------------------------
extern "C" void kernel_launch(void* const* d_in, const int* in_sizes, int n_in,
                              void* d_out, int out_size, void* d_ws, size_t ws_size,
                              hipStream_t stream) {
  const float* x     = (const float*)d_in[0];
  const float* w_pa  = (const float*)d_in[1];
  const float* b_pa  = (const float*)d_in[2];
  const float* g_lna = (const float*)d_in[3];
  const float* b_lna = (const float*)d_in[4];
  const float* w_pc  = (const float*)d_in[5];
  const float* b_pc  = (const float*)d_in[6];
  const float* g_lnc = (const float*)d_in[7];
  const float* b_lnc = (const float*)d_in[8];
  const float* dw_w  = (const float*)d_in[9];
  const float* dw_b  = (const float*)d_in[10];
  const float* g_bn1 = (const float*)d_in[11];
  const float* b_bn1 = (const float*)d_in[12];
  const float* m_bn1 = (const float*)d_in[13];
  const float* v_bn1 = (const float*)d_in[14];
  const float* ci_w1 = (const float*)d_in[15];
  const float* ci_b1 = (const float*)d_in[16];
  const float* g_bn2 = (const float*)d_in[17];
  const float* b_bn2 = (const float*)d_in[18];
  const float* m_bn2 = (const float*)d_in[19];
  const float* v_bn2 = (const float*)d_in[20];
  const float* ci_w2 = (const float*)d_in[21];
  const float* ci_b2 = (const float*)d_in[22];
  const float* pj_w  = (const float*)d_in[23];
  const float* pj_b  = (const float*)d_in[24];
  const float* g_bn3 = (const float*)d_in[25];
  const float* b_bn3 = (const float*)d_in[26];
  const float* m_bn3 = (const float*)d_in[27];
  const float* v_bn3 = (const float*)d_in[28];
  const float* w_qkv = (const float*)d_in[29];
  const float* b_qkv = (const float*)d_in[30];
  const float* si_w1 = (const float*)d_in[31];
  const float* si_b1 = (const float*)d_in[32];
  const float* g_bn4 = (const float*)d_in[33];
  const float* b_bn4 = (const float*)d_in[34];
  const float* m_bn4 = (const float*)d_in[35];
  const float* v_bn4 = (const float*)d_in[36];
  const float* si_w2 = (const float*)d_in[37];
  const float* si_b2 = (const float*)d_in[38];
  const float* g_lno = (const float*)d_in[39];
  const float* b_lno = (const float*)d_in[40];
  const float* w_out = (const float*)d_in[41];
  const float* b_out = (const float*)d_in[42];
  const float* rpb   = (const float*)d_in[43];
  const int*   rel   = (const int*)d_in[44];

  char* ws = (char*)d_ws;
  unsigned short* G12BF = (unsigned short*)(ws + 0);            // (M,768) fused pre-LN
  unsigned short* QKVBF = (unsigned short*)(ws + 0);            // (M,768)
  unsigned short* A1BF  = (unsigned short*)(ws + 154140672ull); // (M,256)
  unsigned short* ATTBF = (unsigned short*)(ws + 154140672ull); // (M,256)
  unsigned short* C1BF  = (unsigned short*)(ws + 205520896ull); // (M,512)
  unsigned short* CAT   = (unsigned short*)(ws + 205520896ull); // (M,512)
  unsigned short* CVBF  = (unsigned short*)(ws + 308281344ull); // (M,512)
  unsigned short* PJBF  = (unsigned short*)(ws + 411041792ull); // (M,256)
  float*          CIP   = (float*)(ws + 462422016ull);          // (1568,512)
  float*          CIM   = (float*)(ws + 465633280ull);          // (2,512)
  float*          GATE  = (float*)(ws + 465637376ull);          // (2,256)
  float*          B12   = (float*)(ws + 465639424ull);          // (768)
  float*          BIASF = (float*)(ws + 465642496ull);          // (8,64,64)
  unsigned short* WT    = (unsigned short*)(ws + 465773568ull);
  unsigned short* WpaT  = WT + 0;
  unsigned short* WpcT  = WT + 131072;
  unsigned short* PjT   = WT + 393216;
  unsigned short* QkvT  = WT + 524288;
  unsigned short* OutT  = WT + 720896;

  const int M = MROWS;
  dim3 b256(256), b512(512);

  wt_convert<<<512, b256, 0, stream>>>(w_pa, WpaT, 512, 256);
  wt_convert<<<1024, b256, 0, stream>>>(w_pc, WpcT, 512, 512);
  wt_convert<<<512, b256, 0, stream>>>(pj_w, PjT, 512, 256);
  wt_convert<<<768, b256, 0, stream>>>(w_qkv, QkvT, 256, 768);
  wt_convert<<<1024, b256, 0, stream>>>(w_out, OutT, 512, 512);
  pack_bias<<<3, b256, 0, stream>>>(b_pa, b_pc, B12);

  // 1+2) fused input GEMM (f32 A): [x@w_pa | x@w_pc] -> G12BF (M,768)
  gemm_f32a<<<dim3(6, M / 128), b256, 0, stream>>>(x, WpaT, B12, G12BF, M, 768, 512);
  ln_rows_bf<256><<<M / 4, b256, 0, stream>>>(G12BF, 768, A1BF, g_lna, b_lna);
  ln_rows_bf<512><<<M / 4, b256, 0, stream>>>(G12BF + 256, 768, C1BF, g_lnc, b_lnc);

  // 3) depthwise conv + BN1 + GELU + channel sums
  dwconv_bn_gelu<<<NWIN, b256, 0, stream>>>(C1BF, dw_w, dw_b, g_bn1, b_bn1, m_bn1,
                                            v_bn1, CVBF, CIP);
  ci_reduce<<<2, b512, 0, stream>>>(CIP, CIM);
  ci_gate<<<1, b512, 0, stream>>>(CIM, ci_w1, ci_b1, g_bn2, b_bn2, m_bn2, v_bn2,
                                  ci_w2, ci_b2, GATE);
  bias_pre<<<16, b256, 0, stream>>>(rpb, rel, BIASF);

  // 4) pj GEMM (bf16 out)
  gemm_bf16<true><<<dim3(2, M / 128), b256, 0, stream>>>(CVBF, PjT, pj_b, PJBF, M, 256, 512);

  // 5) qkv GEMM (bf16 out)
  gemm_bf16<true><<<dim3(6, M / 128), b256, 0, stream>>>(A1BF, QkvT, b_qkv, QKVBF, M, 768, 256);

  // 6) MFMA windowed attention
  attn_mfma<<<NWIN, b256, 0, stream>>>(QKVBF, GATE, BIASF, ATTBF);

  // 7) spatial gate + BN3 + LN-out + concat
  si_ln_concat<<<M / 16, b256, 0, stream>>>(ATTBF, PJBF, si_w1, si_b1, g_bn4, b_bn4,
                                            m_bn4, v_bn4, si_w2, si_b2, g_bn3,
                                            b_bn3, m_bn3, v_bn3, g_lno, b_lno, CAT);

  // 8) final GEMM -> d_out (f32)
  gemm_bf16<false><<<dim3(4, M / 128), b256, 0, stream>>>(CAT, OutT, b_out,
                                                          (float*)d_out, M, 512, 512);
}

// Round 6
// 844.569 us; speedup vs baseline: 4.1903x; 1.0110x over previous
//
#include <hip/hip_runtime.h>
#include <math.h>

#define EPS 1e-5f
#define MROWS 100352        // B_ * N = 1568 * 64
#define NWIN  1568

typedef __attribute__((ext_vector_type(8))) short bf16x8;
typedef __attribute__((ext_vector_type(4))) float f32x4;

__device__ __forceinline__ unsigned short f2bf(float f) {
  unsigned u = __float_as_uint(f);
  u += 0x7fffu + ((u >> 16) & 1u);
  return (unsigned short)(u >> 16);
}
__device__ __forceinline__ float bf2f(unsigned short s) {
  return __uint_as_float(((unsigned)s) << 16);
}
__device__ __forceinline__ float gelu_exact(float x) {
  return 0.5f * x * (1.f + erff(x * 0.70710678118654752f));
}

#define GLOAD16(gp, lp)                                              \
  __builtin_amdgcn_global_load_lds(                                  \
      (const __attribute__((address_space(1))) void*)(gp),           \
      (__attribute__((address_space(3))) void*)(lp), 16, 0, 0)

// XCD-aware chunked swizzle (active only when nwg % 8 == 0).
__device__ __forceinline__ void xcd_map(int& bx, int& by) {
  const int nwg = gridDim.x * gridDim.y;
  int n = blockIdx.y * gridDim.x + blockIdx.x;
  int w = n;
  if ((nwg & 7) == 0) w = (n & 7) * (nwg >> 3) + (n >> 3);
  by = w / gridDim.x;
  bx = w - by * gridDim.x;
}

// ---------------------------------------------------------------------------
// bf16 MFMA GEMM, 2-phase double-buffered (T3 minimum recipe):
// issue next tile's global_load_lds BEFORE computing current tile, so the
// barrier's vmcnt(0) drain overlaps MFMA instead of exposing full latency.
// ---------------------------------------------------------------------------
template <bool OUTBF>
__global__ __launch_bounds__(256) void gemm_bf16(
    const unsigned short* __restrict__ A, const unsigned short* __restrict__ Bt,
    const float* __restrict__ bias, void* __restrict__ Cout,
    int M, int N, int K) {
  __shared__ unsigned short As[2][128 * 32];
  __shared__ unsigned short Bs[2][128 * 32];
  const int tid = threadIdx.x;
  const int lane = tid & 63, wave = tid >> 6;
  const int wr = wave >> 1, wc = wave & 1;
  int bx, by;
  xcd_map(bx, by);
  const int row0 = by * 128, col0 = bx * 128;
  const int lrow = tid >> 2, loff = (tid & 3) * 8;
  const int g8 = (lane >> 4) * 8, rl = lane & 15;
  f32x4 acc[4][4];
#pragma unroll
  for (int m = 0; m < 4; ++m)
#pragma unroll
    for (int n = 0; n < 4; ++n) acc[m][n] = (f32x4){0.f, 0.f, 0.f, 0.f};
  // prologue: stage tile 0 into buffer 0
#pragma unroll
  for (int p = 0; p < 2; ++p) {
    int r = p * 64 + lrow;
    GLOAD16(&A[(size_t)(row0 + r) * K + loff], &As[0][r * 32 + loff]);
    GLOAD16(&Bt[(size_t)(col0 + r) * K + loff], &Bs[0][r * 32 + loff]);
  }
  __syncthreads();
  int cur = 0;
  for (int k0 = 32; k0 < K; k0 += 32) {
    // prefetch next tile into the other buffer (loads fly during MFMA below)
#pragma unroll
    for (int p = 0; p < 2; ++p) {
      int r = p * 64 + lrow;
      GLOAD16(&A[(size_t)(row0 + r) * K + k0 + loff], &As[cur ^ 1][r * 32 + loff]);
      GLOAD16(&Bt[(size_t)(col0 + r) * K + k0 + loff], &Bs[cur ^ 1][r * 32 + loff]);
    }
    // compute current tile
    bf16x8 af[4], bfr[4];
#pragma unroll
    for (int m = 0; m < 4; ++m)
      af[m] = *(const bf16x8*)&As[cur][(wr * 64 + m * 16 + rl) * 32 + g8];
#pragma unroll
    for (int n = 0; n < 4; ++n)
      bfr[n] = *(const bf16x8*)&Bs[cur][(wc * 64 + n * 16 + rl) * 32 + g8];
#pragma unroll
    for (int m = 0; m < 4; ++m)
#pragma unroll
      for (int n = 0; n < 4; ++n)
        acc[m][n] = __builtin_amdgcn_mfma_f32_16x16x32_bf16(af[m], bfr[n],
                                                            acc[m][n], 0, 0, 0);
    __syncthreads();  // drains vmcnt (prefetch) + lgkm; next buffer ready
    cur ^= 1;
  }
  {  // last tile (no prefetch)
    bf16x8 af[4], bfr[4];
#pragma unroll
    for (int m = 0; m < 4; ++m)
      af[m] = *(const bf16x8*)&As[cur][(wr * 64 + m * 16 + rl) * 32 + g8];
#pragma unroll
    for (int n = 0; n < 4; ++n)
      bfr[n] = *(const bf16x8*)&Bs[cur][(wc * 64 + n * 16 + rl) * 32 + g8];
#pragma unroll
    for (int m = 0; m < 4; ++m)
#pragma unroll
      for (int n = 0; n < 4; ++n)
        acc[m][n] = __builtin_amdgcn_mfma_f32_16x16x32_bf16(af[m], bfr[n],
                                                            acc[m][n], 0, 0, 0);
  }
  const int crow = (lane >> 4) * 4, ccol = lane & 15;
#pragma unroll
  for (int n = 0; n < 4; ++n) {
    const int gc = col0 + wc * 64 + n * 16 + ccol;
    const float bz = bias[gc];
#pragma unroll
    for (int m = 0; m < 4; ++m) {
      const int gr0 = row0 + wr * 64 + m * 16 + crow;
#pragma unroll
      for (int r = 0; r < 4; ++r) {
        float val = acc[m][n][r] + bz;
        if constexpr (OUTBF)
          ((unsigned short*)Cout)[(size_t)(gr0 + r) * N + gc] = f2bf(val);
        else
          ((float*)Cout)[(size_t)(gr0 + r) * N + gc] = val;
      }
    }
  }
}

// ---------------------------------------------------------------------------
// f32-A variant, 2-phase double-buffered. A is reg-staged (f32 -> cvt_pk ->
// ds_write_b128 with row=tid>>2 mapping: 8-group bank pattern, structural min,
// vs the old b64 16-way conflict). B via global_load_lds.
// ---------------------------------------------------------------------------
__global__ __launch_bounds__(256) void gemm_f32a(
    const float* __restrict__ A, const unsigned short* __restrict__ Bt,
    const float* __restrict__ bias, unsigned short* __restrict__ Cout,
    int M, int N, int K) {
  __shared__ unsigned short As[2][128 * 32];
  __shared__ unsigned short Bs[2][128 * 32];
  const int tid = threadIdx.x;
  const int lane = tid & 63, wave = tid >> 6;
  const int wr = wave >> 1, wc = wave & 1;
  int bx, by;
  xcd_map(bx, by);
  const int row0 = by * 128, col0 = bx * 128;
  const int lrow = tid >> 2, loff = (tid & 3) * 8;  // B loader
  const int arow = tid >> 2, acol = (tid & 3) * 8;  // A chunk: rows arow, arow+64
  const int g8 = (lane >> 4) * 8, rl = lane & 15;
  f32x4 acc[4][4];
#pragma unroll
  for (int m = 0; m < 4; ++m)
#pragma unroll
    for (int n = 0; n < 4; ++n) acc[m][n] = (f32x4){0.f, 0.f, 0.f, 0.f};

#define LOADA(k0, f00, f01, f10, f11)                                          \
  f00 = *(const float4*)&A[(size_t)(row0 + arow) * K + (k0) + acol];           \
  f01 = *(const float4*)&A[(size_t)(row0 + arow) * K + (k0) + acol + 4];       \
  f10 = *(const float4*)&A[(size_t)(row0 + arow + 64) * K + (k0) + acol];      \
  f11 = *(const float4*)&A[(size_t)(row0 + arow + 64) * K + (k0) + acol + 4];

#define WRITEA(buf, f00, f01, f10, f11)                                        \
  {                                                                            \
    unsigned q0, q1, q2, q3;                                                   \
    asm("v_cvt_pk_bf16_f32 %0, %1, %2" : "=v"(q0) : "v"(f00.x), "v"(f00.y));   \
    asm("v_cvt_pk_bf16_f32 %0, %1, %2" : "=v"(q1) : "v"(f00.z), "v"(f00.w));   \
    asm("v_cvt_pk_bf16_f32 %0, %1, %2" : "=v"(q2) : "v"(f01.x), "v"(f01.y));   \
    asm("v_cvt_pk_bf16_f32 %0, %1, %2" : "=v"(q3) : "v"(f01.z), "v"(f01.w));   \
    *(uint4*)&As[buf][arow * 32 + acol] = make_uint4(q0, q1, q2, q3);          \
    asm("v_cvt_pk_bf16_f32 %0, %1, %2" : "=v"(q0) : "v"(f10.x), "v"(f10.y));   \
    asm("v_cvt_pk_bf16_f32 %0, %1, %2" : "=v"(q1) : "v"(f10.z), "v"(f10.w));   \
    asm("v_cvt_pk_bf16_f32 %0, %1, %2" : "=v"(q2) : "v"(f11.x), "v"(f11.y));   \
    asm("v_cvt_pk_bf16_f32 %0, %1, %2" : "=v"(q3) : "v"(f11.z), "v"(f11.w));   \
    *(uint4*)&As[buf][(arow + 64) * 32 + acol] = make_uint4(q0, q1, q2, q3);   \
  }

  // prologue: tile 0
  {
    float4 f00, f01, f10, f11;
    LOADA(0, f00, f01, f10, f11);
#pragma unroll
    for (int p = 0; p < 2; ++p) {
      int r = p * 64 + lrow;
      GLOAD16(&Bt[(size_t)(col0 + r) * K + loff], &Bs[0][r * 32 + loff]);
    }
    WRITEA(0, f00, f01, f10, f11);
  }
  __syncthreads();
  int cur = 0;
  for (int k0 = 32; k0 < K; k0 += 32) {
    float4 f00, f01, f10, f11;
    LOADA(k0, f00, f01, f10, f11);  // issue early: latency hides under MFMA
#pragma unroll
    for (int p = 0; p < 2; ++p) {
      int r = p * 64 + lrow;
      GLOAD16(&Bt[(size_t)(col0 + r) * K + k0 + loff], &Bs[cur ^ 1][r * 32 + loff]);
    }
    bf16x8 af[4], bfr[4];
#pragma unroll
    for (int m = 0; m < 4; ++m)
      af[m] = *(const bf16x8*)&As[cur][(wr * 64 + m * 16 + rl) * 32 + g8];
#pragma unroll
    for (int n = 0; n < 4; ++n)
      bfr[n] = *(const bf16x8*)&Bs[cur][(wc * 64 + n * 16 + rl) * 32 + g8];
#pragma unroll
    for (int m = 0; m < 4; ++m)
#pragma unroll
      for (int n = 0; n < 4; ++n)
        acc[m][n] = __builtin_amdgcn_mfma_f32_16x16x32_bf16(af[m], bfr[n],
                                                            acc[m][n], 0, 0, 0);
    WRITEA(cur ^ 1, f00, f01, f10, f11);
    __syncthreads();
    cur ^= 1;
  }
  {
    bf16x8 af[4], bfr[4];
#pragma unroll
    for (int m = 0; m < 4; ++m)
      af[m] = *(const bf16x8*)&As[cur][(wr * 64 + m * 16 + rl) * 32 + g8];
#pragma unroll
    for (int n = 0; n < 4; ++n)
      bfr[n] = *(const bf16x8*)&Bs[cur][(wc * 64 + n * 16 + rl) * 32 + g8];
#pragma unroll
    for (int m = 0; m < 4; ++m)
#pragma unroll
      for (int n = 0; n < 4; ++n)
        acc[m][n] = __builtin_amdgcn_mfma_f32_16x16x32_bf16(af[m], bfr[n],
                                                            acc[m][n], 0, 0, 0);
  }
  const int crow = (lane >> 4) * 4, ccol = lane & 15;
#pragma unroll
  for (int n = 0; n < 4; ++n) {
    const int gc = col0 + wc * 64 + n * 16 + ccol;
    const float bz = bias[gc];
#pragma unroll
    for (int m = 0; m < 4; ++m) {
      const int gr0 = row0 + wr * 64 + m * 16 + crow;
#pragma unroll
      for (int r = 0; r < 4; ++r)
        Cout[(size_t)(gr0 + r) * N + gc] = f2bf(acc[m][n][r] + bz);
    }
  }
#undef LOADA
#undef WRITEA
}

// Weight convert + transpose: in (K,N) f32 -> out (N,K) bf16.
__global__ __launch_bounds__(256) void wt_convert(const float* __restrict__ in,
                                                  unsigned short* __restrict__ out,
                                                  int K, int N) {
  int i = blockIdx.x * 256 + threadIdx.x;
  if (i >= K * N) return;
  int n = i / K, k = i - n * K;
  out[i] = f2bf(in[(size_t)k * N + n]);
}

__global__ __launch_bounds__(256) void pack_bias(const float* __restrict__ b_pa,
                                                 const float* __restrict__ b_pc,
                                                 float* __restrict__ out) {
  int t = blockIdx.x * 256 + threadIdx.x;
  if (t < 256) out[t] = b_pa[t];
  else if (t < 768) out[t] = b_pc[t - 256];
}

// ---------------------------------------------------------------------------
// Row LayerNorm, strided bf16 in -> compact bf16 out. 4 rows/block (1/wave).
// ---------------------------------------------------------------------------
template <int W>
__global__ __launch_bounds__(256) void ln_rows_bf(
    const unsigned short* __restrict__ in, int istride,
    unsigned short* __restrict__ out,
    const float* __restrict__ g, const float* __restrict__ b) {
  const int row = blockIdx.x * 4 + (threadIdx.x >> 6);
  const int t = threadIdx.x & 63;
  constexpr int NE = W / 64;
  float v[NE];
  const size_t ibase = (size_t)row * istride + t * NE;
  const size_t obase = (size_t)row * W + t * NE;
#pragma unroll
  for (int c4 = 0; c4 < NE / 4; ++c4) {
    ushort4 u = *(const ushort4*)&in[ibase + c4 * 4];
    v[c4 * 4 + 0] = bf2f(u.x); v[c4 * 4 + 1] = bf2f(u.y);
    v[c4 * 4 + 2] = bf2f(u.z); v[c4 * 4 + 3] = bf2f(u.w);
  }
  float s = 0.f, sq = 0.f;
#pragma unroll
  for (int j = 0; j < NE; ++j) { s += v[j]; sq += v[j] * v[j]; }
#pragma unroll
  for (int off = 32; off >= 1; off >>= 1) {
    s += __shfl_xor(s, off);
    sq += __shfl_xor(sq, off);
  }
  const float mean = s * (1.f / W);
  const float var = sq * (1.f / W) - mean * mean;
  const float rstd = rsqrtf(var + EPS);
#pragma unroll
  for (int c4 = 0; c4 < NE / 4; ++c4) {
    int c = t * NE + c4 * 4;
    ushort4 o = make_ushort4(
        f2bf((v[c4 * 4 + 0] - mean) * rstd * g[c + 0] + b[c + 0]),
        f2bf((v[c4 * 4 + 1] - mean) * rstd * g[c + 1] + b[c + 1]),
        f2bf((v[c4 * 4 + 2] - mean) * rstd * g[c + 2] + b[c + 2]),
        f2bf((v[c4 * 4 + 3] - mean) * rstd * g[c + 3] + b[c + 3]));
    *(ushort4*)&out[obase + c4 * 4] = o;
  }
}

// ---------------------------------------------------------------------------
// Depthwise 3x3 + BN1 + GELU, bf16 LDS tile, vectorized staging.
// ---------------------------------------------------------------------------
__global__ __launch_bounds__(256) void dwconv_bn_gelu(
    const unsigned short* __restrict__ xin, const float* __restrict__ wgt9,
    const float* __restrict__ dwb, const float* __restrict__ g1,
    const float* __restrict__ b1, const float* __restrict__ m1,
    const float* __restrict__ v1, unsigned short* __restrict__ outp,
    float* __restrict__ ci_part) {
  __shared__ unsigned short tile[100 * 128];  // 25.6 KB
  __shared__ float psum[8 * 128];             // 4 KB
  const int b_ = blockIdx.x;
  const int b = b_ / 784, win = b_ % 784;
  const int wi = win / 28, wj = win % 28;
  const int h0 = wi * 8 - 1, w0 = wj * 8 - 1;
  const int tid = threadIdx.x;
  const int c4 = (tid & 31) * 4;
  const int pg = tid >> 5;
  for (int chunk = 0; chunk < 4; ++chunk) {
    const int c0 = chunk * 128;
    __syncthreads();
#pragma unroll
    for (int it = 0; it < 7; ++it) {
      int idx = it * 256 + tid;
      if (idx < 1600) {
        int p = idx >> 4;
        int ch8 = (idx & 15) * 8;
        int ph = h0 + p / 10, pw = w0 + p % 10;
        uint4 val = {0u, 0u, 0u, 0u};
        if (ph >= 0 && ph < 224 && pw >= 0 && pw < 224) {
          int bs = b * 784 + (ph >> 3) * 28 + (pw >> 3);
          int n = ((ph & 7) << 3) | (pw & 7);
          val = *(const uint4*)&xin[(size_t)(bs * 64 + n) * 512 + c0 + ch8];
        }
        *(uint4*)&tile[p * 128 + ch8] = val;
      }
    }
    __syncthreads();
    float wreg[9][4];
    float scale[4], shift[4], bias0[4];
#pragma unroll
    for (int j = 0; j < 4; ++j) {
      int cc = c0 + c4 + j;
#pragma unroll
      for (int k = 0; k < 9; ++k) wreg[k][j] = wgt9[cc * 9 + k];
      scale[j] = g1[cc] * rsqrtf(v1[cc] + EPS);
      shift[j] = b1[cc] - m1[cc] * scale[j];
      bias0[j] = dwb[cc];
    }
    float cs0 = 0.f, cs1 = 0.f, cs2 = 0.f, cs3 = 0.f;
    for (int q = 0; q < 8; ++q) {
      const int qq = pg * 8 + q;
      const int r = qq >> 3, cc_ = qq & 7;
      float a0 = bias0[0], a1 = bias0[1], a2 = bias0[2], a3 = bias0[3];
#pragma unroll
      for (int dr = 0; dr < 3; ++dr)
#pragma unroll
        for (int dc = 0; dc < 3; ++dc) {
          ushort4 u = *(const ushort4*)&tile[((r + dr) * 10 + cc_ + dc) * 128 + c4];
          const int k = dr * 3 + dc;
          a0 += bf2f(u.x) * wreg[k][0];
          a1 += bf2f(u.y) * wreg[k][1];
          a2 += bf2f(u.z) * wreg[k][2];
          a3 += bf2f(u.w) * wreg[k][3];
        }
      float g0 = gelu_exact(a0 * scale[0] + shift[0]);
      float g1v = gelu_exact(a1 * scale[1] + shift[1]);
      float g2v = gelu_exact(a2 * scale[2] + shift[2]);
      float g3v = gelu_exact(a3 * scale[3] + shift[3]);
      cs0 += g0; cs1 += g1v; cs2 += g2v; cs3 += g3v;
      *(ushort4*)&outp[(size_t)(b_ * 64 + qq) * 512 + c0 + c4] =
          make_ushort4(f2bf(g0), f2bf(g1v), f2bf(g2v), f2bf(g3v));
    }
    *(float4*)&psum[pg * 128 + c4] = make_float4(cs0, cs1, cs2, cs3);
    __syncthreads();
    if (tid < 128) {
      float s = 0.f;
#pragma unroll
      for (int g = 0; g < 8; ++g) s += psum[g * 128 + tid];
      ci_part[(size_t)b_ * 512 + c0 + tid] = s;
    }
  }
}

__global__ __launch_bounds__(512) void ci_reduce(const float* __restrict__ ci_part,
                                                 float* __restrict__ ci_mean) {
  const int b = blockIdx.x, c = threadIdx.x;
  float s = 0.f;
  for (int w = 0; w < 784; ++w) s += ci_part[(size_t)(b * 784 + w) * 512 + c];
  ci_mean[b * 512 + c] = s * (1.f / 50176.f);
}

__global__ __launch_bounds__(512) void ci_gate(
    const float* __restrict__ ci_mean, const float* __restrict__ w1,
    const float* __restrict__ bi1, const float* __restrict__ g2,
    const float* __restrict__ b2, const float* __restrict__ m2,
    const float* __restrict__ v2, const float* __restrict__ w2,
    const float* __restrict__ bi2, float* __restrict__ gate) {
  __shared__ float cm[1024];
  __shared__ float c1[128];
  const int t = threadIdx.x;
  cm[t] = ci_mean[t];
  cm[t + 512] = ci_mean[t + 512];
  __syncthreads();
  if (t < 128) {
    int b = t >> 6, j = t & 63;
    float acc = bi1[j];
    for (int c = 0; c < 512; ++c) acc += cm[b * 512 + c] * w1[c * 64 + j];
    float sc = g2[j] * rsqrtf(v2[j] + EPS);
    c1[t] = gelu_exact((acc - m2[j]) * sc + b2[j]);
  }
  __syncthreads();
  {
    int b = t >> 8, o = t & 255;
    float acc = bi2[o];
#pragma unroll
    for (int j = 0; j < 64; ++j) acc += c1[b * 64 + j] * w2[j * 256 + o];
    gate[b * 256 + o] = 1.f / (1.f + expf(-acc));
  }
}

// Precompute bias table biasf[h][n][m] = rpb[rel[n*64+m]*8+h]
__global__ __launch_bounds__(256) void bias_pre(const float* __restrict__ rpb,
                                                const int* __restrict__ rel,
                                                float* __restrict__ biasf) {
  int i = blockIdx.x * 256 + threadIdx.x;
  if (i >= 4096) return;
  int r = rel[i];
#pragma unroll
  for (int h = 0; h < 8; ++h) biasf[h * 4096 + i] = rpb[r * 8 + h];
}

// ---------------------------------------------------------------------------
// MFMA windowed attention (bf16 out). Block = 1 window, 4 waves x 2 heads.
// ---------------------------------------------------------------------------
__global__ __launch_bounds__(256) void attn_mfma(
    const unsigned short* __restrict__ qkv,  // (M,768) bf16
    const float* __restrict__ gate,          // (2,256)
    const float* __restrict__ biasf,         // (8,64,64) f32
    unsigned short* __restrict__ outp) {     // (M,256) bf16
  __shared__ unsigned short lds[4 * (64 * 68 + 32 * 68)];
  const int w = blockIdx.x;
  const int b = w / 784;
  const int tid = threadIdx.x, lane = tid & 63, wave = tid >> 6;
  unsigned short* p_lds = lds + wave * (64 * 68 + 32 * 68);
  unsigned short* vT = p_lds + 64 * 68;
  const int l15 = lane & 15, l4 = lane >> 4;
  const float scale = 0.17677669529663687f;
  for (int hh = 0; hh < 2; ++hh) {
    const int h = wave * 2 + hh;
    {
      const float* gh = &gate[b * 256 + h * 32];
      const size_t vbase = ((size_t)w * 64 + lane) * 768 + 512 + h * 32;
#pragma unroll
      for (int c = 0; c < 4; ++c) {
        uint4 vv = *(const uint4*)&qkv[vbase + c * 8];
        float4 gA = *(const float4*)&gh[c * 8];
        float4 gB = *(const float4*)&gh[c * 8 + 4];
        unsigned vw[4] = {vv.x, vv.y, vv.z, vv.w};
        float gg[8] = {gA.x, gA.y, gA.z, gA.w, gB.x, gB.y, gB.z, gB.w};
#pragma unroll
        for (int j = 0; j < 4; ++j) {
          int d = c * 8 + j * 2;
          vT[(d + 0) * 68 + lane] = f2bf(__uint_as_float(vw[j] << 16) * gg[j * 2]);
          vT[(d + 1) * 68 + lane] =
              f2bf(__uint_as_float(vw[j] & 0xffff0000u) * gg[j * 2 + 1]);
        }
      }
    }
    bf16x8 kf[4], qf[4];
    const size_t qkbase = (size_t)w * 64 * 768 + h * 32 + l4 * 8;
#pragma unroll
    for (int t = 0; t < 4; ++t) {
      kf[t] = *(const bf16x8*)&qkv[qkbase + (size_t)(t * 16 + l15) * 768 + 256];
      qf[t] = *(const bf16x8*)&qkv[qkbase + (size_t)(t * 16 + l15) * 768];
    }
    f32x4 s[4][4];
#pragma unroll
    for (int mt = 0; mt < 4; ++mt)
#pragma unroll
      for (int nt = 0; nt < 4; ++nt) s[mt][nt] = (f32x4){0.f, 0.f, 0.f, 0.f};
#pragma unroll
    for (int mt = 0; mt < 4; ++mt)
#pragma unroll
      for (int nt = 0; nt < 4; ++nt)
        s[mt][nt] = __builtin_amdgcn_mfma_f32_16x16x32_bf16(kf[mt], qf[nt],
                                                            s[mt][nt], 0, 0, 0);
    float inv_s[4];
#pragma unroll
    for (int nt = 0; nt < 4; ++nt) {
      float mx = -1e30f;
#pragma unroll
      for (int mt = 0; mt < 4; ++mt) {
        float4 b4 = *(const float4*)&biasf[(h * 64 + nt * 16 + l15) * 64 +
                                           mt * 16 + l4 * 4];
        s[mt][nt][0] = s[mt][nt][0] * scale + b4.x;
        s[mt][nt][1] = s[mt][nt][1] * scale + b4.y;
        s[mt][nt][2] = s[mt][nt][2] * scale + b4.z;
        s[mt][nt][3] = s[mt][nt][3] * scale + b4.w;
#pragma unroll
        for (int r = 0; r < 4; ++r) mx = fmaxf(mx, s[mt][nt][r]);
      }
      mx = fmaxf(mx, __shfl_xor(mx, 16));
      mx = fmaxf(mx, __shfl_xor(mx, 32));
      float sum = 0.f;
#pragma unroll
      for (int mt = 0; mt < 4; ++mt)
#pragma unroll
        for (int r = 0; r < 4; ++r) {
          float e = __expf(s[mt][nt][r] - mx);
          s[mt][nt][r] = e;
          sum += e;
        }
      sum += __shfl_xor(sum, 16);
      sum += __shfl_xor(sum, 32);
      inv_s[nt] = 1.f / sum;
    }
#pragma unroll
    for (int nt = 0; nt < 4; ++nt)
#pragma unroll
      for (int mt = 0; mt < 4; ++mt) {
        ushort4 pk = make_ushort4(f2bf(s[mt][nt][0] * inv_s[nt]),
                                  f2bf(s[mt][nt][1] * inv_s[nt]),
                                  f2bf(s[mt][nt][2] * inv_s[nt]),
                                  f2bf(s[mt][nt][3] * inv_s[nt]));
        *(ushort4*)&p_lds[(nt * 16 + l15) * 68 + mt * 16 + l4 * 4] = pk;
      }
    f32x4 o[4][2];
#pragma unroll
    for (int i = 0; i < 4; ++i)
#pragma unroll
      for (int dt = 0; dt < 2; ++dt) o[i][dt] = (f32x4){0.f, 0.f, 0.f, 0.f};
#pragma unroll
    for (int ks = 0; ks < 2; ++ks) {
      bf16x8 pa[4], vf[2];
#pragma unroll
      for (int i = 0; i < 4; ++i) {
        const unsigned short* pp = &p_lds[(i * 16 + l15) * 68 + ks * 32 + l4 * 8];
        union { bf16x8 v; ushort4 u[2]; } tmp;
        tmp.u[0] = *(const ushort4*)pp;
        tmp.u[1] = *(const ushort4*)(pp + 4);
        pa[i] = tmp.v;
      }
#pragma unroll
      for (int dt = 0; dt < 2; ++dt) {
        const unsigned short* vp = &vT[(dt * 16 + l15) * 68 + ks * 32 + l4 * 8];
        union { bf16x8 v; ushort4 u[2]; } tmp;
        tmp.u[0] = *(const ushort4*)vp;
        tmp.u[1] = *(const ushort4*)(vp + 4);
        vf[dt] = tmp.v;
      }
#pragma unroll
      for (int i = 0; i < 4; ++i)
#pragma unroll
        for (int dt = 0; dt < 2; ++dt)
          o[i][dt] = __builtin_amdgcn_mfma_f32_16x16x32_bf16(pa[i], vf[dt],
                                                             o[i][dt], 0, 0, 0);
    }
#pragma unroll
    for (int i = 0; i < 4; ++i)
#pragma unroll
      for (int dt = 0; dt < 2; ++dt)
#pragma unroll
        for (int r = 0; r < 4; ++r)
          outp[((size_t)w * 64 + i * 16 + l4 * 4 + r) * 256 + h * 32 +
               dt * 16 + l15] = f2bf(o[i][dt][r]);
  }
}

// ---------------------------------------------------------------------------
// Spatial gate + BN3 + LN-out + concat (bf16 in, bf16 out).
// ---------------------------------------------------------------------------
__global__ __launch_bounds__(256) void si_ln_concat(
    const unsigned short* __restrict__ xatt, const unsigned short* __restrict__ xpj,
    const float* __restrict__ w1, const float* __restrict__ bi1,
    const float* __restrict__ g4, const float* __restrict__ b4v,
    const float* __restrict__ m4, const float* __restrict__ v4,
    const float* __restrict__ w2, const float* __restrict__ bi2,
    const float* __restrict__ g3, const float* __restrict__ b3v,
    const float* __restrict__ m3, const float* __restrict__ v3,
    const float* __restrict__ glno, const float* __restrict__ blno,
    unsigned short* __restrict__ outc) {
  __shared__ float xr[16 * 256];
  __shared__ float s1s[16 * 64];
  __shared__ float sig[16];
  const int t = threadIdx.x;
  const int row0 = blockIdx.x * 16;
#pragma unroll
  for (int i = 0; i < 2; ++i) {
    int idx = i * 256 + t;
    int pr = idx >> 5, pc = (idx & 31) * 8;
    const unsigned short* src = &xatt[(size_t)(row0 + pr) * 256 + pc];
    ushort4 a = *(const ushort4*)src;
    ushort4 c = *(const ushort4*)(src + 4);
    float* dst = &xr[pr * 256 + pc];
    dst[0] = bf2f(a.x); dst[1] = bf2f(a.y); dst[2] = bf2f(a.z); dst[3] = bf2f(a.w);
    dst[4] = bf2f(c.x); dst[5] = bf2f(c.y); dst[6] = bf2f(c.z); dst[7] = bf2f(c.w);
  }
  __syncthreads();
  {
    const int j = t & 63, pg = t >> 6;
    float acc[4];
    const float bj = bi1[j];
#pragma unroll
    for (int i = 0; i < 4; ++i) acc[i] = bj;
    for (int cc = 0; cc < 256; ++cc) {
      float wv = w1[cc * 64 + j];
#pragma unroll
      for (int i = 0; i < 4; ++i) acc[i] += xr[(pg * 4 + i) * 256 + cc] * wv;
    }
    const float sc4 = g4[j] * rsqrtf(v4[j] + EPS);
    const float m4j = m4[j], b4j = b4v[j];
#pragma unroll
    for (int i = 0; i < 4; ++i)
      s1s[(pg * 4 + i) * 64 + j] = gelu_exact((acc[i] - m4j) * sc4 + b4j);
  }
  __syncthreads();
  if (t < 16) {
    float a2 = bi2[0];
#pragma unroll
    for (int jj = 0; jj < 64; ++jj) a2 += s1s[t * 64 + jj] * w2[jj];
    sig[t] = 1.f / (1.f + expf(-a2));
  }
  __syncthreads();
  {
    const int p = t >> 4, l = t & 15;
    float4 v4s[4];
    float s = 0.f, sq = 0.f;
#pragma unroll
    for (int cq = 0; cq < 4; ++cq) {
      float4 x4 = *(const float4*)&xr[p * 256 + cq * 64 + l * 4];
      v4s[cq] = x4;
      s += x4.x + x4.y + x4.z + x4.w;
      sq += x4.x * x4.x + x4.y * x4.y + x4.z * x4.z + x4.w * x4.w;
    }
#pragma unroll
    for (int off = 8; off >= 1; off >>= 1) {
      s += __shfl_xor(s, off);
      sq += __shfl_xor(sq, off);
    }
    const float mean = s * (1.f / 256.f);
    const float var = sq * (1.f / 256.f) - mean * mean;
    const float rstd = rsqrtf(var + EPS);
    const size_t orow = (size_t)(row0 + p) * 512;
#pragma unroll
    for (int cq = 0; cq < 4; ++cq) {
      int c = cq * 64 + l * 4;
      float4 x4 = v4s[cq];
      *(ushort4*)&outc[orow + c] = make_ushort4(
          f2bf((x4.x - mean) * rstd * glno[c + 0] + blno[c + 0]),
          f2bf((x4.y - mean) * rstd * glno[c + 1] + blno[c + 1]),
          f2bf((x4.z - mean) * rstd * glno[c + 2] + blno[c + 2]),
          f2bf((x4.w - mean) * rstd * glno[c + 3] + blno[c + 3]));
    }
    const float sg = sig[p];
#pragma unroll
    for (int cq = 0; cq < 4; ++cq) {
      int c = cq * 64 + l * 4;
      ushort4 pu = *(const ushort4*)&xpj[(size_t)(row0 + p) * 256 + c];
      float px = bf2f(pu.x), py = bf2f(pu.y), pz = bf2f(pu.z), pw = bf2f(pu.w);
      float sc0 = g3[c + 0] * rsqrtf(v3[c + 0] + EPS);
      float sc1 = g3[c + 1] * rsqrtf(v3[c + 1] + EPS);
      float sc2 = g3[c + 2] * rsqrtf(v3[c + 2] + EPS);
      float sc3 = g3[c + 3] * rsqrtf(v3[c + 3] + EPS);
      *(ushort4*)&outc[orow + 256 + c] = make_ushort4(
          f2bf(sg * px * sc0 + (b3v[c + 0] - m3[c + 0] * sc0)),
          f2bf(sg * py * sc1 + (b3v[c + 1] - m3[c + 1] * sc1)),
          f2bf(sg * pz * sc2 + (b3v[c + 2] - m3[c + 2] * sc2)),
          f2bf(sg * pw * sc3 + (b3v[c + 3] - m3[c + 3] * sc3)));
    }
  }
}

// ---------------------------------------------------------------------------
extern "C" void kernel_launch(void* const* d_in, const int* in_sizes, int n_in,
                              void* d_out, int out_size, void* d_ws, size_t ws_size,
                              hipStream_t stream) {
  const float* x     = (const float*)d_in[0];
  const float* w_pa  = (const float*)d_in[1];
  const float* b_pa  = (const float*)d_in[2];
  const float* g_lna = (const float*)d_in[3];
  const float* b_lna = (const float*)d_in[4];
  const float* w_pc  = (const float*)d_in[5];
  const float* b_pc  = (const float*)d_in[6];
  const float* g_lnc = (const float*)d_in[7];
  const float* b_lnc = (const float*)d_in[8];
  const float* dw_w  = (const float*)d_in[9];
  const float* dw_b  = (const float*)d_in[10];
  const float* g_bn1 = (const float*)d_in[11];
  const float* b_bn1 = (const float*)d_in[12];
  const float* m_bn1 = (const float*)d_in[13];
  const float* v_bn1 = (const float*)d_in[14];
  const float* ci_w1 = (const float*)d_in[15];
  const float* ci_b1 = (const float*)d_in[16];
  const float* g_bn2 = (const float*)d_in[17];
  const float* b_bn2 = (const float*)d_in[18];
  const float* m_bn2 = (const float*)d_in[19];
  const float* v_bn2 = (const float*)d_in[20];
  const float* ci_w2 = (const float*)d_in[21];
  const float* ci_b2 = (const float*)d_in[22];
  const float* pj_w  = (const float*)d_in[23];
  const float* pj_b  = (const float*)d_in[24];
  const float* g_bn3 = (const float*)d_in[25];
  const float* b_bn3 = (const float*)d_in[26];
  const float* m_bn3 = (const float*)d_in[27];
  const float* v_bn3 = (const float*)d_in[28];
  const float* w_qkv = (const float*)d_in[29];
  const float* b_qkv = (const float*)d_in[30];
  const float* si_w1 = (const float*)d_in[31];
  const float* si_b1 = (const float*)d_in[32];
  const float* g_bn4 = (const float*)d_in[33];
  const float* b_bn4 = (const float*)d_in[34];
  const float* m_bn4 = (const float*)d_in[35];
  const float* v_bn4 = (const float*)d_in[36];
  const float* si_w2 = (const float*)d_in[37];
  const float* si_b2 = (const float*)d_in[38];
  const float* g_lno = (const float*)d_in[39];
  const float* b_lno = (const float*)d_in[40];
  const float* w_out = (const float*)d_in[41];
  const float* b_out = (const float*)d_in[42];
  const float* rpb   = (const float*)d_in[43];
  const int*   rel   = (const int*)d_in[44];

  char* ws = (char*)d_ws;
  unsigned short* G12BF = (unsigned short*)(ws + 0);            // (M,768) fused pre-LN
  unsigned short* QKVBF = (unsigned short*)(ws + 0);            // (M,768)
  unsigned short* A1BF  = (unsigned short*)(ws + 154140672ull); // (M,256)
  unsigned short* ATTBF = (unsigned short*)(ws + 154140672ull); // (M,256)
  unsigned short* C1BF  = (unsigned short*)(ws + 205520896ull); // (M,512)
  unsigned short* CAT   = (unsigned short*)(ws + 205520896ull); // (M,512)
  unsigned short* CVBF  = (unsigned short*)(ws + 308281344ull); // (M,512)
  unsigned short* PJBF  = (unsigned short*)(ws + 411041792ull); // (M,256)
  float*          CIP   = (float*)(ws + 462422016ull);          // (1568,512)
  float*          CIM   = (float*)(ws + 465633280ull);          // (2,512)
  float*          GATE  = (float*)(ws + 465637376ull);          // (2,256)
  float*          B12   = (float*)(ws + 465639424ull);          // (768)
  float*          BIASF = (float*)(ws + 465642496ull);          // (8,64,64)
  unsigned short* WT    = (unsigned short*)(ws + 465773568ull);
  unsigned short* WpaT  = WT + 0;
  unsigned short* WpcT  = WT + 131072;
  unsigned short* PjT   = WT + 393216;
  unsigned short* QkvT  = WT + 524288;
  unsigned short* OutT  = WT + 720896;

  const int M = MROWS;
  dim3 b256(256), b512(512);

  wt_convert<<<512, b256, 0, stream>>>(w_pa, WpaT, 512, 256);
  wt_convert<<<1024, b256, 0, stream>>>(w_pc, WpcT, 512, 512);
  wt_convert<<<512, b256, 0, stream>>>(pj_w, PjT, 512, 256);
  wt_convert<<<768, b256, 0, stream>>>(w_qkv, QkvT, 256, 768);
  wt_convert<<<1024, b256, 0, stream>>>(w_out, OutT, 512, 512);
  pack_bias<<<3, b256, 0, stream>>>(b_pa, b_pc, B12);

  // 1+2) fused input GEMM (f32 A): [x@w_pa | x@w_pc] -> G12BF (M,768)
  gemm_f32a<<<dim3(6, M / 128), b256, 0, stream>>>(x, WpaT, B12, G12BF, M, 768, 512);
  ln_rows_bf<256><<<M / 4, b256, 0, stream>>>(G12BF, 768, A1BF, g_lna, b_lna);
  ln_rows_bf<512><<<M / 4, b256, 0, stream>>>(G12BF + 256, 768, C1BF, g_lnc, b_lnc);

  // 3) depthwise conv + BN1 + GELU + channel sums
  dwconv_bn_gelu<<<NWIN, b256, 0, stream>>>(C1BF, dw_w, dw_b, g_bn1, b_bn1, m_bn1,
                                            v_bn1, CVBF, CIP);
  ci_reduce<<<2, b512, 0, stream>>>(CIP, CIM);
  ci_gate<<<1, b512, 0, stream>>>(CIM, ci_w1, ci_b1, g_bn2, b_bn2, m_bn2, v_bn2,
                                  ci_w2, ci_b2, GATE);
  bias_pre<<<16, b256, 0, stream>>>(rpb, rel, BIASF);

  // 4) pj GEMM (bf16 out)
  gemm_bf16<true><<<dim3(2, M / 128), b256, 0, stream>>>(CVBF, PjT, pj_b, PJBF, M, 256, 512);

  // 5) qkv GEMM (bf16 out)
  gemm_bf16<true><<<dim3(6, M / 128), b256, 0, stream>>>(A1BF, QkvT, b_qkv, QKVBF, M, 768, 256);

  // 6) MFMA windowed attention
  attn_mfma<<<NWIN, b256, 0, stream>>>(QKVBF, GATE, BIASF, ATTBF);

  // 7) spatial gate + BN3 + LN-out + concat
  si_ln_concat<<<M / 16, b256, 0, stream>>>(ATTBF, PJBF, si_w1, si_b1, g_bn4, b_bn4,
                                            m_bn4, v_bn4, si_w2, si_b2, g_bn3,
                                            b_bn3, m_bn3, v_bn3, g_lno, b_lno, CAT);

  // 8) final GEMM -> d_out (f32)
  gemm_bf16<false><<<dim3(4, M / 128), b256, 0, stream>>>(CAT, OutT, b_out,
                                                          (float*)d_out, M, 512, 512);
}

// Round 7
// 843.192 us; speedup vs baseline: 4.1971x; 1.0016x over previous
//
#include <hip/hip_runtime.h>
#include <math.h>

#define EPS 1e-5f
#define MROWS 100352        // B_ * N = 1568 * 64
#define NWIN  1568

typedef __attribute__((ext_vector_type(8))) short bf16x8;
typedef __attribute__((ext_vector_type(4))) float f32x4;

__device__ __forceinline__ unsigned short f2bf(float f) {
  unsigned u = __float_as_uint(f);
  u += 0x7fffu + ((u >> 16) & 1u);
  return (unsigned short)(u >> 16);
}
__device__ __forceinline__ float bf2f(unsigned short s) {
  return __uint_as_float(((unsigned)s) << 16);
}
__device__ __forceinline__ float gelu_exact(float x) {
  return 0.5f * x * (1.f + erff(x * 0.70710678118654752f));
}

#define GLOAD16(gp, lp)                                              \
  __builtin_amdgcn_global_load_lds(                                  \
      (const __attribute__((address_space(1))) void*)(gp),           \
      (__attribute__((address_space(3))) void*)(lp), 16, 0, 0)

// ---------------------------------------------------------------------------
// 256x256-tile 8-phase bf16 MFMA GEMM (m201-style). 512 threads = 8 waves
// (2 row-halves x 4 col-quarters), BK=64, double-buffered 128 KiB LDS with
// XOR swizzle (byte ^= (row&7)<<4) applied via inverse-swizzled global src
// for global_load_lds (linear dest) + swizzled ds_read. Counted vmcnt(2)
// once per K-tile; raw s_barrier pairs per phase; setprio around MFMA.
// C[M,N] = A[M,K] @ Bt[N,K]^T + bias.
// ---------------------------------------------------------------------------
__device__ __forceinline__ void stage_half256(
    const unsigned short* __restrict__ base, int r0, int K, int kk,
    unsigned short* lds, int ldsbase, int tid) {
#pragma unroll
  for (int inst = 0; inst < 2; ++inst) {
    int r = inst * 64 + (tid >> 3);                  // local row in half (0..127)
    int cb = ((tid & 7) << 4) ^ ((r & 7) << 4);      // inverse-swizzled byte col
    const unsigned short* src = base + (size_t)(r0 + r) * K + kk + (cb >> 1);
    GLOAD16(src, &lds[ldsbase + inst * 4096 + tid * 8]);
  }
}

__device__ __forceinline__ bf16x8 frag_read256(const unsigned short* lds,
                                               int tilebase, int r_t, int cbyte) {
  int off = r_t * 128 + cbyte;
  int phys = off ^ ((r_t & 7) << 4);
  return *(const bf16x8*)&lds[tilebase + (phys >> 1)];
}

template <bool OUTBF>
__global__ __launch_bounds__(512) void gemm256(
    const unsigned short* __restrict__ A, const unsigned short* __restrict__ Bt,
    const float* __restrict__ bias, void* __restrict__ Cout,
    int M, int N, int K) {
  __shared__ unsigned short lds[65536];  // 128 KiB: [buf][A 16384 | B 16384]
  const int tid = threadIdx.x;
  const int lane = tid & 63, wave = tid >> 6;
  const int wr = wave >> 2;   // 0..1: row half (128 rows)
  const int wcn = wave & 3;   // 0..3: col quarter (64 cols)
  int bx, by;
  {
    const int nwg = gridDim.x * gridDim.y;
    int n = blockIdx.y * gridDim.x + blockIdx.x;
    int w = ((nwg & 7) == 0) ? ((n & 7) * (nwg >> 3) + (n >> 3)) : n;
    by = w / gridDim.x;
    bx = w - by * gridDim.x;
  }
  const int row0 = by * 256, col0 = bx * 256;
  const int rl = lane & 15, qd = lane >> 4;
  f32x4 acc[8][4];
#pragma unroll
  for (int m = 0; m < 8; ++m)
#pragma unroll
    for (int n = 0; n < 4; ++n) acc[m][n] = (f32x4){0.f, 0.f, 0.f, 0.f};

  const int KT = K >> 6;
  // prologue: stage K-tile 0 into buffer 0 (8 gload insts/thread)
  stage_half256(A, row0, K, 0, lds, 0, tid);
  stage_half256(A, row0 + 128, K, 0, lds, 8192, tid);
  stage_half256(Bt, col0, K, 0, lds, 16384, tid);
  stage_half256(Bt, col0 + 128, K, 0, lds, 24576, tid);

  for (int kt = 0; kt < KT; ++kt) {
    const int b = kt & 1;
    const int abase = b * 32768, bbase = b * 32768 + 16384;
    const int nb = b ^ 1;
    const int kkn = (kt + 1) << 6;
    const bool last = (kt == KT - 1);
    bf16x8 bfr[4][2];
#pragma unroll
    for (int p = 0; p < 4; ++p) {
      if (!last) {  // stage one half-tile of K-tile kt+1 into the other buffer
        if (p == 0)      stage_half256(A, row0, K, kkn, lds, nb * 32768, tid);
        else if (p == 1) stage_half256(A, row0 + 128, K, kkn, lds, nb * 32768 + 8192, tid);
        else if (p == 2) stage_half256(Bt, col0, K, kkn, lds, nb * 32768 + 16384, tid);
        else             stage_half256(Bt, col0 + 128, K, kkn, lds, nb * 32768 + 24576, tid);
      }
      if (p == 0) {
        if (!last) asm volatile("s_waitcnt vmcnt(2)" ::: "memory");
        else       asm volatile("s_waitcnt vmcnt(0)" ::: "memory");
      }
      __builtin_amdgcn_s_barrier();
      __builtin_amdgcn_sched_barrier(0);
      if (p == 0) {
#pragma unroll
        for (int n = 0; n < 4; ++n)
#pragma unroll
          for (int ks = 0; ks < 2; ++ks)
            bfr[n][ks] = frag_read256(lds, bbase, wcn * 64 + n * 16 + rl,
                                      ks * 64 + qd * 16);
      }
      bf16x8 af[2][2];
#pragma unroll
      for (int i = 0; i < 2; ++i)
#pragma unroll
        for (int ks = 0; ks < 2; ++ks)
          af[i][ks] = frag_read256(lds, abase, wr * 128 + (2 * p + i) * 16 + rl,
                                   ks * 64 + qd * 16);
      __builtin_amdgcn_s_setprio(1);
#pragma unroll
      for (int i = 0; i < 2; ++i)
#pragma unroll
        for (int n = 0; n < 4; ++n)
#pragma unroll
          for (int ks = 0; ks < 2; ++ks)
            acc[2 * p + i][n] = __builtin_amdgcn_mfma_f32_16x16x32_bf16(
                af[i][ks], bfr[n][ks], acc[2 * p + i][n], 0, 0, 0);
      __builtin_amdgcn_s_setprio(0);
      __builtin_amdgcn_s_barrier();
    }
  }
  // epilogue: C/D layout col=lane&15, row=(lane>>4)*4+r per 16x16 fragment
  const int crow = qd * 4, ccol = rl;
#pragma unroll
  for (int n = 0; n < 4; ++n) {
    const int gc = col0 + wcn * 64 + n * 16 + ccol;
    const float bz = bias[gc];
#pragma unroll
    for (int m = 0; m < 8; ++m) {
      const int gr0 = row0 + wr * 128 + m * 16 + crow;
#pragma unroll
      for (int r = 0; r < 4; ++r) {
        float val = acc[m][n][r] + bz;
        if constexpr (OUTBF)
          ((unsigned short*)Cout)[(size_t)(gr0 + r) * N + gc] = f2bf(val);
        else
          ((float*)Cout)[(size_t)(gr0 + r) * N + gc] = val;
      }
    }
  }
}

// Weight convert + transpose: in (K,N) f32 -> out (N,K) bf16.
__global__ __launch_bounds__(256) void wt_convert(const float* __restrict__ in,
                                                  unsigned short* __restrict__ out,
                                                  int K, int N) {
  int i = blockIdx.x * 256 + threadIdx.x;
  if (i >= K * N) return;
  int n = i / K, k = i - n * K;
  out[i] = f2bf(in[(size_t)k * N + n]);
}

__global__ __launch_bounds__(256) void pack_bias(const float* __restrict__ b_pa,
                                                 const float* __restrict__ b_pc,
                                                 float* __restrict__ out) {
  int t = blockIdx.x * 256 + threadIdx.x;
  if (t < 256) out[t] = b_pa[t];
  else if (t < 768) out[t] = b_pc[t - 256];
}

// x (f32) -> bf16, 8 elems/thread.
__global__ __launch_bounds__(256) void cvt_bf16(const float* __restrict__ in,
                                                unsigned short* __restrict__ out,
                                                int n8) {
  int i = blockIdx.x * 256 + threadIdx.x;
  if (i >= n8) return;
  float4 a = ((const float4*)in)[i * 2];
  float4 b = ((const float4*)in)[i * 2 + 1];
  ((ushort4*)out)[i * 2] = make_ushort4(f2bf(a.x), f2bf(a.y), f2bf(a.z), f2bf(a.w));
  ((ushort4*)out)[i * 2 + 1] = make_ushort4(f2bf(b.x), f2bf(b.y), f2bf(b.z), f2bf(b.w));
}

// ---------------------------------------------------------------------------
// Row LayerNorm, strided bf16 in -> compact bf16 out. 4 rows/block (1/wave).
// ---------------------------------------------------------------------------
template <int W>
__global__ __launch_bounds__(256) void ln_rows_bf(
    const unsigned short* __restrict__ in, int istride,
    unsigned short* __restrict__ out,
    const float* __restrict__ g, const float* __restrict__ b) {
  const int row = blockIdx.x * 4 + (threadIdx.x >> 6);
  const int t = threadIdx.x & 63;
  constexpr int NE = W / 64;
  float v[NE];
  const size_t ibase = (size_t)row * istride + t * NE;
  const size_t obase = (size_t)row * W + t * NE;
#pragma unroll
  for (int c4 = 0; c4 < NE / 4; ++c4) {
    ushort4 u = *(const ushort4*)&in[ibase + c4 * 4];
    v[c4 * 4 + 0] = bf2f(u.x); v[c4 * 4 + 1] = bf2f(u.y);
    v[c4 * 4 + 2] = bf2f(u.z); v[c4 * 4 + 3] = bf2f(u.w);
  }
  float s = 0.f, sq = 0.f;
#pragma unroll
  for (int j = 0; j < NE; ++j) { s += v[j]; sq += v[j] * v[j]; }
#pragma unroll
  for (int off = 32; off >= 1; off >>= 1) {
    s += __shfl_xor(s, off);
    sq += __shfl_xor(sq, off);
  }
  const float mean = s * (1.f / W);
  const float var = sq * (1.f / W) - mean * mean;
  const float rstd = rsqrtf(var + EPS);
#pragma unroll
  for (int c4 = 0; c4 < NE / 4; ++c4) {
    int c = t * NE + c4 * 4;
    ushort4 o = make_ushort4(
        f2bf((v[c4 * 4 + 0] - mean) * rstd * g[c + 0] + b[c + 0]),
        f2bf((v[c4 * 4 + 1] - mean) * rstd * g[c + 1] + b[c + 1]),
        f2bf((v[c4 * 4 + 2] - mean) * rstd * g[c + 2] + b[c + 2]),
        f2bf((v[c4 * 4 + 3] - mean) * rstd * g[c + 3] + b[c + 3]));
    *(ushort4*)&out[obase + c4 * 4] = o;
  }
}

// ---------------------------------------------------------------------------
// Depthwise 3x3 + BN1 + GELU, bf16 LDS tile, vectorized staging.
// ---------------------------------------------------------------------------
__global__ __launch_bounds__(256) void dwconv_bn_gelu(
    const unsigned short* __restrict__ xin, const float* __restrict__ wgt9,
    const float* __restrict__ dwb, const float* __restrict__ g1,
    const float* __restrict__ b1, const float* __restrict__ m1,
    const float* __restrict__ v1, unsigned short* __restrict__ outp,
    float* __restrict__ ci_part) {
  __shared__ unsigned short tile[100 * 128];  // 25.6 KB
  __shared__ float psum[8 * 128];             // 4 KB
  const int b_ = blockIdx.x;
  const int b = b_ / 784, win = b_ % 784;
  const int wi = win / 28, wj = win % 28;
  const int h0 = wi * 8 - 1, w0 = wj * 8 - 1;
  const int tid = threadIdx.x;
  const int c4 = (tid & 31) * 4;
  const int pg = tid >> 5;
  for (int chunk = 0; chunk < 4; ++chunk) {
    const int c0 = chunk * 128;
    __syncthreads();
#pragma unroll
    for (int it = 0; it < 7; ++it) {
      int idx = it * 256 + tid;
      if (idx < 1600) {
        int p = idx >> 4;
        int ch8 = (idx & 15) * 8;
        int ph = h0 + p / 10, pw = w0 + p % 10;
        uint4 val = {0u, 0u, 0u, 0u};
        if (ph >= 0 && ph < 224 && pw >= 0 && pw < 224) {
          int bs = b * 784 + (ph >> 3) * 28 + (pw >> 3);
          int n = ((ph & 7) << 3) | (pw & 7);
          val = *(const uint4*)&xin[(size_t)(bs * 64 + n) * 512 + c0 + ch8];
        }
        *(uint4*)&tile[p * 128 + ch8] = val;
      }
    }
    __syncthreads();
    float wreg[9][4];
    float scale[4], shift[4], bias0[4];
#pragma unroll
    for (int j = 0; j < 4; ++j) {
      int cc = c0 + c4 + j;
#pragma unroll
      for (int k = 0; k < 9; ++k) wreg[k][j] = wgt9[cc * 9 + k];
      scale[j] = g1[cc] * rsqrtf(v1[cc] + EPS);
      shift[j] = b1[cc] - m1[cc] * scale[j];
      bias0[j] = dwb[cc];
    }
    float cs0 = 0.f, cs1 = 0.f, cs2 = 0.f, cs3 = 0.f;
    for (int q = 0; q < 8; ++q) {
      const int qq = pg * 8 + q;
      const int r = qq >> 3, cc_ = qq & 7;
      float a0 = bias0[0], a1 = bias0[1], a2 = bias0[2], a3 = bias0[3];
#pragma unroll
      for (int dr = 0; dr < 3; ++dr)
#pragma unroll
        for (int dc = 0; dc < 3; ++dc) {
          ushort4 u = *(const ushort4*)&tile[((r + dr) * 10 + cc_ + dc) * 128 + c4];
          const int k = dr * 3 + dc;
          a0 += bf2f(u.x) * wreg[k][0];
          a1 += bf2f(u.y) * wreg[k][1];
          a2 += bf2f(u.z) * wreg[k][2];
          a3 += bf2f(u.w) * wreg[k][3];
        }
      float g0 = gelu_exact(a0 * scale[0] + shift[0]);
      float g1v = gelu_exact(a1 * scale[1] + shift[1]);
      float g2v = gelu_exact(a2 * scale[2] + shift[2]);
      float g3v = gelu_exact(a3 * scale[3] + shift[3]);
      cs0 += g0; cs1 += g1v; cs2 += g2v; cs3 += g3v;
      *(ushort4*)&outp[(size_t)(b_ * 64 + qq) * 512 + c0 + c4] =
          make_ushort4(f2bf(g0), f2bf(g1v), f2bf(g2v), f2bf(g3v));
    }
    *(float4*)&psum[pg * 128 + c4] = make_float4(cs0, cs1, cs2, cs3);
    __syncthreads();
    if (tid < 128) {
      float s = 0.f;
#pragma unroll
      for (int g = 0; g < 8; ++g) s += psum[g * 128 + tid];
      ci_part[(size_t)b_ * 512 + c0 + tid] = s;
    }
  }
}

__global__ __launch_bounds__(512) void ci_reduce(const float* __restrict__ ci_part,
                                                 float* __restrict__ ci_mean) {
  const int b = blockIdx.x, c = threadIdx.x;
  float s = 0.f;
  for (int w = 0; w < 784; ++w) s += ci_part[(size_t)(b * 784 + w) * 512 + c];
  ci_mean[b * 512 + c] = s * (1.f / 50176.f);
}

__global__ __launch_bounds__(512) void ci_gate(
    const float* __restrict__ ci_mean, const float* __restrict__ w1,
    const float* __restrict__ bi1, const float* __restrict__ g2,
    const float* __restrict__ b2, const float* __restrict__ m2,
    const float* __restrict__ v2, const float* __restrict__ w2,
    const float* __restrict__ bi2, float* __restrict__ gate) {
  __shared__ float cm[1024];
  __shared__ float c1[128];
  const int t = threadIdx.x;
  cm[t] = ci_mean[t];
  cm[t + 512] = ci_mean[t + 512];
  __syncthreads();
  if (t < 128) {
    int b = t >> 6, j = t & 63;
    float acc = bi1[j];
    for (int c = 0; c < 512; ++c) acc += cm[b * 512 + c] * w1[c * 64 + j];
    float sc = g2[j] * rsqrtf(v2[j] + EPS);
    c1[t] = gelu_exact((acc - m2[j]) * sc + b2[j]);
  }
  __syncthreads();
  {
    int b = t >> 8, o = t & 255;
    float acc = bi2[o];
#pragma unroll
    for (int j = 0; j < 64; ++j) acc += c1[b * 64 + j] * w2[j * 256 + o];
    gate[b * 256 + o] = 1.f / (1.f + expf(-acc));
  }
}

// Precompute bias table biasf[h][n][m] = rpb[rel[n*64+m]*8+h]
__global__ __launch_bounds__(256) void bias_pre(const float* __restrict__ rpb,
                                                const int* __restrict__ rel,
                                                float* __restrict__ biasf) {
  int i = blockIdx.x * 256 + threadIdx.x;
  if (i >= 4096) return;
  int r = rel[i];
#pragma unroll
  for (int h = 0; h < 8; ++h) biasf[h * 4096 + i] = rpb[r * 8 + h];
}

// ---------------------------------------------------------------------------
// MFMA windowed attention (bf16 out). Block = 1 window, 4 waves x 2 heads.
// ---------------------------------------------------------------------------
__global__ __launch_bounds__(256) void attn_mfma(
    const unsigned short* __restrict__ qkv,  // (M,768) bf16
    const float* __restrict__ gate,          // (2,256)
    const float* __restrict__ biasf,         // (8,64,64) f32
    unsigned short* __restrict__ outp) {     // (M,256) bf16
  __shared__ unsigned short lds[4 * (64 * 68 + 32 * 68)];
  const int w = blockIdx.x;
  const int b = w / 784;
  const int tid = threadIdx.x, lane = tid & 63, wave = tid >> 6;
  unsigned short* p_lds = lds + wave * (64 * 68 + 32 * 68);
  unsigned short* vT = p_lds + 64 * 68;
  const int l15 = lane & 15, l4 = lane >> 4;
  const float scale = 0.17677669529663687f;
  for (int hh = 0; hh < 2; ++hh) {
    const int h = wave * 2 + hh;
    {
      const float* gh = &gate[b * 256 + h * 32];
      const size_t vbase = ((size_t)w * 64 + lane) * 768 + 512 + h * 32;
#pragma unroll
      for (int c = 0; c < 4; ++c) {
        uint4 vv = *(const uint4*)&qkv[vbase + c * 8];
        float4 gA = *(const float4*)&gh[c * 8];
        float4 gB = *(const float4*)&gh[c * 8 + 4];
        unsigned vw[4] = {vv.x, vv.y, vv.z, vv.w};
        float gg[8] = {gA.x, gA.y, gA.z, gA.w, gB.x, gB.y, gB.z, gB.w};
#pragma unroll
        for (int j = 0; j < 4; ++j) {
          int d = c * 8 + j * 2;
          vT[(d + 0) * 68 + lane] = f2bf(__uint_as_float(vw[j] << 16) * gg[j * 2]);
          vT[(d + 1) * 68 + lane] =
              f2bf(__uint_as_float(vw[j] & 0xffff0000u) * gg[j * 2 + 1]);
        }
      }
    }
    bf16x8 kf[4], qf[4];
    const size_t qkbase = (size_t)w * 64 * 768 + h * 32 + l4 * 8;
#pragma unroll
    for (int t = 0; t < 4; ++t) {
      kf[t] = *(const bf16x8*)&qkv[qkbase + (size_t)(t * 16 + l15) * 768 + 256];
      qf[t] = *(const bf16x8*)&qkv[qkbase + (size_t)(t * 16 + l15) * 768];
    }
    f32x4 s[4][4];
#pragma unroll
    for (int mt = 0; mt < 4; ++mt)
#pragma unroll
      for (int nt = 0; nt < 4; ++nt) s[mt][nt] = (f32x4){0.f, 0.f, 0.f, 0.f};
#pragma unroll
    for (int mt = 0; mt < 4; ++mt)
#pragma unroll
      for (int nt = 0; nt < 4; ++nt)
        s[mt][nt] = __builtin_amdgcn_mfma_f32_16x16x32_bf16(kf[mt], qf[nt],
                                                            s[mt][nt], 0, 0, 0);
    float inv_s[4];
#pragma unroll
    for (int nt = 0; nt < 4; ++nt) {
      float mx = -1e30f;
#pragma unroll
      for (int mt = 0; mt < 4; ++mt) {
        float4 b4 = *(const float4*)&biasf[(h * 64 + nt * 16 + l15) * 64 +
                                           mt * 16 + l4 * 4];
        s[mt][nt][0] = s[mt][nt][0] * scale + b4.x;
        s[mt][nt][1] = s[mt][nt][1] * scale + b4.y;
        s[mt][nt][2] = s[mt][nt][2] * scale + b4.z;
        s[mt][nt][3] = s[mt][nt][3] * scale + b4.w;
#pragma unroll
        for (int r = 0; r < 4; ++r) mx = fmaxf(mx, s[mt][nt][r]);
      }
      mx = fmaxf(mx, __shfl_xor(mx, 16));
      mx = fmaxf(mx, __shfl_xor(mx, 32));
      float sum = 0.f;
#pragma unroll
      for (int mt = 0; mt < 4; ++mt)
#pragma unroll
        for (int r = 0; r < 4; ++r) {
          float e = __expf(s[mt][nt][r] - mx);
          s[mt][nt][r] = e;
          sum += e;
        }
      sum += __shfl_xor(sum, 16);
      sum += __shfl_xor(sum, 32);
      inv_s[nt] = 1.f / sum;
    }
#pragma unroll
    for (int nt = 0; nt < 4; ++nt)
#pragma unroll
      for (int mt = 0; mt < 4; ++mt) {
        ushort4 pk = make_ushort4(f2bf(s[mt][nt][0] * inv_s[nt]),
                                  f2bf(s[mt][nt][1] * inv_s[nt]),
                                  f2bf(s[mt][nt][2] * inv_s[nt]),
                                  f2bf(s[mt][nt][3] * inv_s[nt]));
        *(ushort4*)&p_lds[(nt * 16 + l15) * 68 + mt * 16 + l4 * 4] = pk;
      }
    f32x4 o[4][2];
#pragma unroll
    for (int i = 0; i < 4; ++i)
#pragma unroll
      for (int dt = 0; dt < 2; ++dt) o[i][dt] = (f32x4){0.f, 0.f, 0.f, 0.f};
#pragma unroll
    for (int ks = 0; ks < 2; ++ks) {
      bf16x8 pa[4], vf[2];
#pragma unroll
      for (int i = 0; i < 4; ++i) {
        const unsigned short* pp = &p_lds[(i * 16 + l15) * 68 + ks * 32 + l4 * 8];
        union { bf16x8 v; ushort4 u[2]; } tmp;
        tmp.u[0] = *(const ushort4*)pp;
        tmp.u[1] = *(const ushort4*)(pp + 4);
        pa[i] = tmp.v;
      }
#pragma unroll
      for (int dt = 0; dt < 2; ++dt) {
        const unsigned short* vp = &vT[(dt * 16 + l15) * 68 + ks * 32 + l4 * 8];
        union { bf16x8 v; ushort4 u[2]; } tmp;
        tmp.u[0] = *(const ushort4*)vp;
        tmp.u[1] = *(const ushort4*)(vp + 4);
        vf[dt] = tmp.v;
      }
#pragma unroll
      for (int i = 0; i < 4; ++i)
#pragma unroll
        for (int dt = 0; dt < 2; ++dt)
          o[i][dt] = __builtin_amdgcn_mfma_f32_16x16x32_bf16(pa[i], vf[dt],
                                                             o[i][dt], 0, 0, 0);
    }
#pragma unroll
    for (int i = 0; i < 4; ++i)
#pragma unroll
      for (int dt = 0; dt < 2; ++dt)
#pragma unroll
        for (int r = 0; r < 4; ++r)
          outp[((size_t)w * 64 + i * 16 + l4 * 4 + r) * 256 + h * 32 +
               dt * 16 + l15] = f2bf(o[i][dt][r]);
  }
}

// ---------------------------------------------------------------------------
// Spatial gate + BN3 + LN-out + concat (bf16 in, bf16 out).
// ---------------------------------------------------------------------------
__global__ __launch_bounds__(256) void si_ln_concat(
    const unsigned short* __restrict__ xatt, const unsigned short* __restrict__ xpj,
    const float* __restrict__ w1, const float* __restrict__ bi1,
    const float* __restrict__ g4, const float* __restrict__ b4v,
    const float* __restrict__ m4, const float* __restrict__ v4,
    const float* __restrict__ w2, const float* __restrict__ bi2,
    const float* __restrict__ g3, const float* __restrict__ b3v,
    const float* __restrict__ m3, const float* __restrict__ v3,
    const float* __restrict__ glno, const float* __restrict__ blno,
    unsigned short* __restrict__ outc) {
  __shared__ float xr[16 * 256];
  __shared__ float s1s[16 * 64];
  __shared__ float sig[16];
  const int t = threadIdx.x;
  const int row0 = blockIdx.x * 16;
#pragma unroll
  for (int i = 0; i < 2; ++i) {
    int idx = i * 256 + t;
    int pr = idx >> 5, pc = (idx & 31) * 8;
    const unsigned short* src = &xatt[(size_t)(row0 + pr) * 256 + pc];
    ushort4 a = *(const ushort4*)src;
    ushort4 c = *(const ushort4*)(src + 4);
    float* dst = &xr[pr * 256 + pc];
    dst[0] = bf2f(a.x); dst[1] = bf2f(a.y); dst[2] = bf2f(a.z); dst[3] = bf2f(a.w);
    dst[4] = bf2f(c.x); dst[5] = bf2f(c.y); dst[6] = bf2f(c.z); dst[7] = bf2f(c.w);
  }
  __syncthreads();
  {
    const int j = t & 63, pg = t >> 6;
    float acc[4];
    const float bj = bi1[j];
#pragma unroll
    for (int i = 0; i < 4; ++i) acc[i] = bj;
    for (int cc = 0; cc < 256; ++cc) {
      float wv = w1[cc * 64 + j];
#pragma unroll
      for (int i = 0; i < 4; ++i) acc[i] += xr[(pg * 4 + i) * 256 + cc] * wv;
    }
    const float sc4 = g4[j] * rsqrtf(v4[j] + EPS);
    const float m4j = m4[j], b4j = b4v[j];
#pragma unroll
    for (int i = 0; i < 4; ++i)
      s1s[(pg * 4 + i) * 64 + j] = gelu_exact((acc[i] - m4j) * sc4 + b4j);
  }
  __syncthreads();
  if (t < 16) {
    float a2 = bi2[0];
#pragma unroll
    for (int jj = 0; jj < 64; ++jj) a2 += s1s[t * 64 + jj] * w2[jj];
    sig[t] = 1.f / (1.f + expf(-a2));
  }
  __syncthreads();
  {
    const int p = t >> 4, l = t & 15;
    float4 v4s[4];
    float s = 0.f, sq = 0.f;
#pragma unroll
    for (int cq = 0; cq < 4; ++cq) {
      float4 x4 = *(const float4*)&xr[p * 256 + cq * 64 + l * 4];
      v4s[cq] = x4;
      s += x4.x + x4.y + x4.z + x4.w;
      sq += x4.x * x4.x + x4.y * x4.y + x4.z * x4.z + x4.w * x4.w;
    }
#pragma unroll
    for (int off = 8; off >= 1; off >>= 1) {
      s += __shfl_xor(s, off);
      sq += __shfl_xor(sq, off);
    }
    const float mean = s * (1.f / 256.f);
    const float var = sq * (1.f / 256.f) - mean * mean;
    const float rstd = rsqrtf(var + EPS);
    const size_t orow = (size_t)(row0 + p) * 512;
#pragma unroll
    for (int cq = 0; cq < 4; ++cq) {
      int c = cq * 64 + l * 4;
      float4 x4 = v4s[cq];
      *(ushort4*)&outc[orow + c] = make_ushort4(
          f2bf((x4.x - mean) * rstd * glno[c + 0] + blno[c + 0]),
          f2bf((x4.y - mean) * rstd * glno[c + 1] + blno[c + 1]),
          f2bf((x4.z - mean) * rstd * glno[c + 2] + blno[c + 2]),
          f2bf((x4.w - mean) * rstd * glno[c + 3] + blno[c + 3]));
    }
    const float sg = sig[p];
#pragma unroll
    for (int cq = 0; cq < 4; ++cq) {
      int c = cq * 64 + l * 4;
      ushort4 pu = *(const ushort4*)&xpj[(size_t)(row0 + p) * 256 + c];
      float px = bf2f(pu.x), py = bf2f(pu.y), pz = bf2f(pu.z), pw = bf2f(pu.w);
      float sc0 = g3[c + 0] * rsqrtf(v3[c + 0] + EPS);
      float sc1 = g3[c + 1] * rsqrtf(v3[c + 1] + EPS);
      float sc2 = g3[c + 2] * rsqrtf(v3[c + 2] + EPS);
      float sc3 = g3[c + 3] * rsqrtf(v3[c + 3] + EPS);
      *(ushort4*)&outc[orow + 256 + c] = make_ushort4(
          f2bf(sg * px * sc0 + (b3v[c + 0] - m3[c + 0] * sc0)),
          f2bf(sg * py * sc1 + (b3v[c + 1] - m3[c + 1] * sc1)),
          f2bf(sg * pz * sc2 + (b3v[c + 2] - m3[c + 2] * sc2)),
          f2bf(sg * pw * sc3 + (b3v[c + 3] - m3[c + 3] * sc3)));
    }
  }
}

// ---------------------------------------------------------------------------
extern "C" void kernel_launch(void* const* d_in, const int* in_sizes, int n_in,
                              void* d_out, int out_size, void* d_ws, size_t ws_size,
                              hipStream_t stream) {
  const float* x     = (const float*)d_in[0];
  const float* w_pa  = (const float*)d_in[1];
  const float* b_pa  = (const float*)d_in[2];
  const float* g_lna = (const float*)d_in[3];
  const float* b_lna = (const float*)d_in[4];
  const float* w_pc  = (const float*)d_in[5];
  const float* b_pc  = (const float*)d_in[6];
  const float* g_lnc = (const float*)d_in[7];
  const float* b_lnc = (const float*)d_in[8];
  const float* dw_w  = (const float*)d_in[9];
  const float* dw_b  = (const float*)d_in[10];
  const float* g_bn1 = (const float*)d_in[11];
  const float* b_bn1 = (const float*)d_in[12];
  const float* m_bn1 = (const float*)d_in[13];
  const float* v_bn1 = (const float*)d_in[14];
  const float* ci_w1 = (const float*)d_in[15];
  const float* ci_b1 = (const float*)d_in[16];
  const float* g_bn2 = (const float*)d_in[17];
  const float* b_bn2 = (const float*)d_in[18];
  const float* m_bn2 = (const float*)d_in[19];
  const float* v_bn2 = (const float*)d_in[20];
  const float* ci_w2 = (const float*)d_in[21];
  const float* ci_b2 = (const float*)d_in[22];
  const float* pj_w  = (const float*)d_in[23];
  const float* pj_b  = (const float*)d_in[24];
  const float* g_bn3 = (const float*)d_in[25];
  const float* b_bn3 = (const float*)d_in[26];
  const float* m_bn3 = (const float*)d_in[27];
  const float* v_bn3 = (const float*)d_in[28];
  const float* w_qkv = (const float*)d_in[29];
  const float* b_qkv = (const float*)d_in[30];
  const float* si_w1 = (const float*)d_in[31];
  const float* si_b1 = (const float*)d_in[32];
  const float* g_bn4 = (const float*)d_in[33];
  const float* b_bn4 = (const float*)d_in[34];
  const float* m_bn4 = (const float*)d_in[35];
  const float* v_bn4 = (const float*)d_in[36];
  const float* si_w2 = (const float*)d_in[37];
  const float* si_b2 = (const float*)d_in[38];
  const float* g_lno = (const float*)d_in[39];
  const float* b_lno = (const float*)d_in[40];
  const float* w_out = (const float*)d_in[41];
  const float* b_out = (const float*)d_in[42];
  const float* rpb   = (const float*)d_in[43];
  const int*   rel   = (const int*)d_in[44];

  char* ws = (char*)d_ws;
  // Phase-aliased workspace (~468 MB):
  unsigned short* G12BF = (unsigned short*)(ws + 0);            // (M,768) fused pre-LN
  unsigned short* QKVBF = (unsigned short*)(ws + 0);            // (M,768), after G12 dead
  unsigned short* A1BF  = (unsigned short*)(ws + 154140672ull); // (M,256) x_att LN
  unsigned short* ATTBF = (unsigned short*)(ws + 154140672ull); // (M,256), after A1 dead
  unsigned short* C1BF  = (unsigned short*)(ws + 205520896ull); // (M,512) x_cnn LN
  unsigned short* CAT   = (unsigned short*)(ws + 205520896ull); // (M,512), after C1 dead
  unsigned short* XBF   = (unsigned short*)(ws + 308281344ull); // (M,512) x bf16
  unsigned short* CVBF  = (unsigned short*)(ws + 308281344ull); // (M,512), after XBF dead
  unsigned short* PJBF  = (unsigned short*)(ws + 411041792ull); // (M,256) pj out
  float*          CIP   = (float*)(ws + 462422016ull);          // (1568,512)
  float*          CIM   = (float*)(ws + 465633280ull);          // (2,512)
  float*          GATE  = (float*)(ws + 465637376ull);          // (2,256)
  float*          B12   = (float*)(ws + 465639424ull);          // (768)
  float*          BIASF = (float*)(ws + 465642496ull);          // (8,64,64)
  unsigned short* WT    = (unsigned short*)(ws + 465773568ull);
  unsigned short* WpaT  = WT + 0;       // (256,512) -- contiguous with WpcT = (768,512)
  unsigned short* WpcT  = WT + 131072;  // (512,512)
  unsigned short* PjT   = WT + 393216;  // (256,512)
  unsigned short* QkvT  = WT + 524288;  // (768,256)
  unsigned short* OutT  = WT + 720896;  // (512,512)

  const int M = MROWS;
  dim3 b256(256), b512(512);

  wt_convert<<<512, b256, 0, stream>>>(w_pa, WpaT, 512, 256);
  wt_convert<<<1024, b256, 0, stream>>>(w_pc, WpcT, 512, 512);
  wt_convert<<<512, b256, 0, stream>>>(pj_w, PjT, 512, 256);
  wt_convert<<<768, b256, 0, stream>>>(w_qkv, QkvT, 256, 768);
  wt_convert<<<1024, b256, 0, stream>>>(w_out, OutT, 512, 512);
  pack_bias<<<3, b256, 0, stream>>>(b_pa, b_pc, B12);

  // 0) x -> bf16
  cvt_bf16<<<(M * 512 / 8 + 255) / 256, b256, 0, stream>>>(x, XBF, M * 512 / 8);

  // 1+2) fused input GEMM: [x@w_pa | x@w_pc] -> G12BF (M,768)
  gemm256<true><<<dim3(3, M / 256), dim3(512), 0, stream>>>(XBF, WpaT, B12, G12BF,
                                                            M, 768, 512);
  ln_rows_bf<256><<<M / 4, b256, 0, stream>>>(G12BF, 768, A1BF, g_lna, b_lna);
  ln_rows_bf<512><<<M / 4, b256, 0, stream>>>(G12BF + 256, 768, C1BF, g_lnc, b_lnc);

  // 3) depthwise conv + BN1 + GELU + channel sums (XBF dead -> CVBF)
  dwconv_bn_gelu<<<NWIN, b256, 0, stream>>>(C1BF, dw_w, dw_b, g_bn1, b_bn1, m_bn1,
                                            v_bn1, CVBF, CIP);
  ci_reduce<<<2, b512, 0, stream>>>(CIP, CIM);
  ci_gate<<<1, b512, 0, stream>>>(CIM, ci_w1, ci_b1, g_bn2, b_bn2, m_bn2, v_bn2,
                                  ci_w2, ci_b2, GATE);
  bias_pre<<<16, b256, 0, stream>>>(rpb, rel, BIASF);

  // 4) pj GEMM (bf16 out)
  gemm256<true><<<dim3(1, M / 256), dim3(512), 0, stream>>>(CVBF, PjT, pj_b, PJBF,
                                                            M, 256, 512);

  // 5) qkv GEMM (bf16 out; G12BF dead -> QKVBF)
  gemm256<true><<<dim3(3, M / 256), dim3(512), 0, stream>>>(A1BF, QkvT, b_qkv, QKVBF,
                                                            M, 768, 256);

  // 6) MFMA windowed attention (A1BF dead -> ATTBF)
  attn_mfma<<<NWIN, b256, 0, stream>>>(QKVBF, GATE, BIASF, ATTBF);

  // 7) spatial gate + BN3 + LN-out + concat (C1BF dead -> CAT)
  si_ln_concat<<<M / 16, b256, 0, stream>>>(ATTBF, PJBF, si_w1, si_b1, g_bn4, b_bn4,
                                            m_bn4, v_bn4, si_w2, si_b2, g_bn3,
                                            b_bn3, m_bn3, v_bn3, g_lno, b_lno, CAT);

  // 8) final GEMM -> d_out (f32)
  gemm256<false><<<dim3(2, M / 256), dim3(512), 0, stream>>>(CAT, OutT, b_out,
                                                             (float*)d_out, M, 512, 512);
}